// Round 7
// baseline (655.484 us; speedup 1.0000x reference)
//
#include <hip/hip_runtime.h>
#include <hip/hip_bf16.h>
#include <cstdint>
#include <cstddef>

#define NTOT 2048
#define BTOT 4

typedef short bf16x8 __attribute__((ext_vector_type(8)));
typedef float f32x4 __attribute__((ext_vector_type(4)));

__device__ inline unsigned short f2b(float v) {
    __hip_bfloat16 h = __float2bfloat16(v);
    return *reinterpret_cast<unsigned short*>(&h);
}

// ---------------- workspace layout (float-element offsets) ----------------
static const size_t WS_IDX20 = 0;                       // int[163840]
static const size_t WS_X1T   = 163840;                  // float[1032192] (B,2048,126) pool1 gather copy
static const size_t WS_X0    = 1638400;                 // float[2064384] (B,42,3,2048)
static const size_t WS_X1    = 3702784;                 // float[2064384]
static const size_t WS_XM2   = 5767168;                 // float[258048]
static const size_t WS_X2    = 6025216;                 // float[516096]
static const size_t WS_X3    = 6541312;                 // float[516096]
static const size_t WS_IDX42 = 7057408;                 // int[2048]
static const size_t WS_XM4   = 7059456;                 // float[129024]
static const size_t WS_X4    = 7188480;                 // float[258048]
static const size_t WS_I1    = 7446528;                 // int[8192]
static const size_t WS_I2    = 7454720;                 // int[8192]
static const size_t WS_MF    = 7462912;                 // float[5040]
static const size_t WS_INVGL = 7467952;                 // float[3360]
static const size_t WS_STATS = 7471312;                 // double[840] (1680 fl slots)
static const size_t WS_CST   = 7472992;                 // float[3912] conv bn sums
static const size_t WS_CB    = 7480320;                 // float[4096]   cb[b][o]
static const size_t WS_AB    = 7484416;                 // float[12288]  ab[b][o][3]
static const size_t WS_W0    = 7496704;                 // float[1024]   ws1[:,0]
static const size_t WS_X3T   = 7501312;                 // float[516096] (B,512,252) pool2 gather copy
                                                        //   (inside Y2T span; lifetime-disjoint: dead before gemm1)
static const size_t WS_W2B   = 13378560;                // ushort[512*1024]
static const size_t WS_W3B   = 13640704;                // ushort[512*512]
static const size_t WS_Y1B   = 0;                       // ushort overlay (written late; x1t dead by then)
static const size_t WS_Y2T   = 7480320;                 // float overlay (CB/AB dead)
static const size_t WS_Y2B   = 4194304;                 // ushort overlay
static const size_t WS_Y3T   = 13771776;                // float overlay

// zero-span: mfw..cst contiguous (mfw 5040 + invgl 3360 + stats 1680 + cst 3912)
#define ZERO_SPAN_BYTES ((7476904 - 7462912) * 4)

#define ST0_OFF 0
#define ST1_OFF 84
#define ST2_OFF 168
#define ST3_OFF 336
#define ST4_OFF 504
#define CST1_OFF 0
#define CST2_OFF 2048
#define CST3_OFF 3072

#define OUT_EQV   0
#define OUT_MF    10321920
#define OUT_INV   10326960
#define OUT_INVGL 13767600

// ============================ KNN v5 (v3 extraction + NQ-query ILP) ==========
// NOTE: fp contract OFF here — distance ordering feeds index selection.
template <int SLOTS, int K, int NQ>
__global__ __launch_bounds__(256)
void knn_reg_kernel(const float* __restrict__ coord, int cand_stride, int q_stride,
                    int* __restrict__ out_idx, int q_cnt)
{
#pragma clang fp contract(off)
    constexpr int Q = SLOTS / 8;
    int b = blockIdx.y;
    int wave = threadIdx.x >> 6, lane = threadIdx.x & 63;
    int qbase = (blockIdx.x * 4 + wave) * NQ;
    if (qbase >= q_cnt) return;
    float qx[NQ], qy[NQ], qz[NQ], xxq[NQ];
#pragma unroll
    for (int u = 0; u < NQ; ++u) {
        int nq = (qbase + u) * q_stride;
        qx[u] = coord[(b * 3 + 0) * NTOT + nq];
        qy[u] = coord[(b * 3 + 1) * NTOT + nq];
        qz[u] = coord[(b * 3 + 2) * NTOT + nq];
        xxq[u] = qx[u] * qx[u] + qy[u] * qy[u] + qz[u] * qz[u];
    }
    float v[NQ][SLOTS];
#pragma unroll
    for (int j = 0; j < SLOTS; ++j) {
        int mo = (lane + 64 * j) * cand_stride;
        float cx = coord[(b * 3 + 0) * NTOT + mo];
        float cy = coord[(b * 3 + 1) * NTOT + mo];
        float cz = coord[(b * 3 + 2) * NTOT + mo];
        float xxc = cx * cx + cy * cy + cz * cz;
#pragma unroll
        for (int u = 0; u < NQ; ++u) {
            float inner = qx[u] * cx + qy[u] * cy + qz[u] * cz;
            v[u][j] = (2.0f * inner - xxq[u]) - xxc;
        }
    }
    float qv[NQ][Q]; int qj[NQ][Q];
#pragma unroll
    for (int u = 0; u < NQ; ++u)
#pragma unroll
        for (int qq = 0; qq < Q; ++qq) {
            float nv = v[u][qq * 8]; int nj = qq * 8;
#pragma unroll
            for (int j = 1; j < 8; ++j)
                if (v[u][qq * 8 + j] > nv) { nv = v[u][qq * 8 + j]; nj = qq * 8 + j; }
            qv[u][qq] = nv; qj[u][qq] = nj;
        }
#pragma clang loop unroll(disable)
    for (int kk = 0; kk < K; ++kk) {
        float bv[NQ]; int bm[NQ];
#pragma unroll
        for (int u = 0; u < NQ; ++u) {
            float tv = qv[u][0]; int tj = qj[u][0];
#pragma unroll
            for (int qq = 1; qq < Q; ++qq)
                if (qv[u][qq] > tv) { tv = qv[u][qq]; tj = qj[u][qq]; }
            bv[u] = tv; bm[u] = lane + 64 * tj;
        }
        // interleaved butterflies: NQ independent chains hide shuffle latency
        for (int off = 32; off; off >>= 1) {
            float ov[NQ]; int om[NQ];
#pragma unroll
            for (int u = 0; u < NQ; ++u) {
                ov[u] = __shfl_down(bv[u], off);
                om[u] = __shfl_down(bm[u], off);
            }
#pragma unroll
            for (int u = 0; u < NQ; ++u)
                if (ov[u] > bv[u] || (ov[u] == bv[u] && om[u] < bm[u])) {
                    bv[u] = ov[u]; bm[u] = om[u];
                }
        }
#pragma unroll
        for (int u = 0; u < NQ; ++u) {
            int m_win = __builtin_amdgcn_readfirstlane(bm[u]);
            if (lane == 0)
                out_idx[((size_t)(b * q_cnt) + qbase + u) * K + kk] = m_win;
            int w_slot = m_win >> 6;
            bool isw = (lane == (m_win & 63));
#pragma unroll
            for (int qq = 0; qq < Q; ++qq) {
                if (qq == (w_slot >> 3)) {
#pragma unroll
                    for (int j = 0; j < 8; ++j)
                        if (qq * 8 + j == w_slot)
                            v[u][qq * 8 + j] = isw ? -3.4e38f : v[u][qq * 8 + j];
                    float nv = v[u][qq * 8]; int nj = qq * 8;
#pragma unroll
                    for (int j = 1; j < 8; ++j)
                        if (v[u][qq * 8 + j] > nv) { nv = v[u][qq * 8 + j]; nj = qq * 8 + j; }
                    qv[u][qq] = nv; qj[u][qq] = nj;
                }
            }
        }
    }
}

// ============================ nearest DUAL (i1 stride-4 + i2 stride-16) ======
__global__ __launch_bounds__(256)
void nearest_dual_kernel(const float* __restrict__ coord,
                         int* __restrict__ out1, int* __restrict__ out2)
{
#pragma clang fp contract(off)
    int b = blockIdx.y;
    int wave = threadIdx.x >> 6, lane = threadIdx.x & 63;
    int n = blockIdx.x * 4 + wave;
    float qx = coord[(b * 3 + 0) * NTOT + n];
    float qy = coord[(b * 3 + 1) * NTOT + n];
    float qz = coord[(b * 3 + 2) * NTOT + n];
    float tt = qx * qx + qy * qy + qz * qz;
    float v[8];
#pragma unroll
    for (int j = 0; j < 8; ++j) {
        int mo = (lane + 64 * j) * 4;
        float cx = coord[(b * 3 + 0) * NTOT + mo];
        float cy = coord[(b * 3 + 1) * NTOT + mo];
        float cz = coord[(b * 3 + 2) * NTOT + mo];
        float inner = qx * cx + qy * cy + qz * cz;
        float ss = cx * cx + cy * cy + cz * cz;
        v[j] = (tt - 2.0f * inner) + ss;
    }
    float bv = v[0];
    int bj = 0;
#pragma unroll
    for (int j = 1; j < 8; ++j)
        if (v[j] < bv) { bv = v[j]; bj = j; }
    int bm = lane + 64 * bj;
    bool has2 = ((lane & 3) == 0);
    float bv2 = 3.4e38f;
    int bm2 = 0x7fffffff;
    if (has2) {
        bv2 = v[0]; bm2 = (lane >> 2);
#pragma unroll
        for (int j = 1; j < 8; ++j) {
            if (v[j] < bv2) { bv2 = v[j]; bm2 = (lane >> 2) + 16 * j; }
        }
    }
    for (int off = 32; off; off >>= 1) {
        float ov = __shfl_down(bv, off);
        int   om = __shfl_down(bm, off);
        if (ov < bv || (ov == bv && om < bm)) { bv = ov; bm = om; }
        float ov2 = __shfl_down(bv2, off);
        int   om2 = __shfl_down(bm2, off);
        if (ov2 < bv2 || (ov2 == bv2 && om2 < bm2)) { bv2 = ov2; bm2 = om2; }
    }
    if (lane == 0) {
        out1[b * NTOT + n] = bm;
        out2[b * NTOT + n] = bm2;
    }
}

// ============================ stage-0 stats (fused surf feature) ==============
__global__ __launch_bounds__(256)
void stats0_kernel(const float* __restrict__ coord, const int* __restrict__ idx20,
                   const float* __restrict__ wf0, double* __restrict__ stats)
{
    __shared__ float nbc[360];   // [6 pts][20 nb][xyz]
    __shared__ float ctr[18];    // [6 pts][xyz]
    __shared__ double red[2][6][42];
    int t = threadIdx.x, b = blockIdx.y;
    int ps = t / 42, o = t - ps * 42;
    bool active = ps < 6;
    float w0 = 0.f, w1 = 0.f, w2 = 0.f;
    if (active) { w0 = wf0[o * 3]; w1 = wf0[o * 3 + 1]; w2 = wf0[o * 3 + 2]; }
    double s = 0.0, s2 = 0.0;
    int base = blockIdx.x * 48;
    for (int it = 0; it < 8; ++it) {
        int n0 = base + it * 6;
        __syncthreads();
        if (t < 120) {
            int pl = t / 20, k = t - pl * 20;
            int n = n0 + pl; if (n > NTOT - 1) n = NTOT - 1;
            int m = idx20[((size_t)(b * NTOT + n)) * 20 + k];
            nbc[t * 3 + 0] = coord[(b * 3 + 0) * NTOT + m];
            nbc[t * 3 + 1] = coord[(b * 3 + 1) * NTOT + m];
            nbc[t * 3 + 2] = coord[(b * 3 + 2) * NTOT + m];
        }
        if (t >= 128 && t < 146) {
            int i = t - 128; int pl = i / 3, vd = i - pl * 3;
            int n = n0 + pl; if (n > NTOT - 1) n = NTOT - 1;
            ctr[i] = coord[(b * 3 + vd) * NTOT + n];
        }
        __syncthreads();
        if (active && n0 + ps < NTOT) {
            float cx = ctr[ps * 3], cy = ctr[ps * 3 + 1], cz = ctr[ps * 3 + 2];
            const float* nb = &nbc[ps * 60];
            float sf = 0.f, sf2 = 0.f;
            for (int k = 0; k < 20; ++k) {
                float nx = nb[k * 3], ny = nb[k * 3 + 1], nz = nb[k * 3 + 2];
                float dx = nx - cx, dy = ny - cy, dz = nz - cz;
                float crx = ny * cz - nz * cy;
                float cry = nz * cx - nx * cz;
                float crz = nx * cy - ny * cx;
                float p0 = w0 * dx + w1 * cx + w2 * crx;
                float p1 = w0 * dy + w1 * cy + w2 * cry;
                float p2 = w0 * dz + w1 * cz + w2 * crz;
                float nrm = sqrtf(p0 * p0 + p1 * p1 + p2 * p2) + 1e-6f;
                sf += nrm; sf2 += nrm * nrm;
            }
            s += (double)sf; s2 += (double)sf2;
        }
    }
    if (active) { red[0][ps][o] = s; red[1][ps][o] = s2; }
    __syncthreads();
    if (t < 42) {
        double a = 0.0, a2 = 0.0;
#pragma unroll
        for (int p = 0; p < 6; ++p) { a += red[0][p][t]; a2 += red[1][p][t]; }
        atomicAdd(&stats[t], a);
        atomicAdd(&stats[42 + t], a2);
    }
}

// ============ stage-0 apply (fused surf feature + FUSED stage-1 stats) =======
// NIT=8: grid (43,4), each block covers 48 points; stage-1 BN stats computed
// from the block-resident outputs (kills the standalone stats1 pass + x0 re-read).
__global__ __launch_bounds__(256)
void apply0_kernel(const float* __restrict__ coord, const int* __restrict__ idx20,
                   const float* __restrict__ wf0, const float* __restrict__ wd0,
                   const float* __restrict__ g0, const float* __restrict__ b0,
                   const double* __restrict__ stats,
                   const float* __restrict__ wf1, double* __restrict__ stats1,
                   float* __restrict__ x0)
{
    __shared__ float nbc[360];
    __shared__ float ctr[18];
    __shared__ float colout[6][127];
    __shared__ double red[2][6][42];
    int t = threadIdx.x;
    int b = blockIdx.y;
    int ps = t / 42, o = t - ps * 42;
    bool active = ps < 6;
    float m = 0.f, gs = 0.f, bb = 0.f;
    float wa0 = 0.f, wa1 = 0.f, wa2 = 0.f, wb0 = 0.f, wb1 = 0.f, wb2 = 0.f;
    if (active) {
        double S1 = stats[o], S2 = stats[42 + o];
        double md = S1 / 163840.0;
        m = (float)md;
        float var = (float)(S2 / 163840.0 - md * md);
        gs = g0[o] / sqrtf(var + 1e-5f);
        bb = b0[o];
        wa0 = wf0[o * 3]; wa1 = wf0[o * 3 + 1]; wa2 = wf0[o * 3 + 2];
        wb0 = wd0[o * 3]; wb1 = wd0[o * 3 + 1]; wb2 = wd0[o * 3 + 2];
    }
    double s1 = 0.0, s2 = 0.0;
    int base = blockIdx.x * 48;
    for (int it = 0; it < 8; ++it) {
        int n0 = base + it * 6;
        __syncthreads();
        if (t < 120) {
            int pl = t / 20, k = t - pl * 20;
            int n = n0 + pl; if (n > NTOT - 1) n = NTOT - 1;
            int mm = idx20[((size_t)(b * NTOT + n)) * 20 + k];
            nbc[t * 3 + 0] = coord[(b * 3 + 0) * NTOT + mm];
            nbc[t * 3 + 1] = coord[(b * 3 + 1) * NTOT + mm];
            nbc[t * 3 + 2] = coord[(b * 3 + 2) * NTOT + mm];
        }
        if (t >= 128 && t < 146) {
            int i = t - 128; int pl = i / 3, vd = i - pl * 3;
            int n = n0 + pl; if (n > NTOT - 1) n = NTOT - 1;
            ctr[i] = coord[(b * 3 + vd) * NTOT + n];
        }
        __syncthreads();
        int n = n0 + ps;
        bool valid = active && n < NTOT;
        if (valid) {
            float cx = ctr[ps * 3], cy = ctr[ps * 3 + 1], cz = ctr[ps * 3 + 2];
            const float* nb = &nbc[ps * 60];
            float a0 = 0.f, a1 = 0.f, a2 = 0.f;
            for (int k = 0; k < 20; ++k) {
                float nx = nb[k * 3], ny = nb[k * 3 + 1], nz = nb[k * 3 + 2];
                float dx = nx - cx, dy = ny - cy, dz = nz - cz;
                float crx = ny * cz - nz * cy;
                float cry = nz * cx - nx * cz;
                float crz = nx * cy - ny * cx;
                float p0 = wa0 * dx + wa1 * cx + wa2 * crx;
                float p1 = wa0 * dy + wa1 * cy + wa2 * cry;
                float p2 = wa0 * dz + wa1 * cz + wa2 * crz;
                float d0 = wb0 * dx + wb1 * cx + wb2 * crx;
                float d1 = wb0 * dy + wb1 * cy + wb2 * cry;
                float d2 = wb0 * dz + wb1 * cz + wb2 * crz;
                float nrm = sqrtf(p0 * p0 + p1 * p1 + p2 * p2) + 1e-6f;
                float nbv = gs * (nrm - m) + bb;
                float sc = nbv / nrm;
                p0 *= sc; p1 *= sc; p2 *= sc;
                float dot = p0 * d0 + p1 * d1 + p2 * d2;
                float dsq = d0 * d0 + d1 * d1 + d2 * d2 + 1e-6f;
                float tq = fminf(dot, 0.f) / dsq;
                a0 += 0.2f * p0 + 0.8f * (p0 - tq * d0);
                a1 += 0.2f * p1 + 0.8f * (p1 - tq * d1);
                a2 += 0.2f * p2 + 0.8f * (p2 - tq * d2);
            }
            float o0 = a0 / 20.0f, o1 = a1 / 20.0f, o2 = a2 / 20.0f;
            x0[((size_t)(b * 42 + o) * 3 + 0) * NTOT + n] = o0;
            x0[((size_t)(b * 42 + o) * 3 + 1) * NTOT + n] = o1;
            x0[((size_t)(b * 42 + o) * 3 + 2) * NTOT + n] = o2;
            colout[ps][o * 3 + 0] = o0;
            colout[ps][o * 3 + 1] = o1;
            colout[ps][o * 3 + 2] = o2;
        }
        __syncthreads();
        if (valid) {
            const float* wr = wf1 + o * 42;
            const float* cl = colout[ps];
            float p0 = 0.f, p1 = 0.f, p2 = 0.f;
            for (int c = 0; c < 42; ++c) {
                float w = wr[c];
                p0 += w * cl[3 * c]; p1 += w * cl[3 * c + 1]; p2 += w * cl[3 * c + 2];
            }
            float nrm = sqrtf(p0 * p0 + p1 * p1 + p2 * p2) + 1e-6f;
            s1 += (double)nrm; s2 += (double)(nrm * nrm);
        }
    }
    if (active) { red[0][ps][o] = s1; red[1][ps][o] = s2; }
    __syncthreads();
    if (t < 42) {
        double a = 0.0, a2 = 0.0;
#pragma unroll
        for (int p = 0; p < 6; ++p) { a += red[0][p][t]; a2 += red[1][p][t]; }
        atomicAdd(&stats1[t], a);
        atomicAdd(&stats1[42 + t], a2);
    }
}

// ============================ generic VN stats (packed (ps,o)) ================
template <int Ci, int Co, int PTS, int NT, int NIT>
__global__ __launch_bounds__(NT)
void vn_stats_kernel(const float* __restrict__ xin,
                     const float* __restrict__ wf,
                     double* __restrict__ stats, int Npts)
{
    constexpr int Ci3 = Ci * 3;
    constexpr int STRIDE = Ci3 + 1;
    __shared__ float col[PTS * STRIDE];
    __shared__ double red[2][PTS][Co];
    int t = threadIdx.x;
    int b = blockIdx.y;
    int ps = t / Co;
    int o = t - ps * Co;
    bool active = ps < PTS;
    double s = 0.0, s2 = 0.0;
    int base = blockIdx.x * (PTS * NIT);
    for (int it = 0; it < NIT; ++it) {
        int pt0 = base + it * PTS;
        __syncthreads();
        for (int i = t; i < PTS * Ci3; i += NT) {
            int pl = i / Ci3, off = i - pl * Ci3;
            int pt = pt0 + pl; if (pt >= Npts) pt = Npts - 1;
            col[pl * STRIDE + off] = xin[(size_t)(b * 3 * Ci + off) * Npts + pt];
        }
        __syncthreads();
        if (active && pt0 + ps < Npts) {
            const float* cl = &col[ps * STRIDE];
            const float* wr = wf + o * Ci;
            float p0 = 0.f, p1 = 0.f, p2 = 0.f;
#pragma unroll
            for (int c = 0; c < Ci; ++c) {
                float w = wr[c];
                p0 += w * cl[3 * c]; p1 += w * cl[3 * c + 1]; p2 += w * cl[3 * c + 2];
            }
            float nrm = sqrtf(p0 * p0 + p1 * p1 + p2 * p2) + 1e-6f;
            s += (double)nrm; s2 += (double)nrm * (double)nrm;
        }
    }
    if (active) { red[0][ps][o] = s; red[1][ps][o] = s2; }
    __syncthreads();
    if (t < Co) {
        double a = 0.0, a2 = 0.0;
#pragma unroll
        for (int p = 0; p < PTS; ++p) { a += red[0][p][t]; a2 += red[1][p][t]; }
        atomicAdd(&stats[t], a);
        atomicAdd(&stats[Co + t], a2);
    }
}

// ========= VN apply (packed (ps,o); optional transposed out; optional fused
//           next-stage stats when CoN>0, requires CoN == Co packing) =========
template <int Ci, int Co, int PTS, int NT, int NIT, bool WT, int CoN>
__global__ __launch_bounds__(NT)
void vn_apply_kernel(const float* __restrict__ xin,
                     const float* __restrict__ wf,
                     const float* __restrict__ wd,
                     const float* __restrict__ g,
                     const float* __restrict__ bbp,
                     const double* __restrict__ stats,
                     double count, int Npts,
                     float* __restrict__ xout,
                     float* __restrict__ xt,
                     const float* __restrict__ wfn,
                     double* __restrict__ statsn)
{
    constexpr int Ci3 = Ci * 3;
    constexpr int STRIDE = Ci3 + 1;
    constexpr int CH = Co * 3;
    __shared__ float col[PTS * STRIDE];
    __shared__ float colout[(CoN > 0) ? PTS * (CH + 1) : 1];
    __shared__ double redn[(CoN > 0) ? 2 * PTS * CoN : 1];
    int t = threadIdx.x;
    int b = blockIdx.y;
    int ps = t / Co;
    int o = t - ps * Co;
    bool active = ps < PTS;
    float m = 0.f, gs = 0.f, bb = 0.f;
    if (active) {
        double S1 = stats[o], S2 = stats[Co + o];
        double md = S1 / count;
        m = (float)md;
        float var = (float)(S2 / count - md * md);
        gs = g[o] / sqrtf(var + 1e-5f);
        bb = bbp[o];
    }
    double sn1 = 0.0, sn2 = 0.0;
    for (int itn = 0; itn < NIT; ++itn) {
        int pt0 = (blockIdx.x * NIT + itn) * PTS;
        __syncthreads();
        for (int i = t; i < PTS * Ci3; i += NT) {
            int pl = i / Ci3, off = i - pl * Ci3;
            int pt = pt0 + pl; if (pt >= Npts) pt = Npts - 1;
            col[pl * STRIDE + off] = xin[(size_t)(b * 3 * Ci + off) * Npts + pt];
        }
        __syncthreads();
        int pt = pt0 + ps;
        bool valid = active && pt < Npts;
        if (valid) {
            const float* cl = &col[ps * STRIDE];
            const float* wr = wf + o * Ci;
            const float* wdr = wd + o * Ci;
            float p0 = 0.f, p1 = 0.f, p2 = 0.f, d0 = 0.f, d1 = 0.f, d2 = 0.f;
#pragma unroll
            for (int c = 0; c < Ci; ++c) {
                float c0 = cl[3 * c], c1 = cl[3 * c + 1], c2 = cl[3 * c + 2];
                float w = wr[c];
                p0 += w * c0; p1 += w * c1; p2 += w * c2;
                float w2 = wdr[c];
                d0 += w2 * c0; d1 += w2 * c1; d2 += w2 * c2;
            }
            float nrm = sqrtf(p0 * p0 + p1 * p1 + p2 * p2) + 1e-6f;
            float nb = gs * (nrm - m) + bb;
            float sc = nb / nrm;
            p0 *= sc; p1 *= sc; p2 *= sc;
            float dot = p0 * d0 + p1 * d1 + p2 * d2;
            float dsq = d0 * d0 + d1 * d1 + d2 * d2 + 1e-6f;
            float tq = fminf(dot, 0.f) / dsq;
            float r0 = p0 - tq * d0, r1 = p1 - tq * d1, r2 = p2 - tq * d2;
            float o0 = 0.2f * p0 + 0.8f * r0;
            float o1 = 0.2f * p1 + 0.8f * r1;
            float o2 = 0.2f * p2 + 0.8f * r2;
            xout[((size_t)(b * Co + o) * 3 + 0) * Npts + pt] = o0;
            xout[((size_t)(b * Co + o) * 3 + 1) * Npts + pt] = o1;
            xout[((size_t)(b * Co + o) * 3 + 2) * Npts + pt] = o2;
            if (WT) {
                float* tp = xt + ((size_t)(b * Npts + pt)) * CH + o * 3;
                tp[0] = o0; tp[1] = o1; tp[2] = o2;
            }
            if constexpr (CoN > 0) {
                colout[ps * (CH + 1) + o * 3 + 0] = o0;
                colout[ps * (CH + 1) + o * 3 + 1] = o1;
                colout[ps * (CH + 1) + o * 3 + 2] = o2;
            }
        }
        if constexpr (CoN > 0) {
            __syncthreads();
            if (valid) {
                const float* wrn = wfn + o * Co;
                const float* cl2 = &colout[ps * (CH + 1)];
                float p0 = 0.f, p1 = 0.f, p2 = 0.f;
#pragma unroll
                for (int c = 0; c < Co; ++c) {
                    float w = wrn[c];
                    p0 += w * cl2[3 * c]; p1 += w * cl2[3 * c + 1]; p2 += w * cl2[3 * c + 2];
                }
                float nrm = sqrtf(p0 * p0 + p1 * p1 + p2 * p2) + 1e-6f;
                sn1 += (double)nrm; sn2 += (double)(nrm * nrm);
            }
        }
    }
    if constexpr (CoN > 0) {
        if (active) {
            redn[(0 * PTS + ps) * CoN + o] = sn1;
            redn[(1 * PTS + ps) * CoN + o] = sn2;
        }
        __syncthreads();
        if (t < CoN) {
            double a = 0.0, a2 = 0.0;
#pragma unroll
            for (int p = 0; p < PTS; ++p) {
                a  += redn[(0 * PTS + p) * CoN + t];
                a2 += redn[(1 * PTS + p) * CoN + t];
            }
            atomicAdd(&statsn[t], a);
            atomicAdd(&statsn[CoN + t], a2);
        }
    }
}

// ============================ VN max-pool-down (point-major gather) ==========
// NOTE: keep fp contract OFF here — argmax selection over dots.
__global__ void vn_pool_kernel(const float* __restrict__ xint,
                               const int* __restrict__ idx, long long sb, int sq,
                               const float* __restrict__ wp,
                               float* __restrict__ xout,
                               int C, int Np, int Nq)
{
#pragma clang fp contract(off)
    __shared__ float nb[4 * 84 * 3];
    int b = blockIdx.y;
    int q = blockIdx.x;
    const int* ir = idx + b * sb + (long long)q * sq;
    int CH = C * 3;
    for (int kk = 0; kk < 4; ++kk) {
        int mm = ir[kk];
        const float* src = xint + ((size_t)(b * Np + mm)) * CH;
        for (int t = threadIdx.x; t < CH; t += blockDim.x)
            nb[kk * CH + t] = src[t];
    }
    __syncthreads();
    int o = threadIdx.x;
    if (o >= C) return;
    const float* wr = wp + o * C;
    float best = -3.4e38f;
    int bk = 0;
    for (int kk = 0; kk < 4; ++kk) {
        const float* cl = &nb[kk * CH];
        float d0 = 0.f, d1 = 0.f, d2 = 0.f;
        for (int c = 0; c < C; ++c) {
            float w = wr[c];
            d0 += w * cl[3 * c]; d1 += w * cl[3 * c + 1]; d2 += w * cl[3 * c + 2];
        }
        float dot = cl[o * 3] * d0 + cl[o * 3 + 1] * d1 + cl[o * 3 + 2] * d2;
        if (dot > best) { best = dot; bk = kk; }
    }
    const float* cb = &nb[bk * CH];
    xout[((size_t)(b * C + o) * 3 + 0) * Nq + q] = cb[o * 3];
    xout[((size_t)(b * C + o) * 3 + 1) * Nq + q] = cb[o * 3 + 1];
    xout[((size_t)(b * C + o) * 3 + 2) * Nq + q] = cb[o * 3 + 2];
}

// ============================ eqv assembly + fused mean partial ==============
__global__ void eqv_kernel(const float* __restrict__ x0, const float* __restrict__ x1,
                           const float* __restrict__ x2, const float* __restrict__ x3,
                           const float* __restrict__ x4,
                           const int* __restrict__ i1, const int* __restrict__ i2,
                           float* __restrict__ out_eqv, float* __restrict__ mfw)
{
    __shared__ float wsum[4];
    int n = blockIdx.x * 256 + threadIdx.x;
    int cv = blockIdx.y;
    int b = blockIdx.z;
    int cc = cv / 3, v = cv % 3;
    float val;
    if (cc < 42)
        val = x0[((size_t)(b * 42 + cc) * 3 + v) * NTOT + n];
    else if (cc < 84)
        val = x1[((size_t)(b * 42 + (cc - 42)) * 3 + v) * NTOT + n];
    else if (cc < 168) {
        int m = i1[b * NTOT + n];
        val = x2[((size_t)(b * 84 + (cc - 84)) * 3 + v) * 512 + m];
    } else if (cc < 252) {
        int m = i1[b * NTOT + n];
        val = x3[((size_t)(b * 84 + (cc - 168)) * 3 + v) * 512 + m];
    } else {
        int m = i2[b * NTOT + n];
        val = x4[((size_t)(b * 168 + (cc - 252)) * 3 + v) * 128 + m];
    }
    out_eqv[((size_t)(b * 1260 + cv)) * NTOT + n] = val;
    float s = val;
    for (int off = 32; off; off >>= 1) s += __shfl_down(s, off);
    if ((threadIdx.x & 63) == 0) wsum[threadIdx.x >> 6] = s;
    __syncthreads();
    if (threadIdx.x == 0)
        atomicAdd(&mfw[b * 1260 + cv], (wsum[0] + wsum[1]) + (wsum[2] + wsum[3]));
}

// ===== zhead: mf_finalize + z1 + z2 + z3 + inv_gl fused (grid = BTOT) ========
__global__ __launch_bounds__(256)
void zhead_kernel(float* __restrict__ mfw, float* __restrict__ out_mf,
                  const float* __restrict__ wv1f, const float* __restrict__ wv1d,
                  const float* __restrict__ wv2f, const float* __restrict__ wv2d,
                  const float* __restrict__ w3,
                  float* __restrict__ invgl_ws, float* __restrict__ out_invgl)
{
    __shared__ float mf[1260];
    __shared__ float z1l[630];
    __shared__ float z2l[252];
    __shared__ float z3l[6];
    int b = blockIdx.x;
    int t = threadIdx.x;
    for (int i = t; i < 1260; i += 256) {
        float m = mfw[b * 1260 + i] / 2048.0f;
        mfw[b * 1260 + i] = m;
        out_mf[b * 1260 + i] = m;
        mf[i] = m;
    }
    __syncthreads();
    if (t < 210) {
        const float* wr  = wv1f + (size_t)t * 420;
        const float* wdr = wv1d + (size_t)t * 420;
        float p0 = 0.f, p1 = 0.f, p2 = 0.f, d0 = 0.f, d1 = 0.f, d2 = 0.f;
        for (int c = 0; c < 420; ++c) {
            float m0 = mf[3 * c], m1 = mf[3 * c + 1], m2 = mf[3 * c + 2];
            float w = wr[c];
            p0 += w * m0; p1 += w * m1; p2 += w * m2;
            float w2 = wdr[c];
            d0 += w2 * m0; d1 += w2 * m1; d2 += w2 * m2;
        }
        float dot = p0 * d0 + p1 * d1 + p2 * d2;
        float dsq = d0 * d0 + d1 * d1 + d2 * d2 + 1e-6f;
        float tq = fminf(dot, 0.f) / dsq;
        z1l[t * 3 + 0] = 0.2f * p0 + 0.8f * (p0 - tq * d0);
        z1l[t * 3 + 1] = 0.2f * p1 + 0.8f * (p1 - tq * d1);
        z1l[t * 3 + 2] = 0.2f * p2 + 0.8f * (p2 - tq * d2);
    }
    __syncthreads();
    if (t < 84) {
        const float* wr  = wv2f + (size_t)t * 210;
        const float* wdr = wv2d + (size_t)t * 210;
        float p0 = 0.f, p1 = 0.f, p2 = 0.f, d0 = 0.f, d1 = 0.f, d2 = 0.f;
        for (int c = 0; c < 210; ++c) {
            float m0 = z1l[3 * c], m1 = z1l[3 * c + 1], m2 = z1l[3 * c + 2];
            float w = wr[c];
            p0 += w * m0; p1 += w * m1; p2 += w * m2;
            float w2 = wdr[c];
            d0 += w2 * m0; d1 += w2 * m1; d2 += w2 * m2;
        }
        float dot = p0 * d0 + p1 * d1 + p2 * d2;
        float dsq = d0 * d0 + d1 * d1 + d2 * d2 + 1e-6f;
        float tq = fminf(dot, 0.f) / dsq;
        z2l[t * 3 + 0] = 0.2f * p0 + 0.8f * (p0 - tq * d0);
        z2l[t * 3 + 1] = 0.2f * p1 + 0.8f * (p1 - tq * d1);
        z2l[t * 3 + 2] = 0.2f * p2 + 0.8f * (p2 - tq * d2);
    }
    __syncthreads();
    if (t < 6) {
        int v = t / 2, kt = t % 2;
        float s = 0.f;
        for (int c = 0; c < 84; ++c) s += z2l[c * 3 + v] * w3[kt * 84 + c];
        z3l[v * 2 + kt] = s;
    }
    __syncthreads();
    for (int i = t; i < 840; i += 256) {
        int ii = i / 2, kt = i % 2;
        float s = mf[ii * 3] * z3l[0 + kt] + mf[ii * 3 + 1] * z3l[2 + kt] +
                  mf[ii * 3 + 2] * z3l[4 + kt];
        invgl_ws[b * 840 + i] = s;
        out_invgl[b * 840 + i] = s;
    }
}

// ============================ conv1 factored coefficients (wave-per-o) =======
__global__ __launch_bounds__(256)
void conv1_coef_kernel(const float* __restrict__ ws1,
                       const float* __restrict__ invgl,
                       const float* __restrict__ mfw,
                       const int* __restrict__ cat,
                       float* __restrict__ cb, float* __restrict__ ab,
                       float* __restrict__ w0)
{
    int wave = threadIdx.x >> 6, lane = threadIdx.x & 63;
    int o = blockIdx.x * 4 + wave;           // 0..1023
    int b = blockIdx.y;
    const float* wr = ws1 + (size_t)o * 1267;
    float s = 0.f;
    for (int j = lane; j < 840; j += 64)
        s += wr[1 + j] * invgl[b * 840 + j];
    float a0 = 0.f, a1 = 0.f, a2 = 0.f;
    for (int i = lane; i < 420; i += 64) {
        float w = wr[841 + i];
        a0 += w * mfw[b * 1260 + i * 3];
        a1 += w * mfw[b * 1260 + i * 3 + 1];
        a2 += w * mfw[b * 1260 + i * 3 + 2];
    }
    for (int off = 32; off; off >>= 1) {
        s  += __shfl_down(s, off);
        a0 += __shfl_down(a0, off);
        a1 += __shfl_down(a1, off);
        a2 += __shfl_down(a2, off);
    }
    if (lane == 0) {
        cb[b * 1024 + o] = s + wr[1261 + cat[b]];
        ab[((size_t)(b * 1024 + o)) * 3 + 0] = a0;
        ab[((size_t)(b * 1024 + o)) * 3 + 1] = a1;
        ab[((size_t)(b * 1024 + o)) * 3 + 2] = a2;
        if (b == 0) w0[o] = wr[0];
    }
}

// ============================ y1 stats (no y1t materialization) ==============
__global__ __launch_bounds__(256)
void y1_stats_kernel(const float* __restrict__ cb, const float* __restrict__ ab,
                     const float* __restrict__ w0, const float* __restrict__ coord,
                     const float* __restrict__ normv, float* __restrict__ cst)
{
    __shared__ float px[256], py[256], pz[256], pn[256];
    int t = threadIdx.x;
    int o = blockIdx.x * 256 + t;
    int b = blockIdx.y >> 3;
    int n0 = (blockIdx.y & 7) * 256;
    px[t] = coord[(b * 3 + 0) * NTOT + n0 + t];
    py[t] = coord[(b * 3 + 1) * NTOT + n0 + t];
    pz[t] = coord[(b * 3 + 2) * NTOT + n0 + t];
    pn[t] = normv[b * NTOT + n0 + t];
    __syncthreads();
    size_t bo = (size_t)(b * 1024 + o);
    float c0 = cb[bo];
    float a0 = ab[bo * 3], a1 = ab[bo * 3 + 1], a2 = ab[bo * 3 + 2];
    float wn = w0[o];
    float s = 0.f, s2 = 0.f;
    for (int k = 0; k < 256; ++k) {
        float v = c0 + a0 * px[k] + a1 * py[k] + a2 * pz[k] + wn * pn[k];
        s += v; s2 += v * v;
    }
    atomicAdd(&cst[o], s);
    atomicAdd(&cst[1024 + o], s2);
}

// ============================ y1 BN+ReLU generator -> bf16 ====================
__global__ __launch_bounds__(256)
void y1_bnrelu_kernel(const float* __restrict__ cb, const float* __restrict__ ab,
                      const float* __restrict__ w0, const float* __restrict__ coord,
                      const float* __restrict__ normv, const float* __restrict__ cst,
                      const float* __restrict__ sg, const float* __restrict__ sb,
                      unsigned short* __restrict__ y1b)
{
    __shared__ float px[256], py[256], pz[256], pn[256];
    int t = threadIdx.x;
    int o = blockIdx.x * 256 + t;
    int b = blockIdx.y >> 3;
    int n0 = (blockIdx.y & 7) * 256;
    px[t] = coord[(b * 3 + 0) * NTOT + n0 + t];
    py[t] = coord[(b * 3 + 1) * NTOT + n0 + t];
    pz[t] = coord[(b * 3 + 2) * NTOT + n0 + t];
    pn[t] = normv[b * NTOT + n0 + t];
    __syncthreads();
    size_t bo = (size_t)(b * 1024 + o);
    float c0 = cb[bo];
    float a0 = ab[bo * 3], a1 = ab[bo * 3 + 1], a2 = ab[bo * 3 + 2];
    float wn = w0[o];
    float mm = cst[o] * (1.f / 8192.f);
    float var = cst[1024 + o] * (1.f / 8192.f) - mm * mm;
    float sc = sg[o] / sqrtf(var + 1e-5f);
    float bs = sb[o] - mm * sc;
    size_t rowbase = (size_t)(b * NTOT + n0) * 1024 + o;
    for (int k = 0; k < 256; ++k) {
        float v = c0 + a0 * px[k] + a1 * py[k] + a2 * pz[k] + wn * pn[k];
        float r = sc * v + bs;
        y1b[rowbase + (size_t)k * 1024] = f2b(r > 0.f ? r : 0.f);
    }
}

// ============================ weight convert f32 -> bf16 ============================
__global__ void wconv_kernel(const float* __restrict__ src, unsigned short* __restrict__ dst,
                             int Msrc, int Ksrc, int Kpad)
{
    int k = blockIdx.x * 256 + threadIdx.x;
    int o = blockIdx.y;
    float v = (o < Msrc && k < Ksrc) ? src[(size_t)o * Ksrc + k] : 0.f;
    dst[(size_t)o * Kpad + k] = f2b(v);
}

// ============================ MFMA GEMM 64x64/BK64 (+fused col BN stats) =====
__global__ __launch_bounds__(256)
void gemm_mfma_kernel(const unsigned short* __restrict__ A,
                      const unsigned short* __restrict__ Bw,
                      float* __restrict__ C, float* __restrict__ st,
                      int K, int Mreal)
{
    __shared__ __align__(16) unsigned short Al[64 * 72];
    __shared__ __align__(16) unsigned short Bl[64 * 72];
    __shared__ float sst[64], sst2[64];
    int t = threadIdx.x;
    if (t < 64) { sst[t] = 0.f; sst2[t] = 0.f; }
    int r0 = blockIdx.x * 64;
    int c0 = blockIdx.y * 64;
    int w = t >> 6, l = t & 63;
    int wm = w & 1, wn = w >> 1;
    int lm = l & 15, lq = l >> 4;
    f32x4 acc[2][2] = {};
    for (int k0 = 0; k0 < K; k0 += 64) {
#pragma unroll
        for (int half = 0; half < 2; ++half) {
            int ch = t + half * 256;
            int row = ch >> 3, kc = ch & 7;
            *(uint4*)&Al[row * 72 + kc * 8] =
                *(const uint4*)&A[(size_t)(r0 + row) * K + k0 + kc * 8];
            *(uint4*)&Bl[row * 72 + kc * 8] =
                *(const uint4*)&Bw[(size_t)(c0 + row) * K + k0 + kc * 8];
        }
        __syncthreads();
        bf16x8 af[2][2], bfr[2][2];
#pragma unroll
        for (int kk = 0; kk < 2; ++kk) {
#pragma unroll
            for (int i = 0; i < 2; ++i)
                af[kk][i] = *(const bf16x8*)&Al[(wm * 32 + i * 16 + lm) * 72 + kk * 32 + lq * 8];
#pragma unroll
            for (int j = 0; j < 2; ++j)
                bfr[kk][j] = *(const bf16x8*)&Bl[(wn * 32 + j * 16 + lm) * 72 + kk * 32 + lq * 8];
        }
#pragma unroll
        for (int kk = 0; kk < 2; ++kk)
#pragma unroll
            for (int i = 0; i < 2; ++i)
#pragma unroll
                for (int j = 0; j < 2; ++j)
                    acc[i][j] = __builtin_amdgcn_mfma_f32_16x16x32_bf16(
                        af[kk][i], bfr[kk][j], acc[i][j], 0, 0, 0);
        __syncthreads();
    }
#pragma unroll
    for (int i = 0; i < 2; ++i) {
#pragma unroll
        for (int j = 0; j < 2; ++j) {
            int col = c0 + wn * 32 + j * 16 + lm;
            if (col < Mreal) {
                int rbase = r0 + wm * 32 + i * 16 + lq * 4;
#pragma unroll
                for (int r = 0; r < 4; ++r)
                    C[(size_t)(rbase + r) * Mreal + col] = acc[i][j][r];
            }
        }
    }
#pragma unroll
    for (int j = 0; j < 2; ++j) {
        float s = 0.f, s2 = 0.f;
#pragma unroll
        for (int i = 0; i < 2; ++i)
#pragma unroll
            for (int r = 0; r < 4; ++r) { float x = acc[i][j][r]; s += x; s2 += x * x; }
        s  += __shfl_down(s, 32);  s  += __shfl_down(s, 16);
        s2 += __shfl_down(s2, 32); s2 += __shfl_down(s2, 16);
        if (l < 16) {
            int cc = wn * 32 + j * 16 + lm;
            atomicAdd(&sst[cc], s);
            atomicAdd(&sst2[cc], s2);
        }
    }
    __syncthreads();
    if (t < 64) {
        int col = c0 + t;
        if (col < Mreal) {
            atomicAdd(&st[col], sst[t]);
            atomicAdd(&st[Mreal + col], sst2[t]);
        }
    }
}

// ============================ BN+ReLU -> bf16 ============================
__global__ void bnreluT_kernel(const float* __restrict__ Ct, const float* __restrict__ st,
                               const float* __restrict__ g, const float* __restrict__ be,
                               unsigned short* __restrict__ outb, int M, int maskM)
{
    size_t idx = (size_t)blockIdx.x * 256 + threadIdx.x;
    int o = (int)(idx & (size_t)maskM);
    float m = st[o] * (1.f / 8192.f);
    float var = st[M + o] * (1.f / 8192.f) - m * m;
    float sqv = sqrtf(var + 1e-5f);
    float v = g[o] * (Ct[idx] - m) / sqv + be[o];
    outb[idx] = f2b(v > 0.f ? v : 0.f);
}

// ============================ final BN+ReLU + transpose ============================
__global__ void bnrelu_outT_kernel(const float* __restrict__ Ct, const float* __restrict__ st,
                                   const float* __restrict__ g, const float* __restrict__ be,
                                   float* __restrict__ outinv)
{
    __shared__ float tile[64][65];
    int t = threadIdx.x;
    int r0 = blockIdx.x * 64;
    int o0 = blockIdx.y * 64;
    int b = r0 >> 11, n0 = r0 & 2047;
    int oi = t & 63;
    int o = o0 + oi;
    float m = 0.f, sqv = 1.f, gg = 0.f, bb = 0.f;
    if (o < 420) {
        m = st[o] * (1.f / 8192.f);
        float var = st[420 + o] * (1.f / 8192.f) - m * m;
        sqv = sqrtf(var + 1e-5f);
        gg = g[o]; bb = be[o];
    }
    for (int it = 0; it < 16; ++it) {
        int rr = it * 4 + (t >> 6);
        float v = 0.f;
        if (o < 420) {
            v = gg * (Ct[(size_t)(r0 + rr) * 420 + o] - m) / sqv + bb;
            v = v > 0.f ? v : 0.f;
        }
        tile[rr][oi] = v;
    }
    __syncthreads();
    for (int it = 0; it < 16; ++it) {
        int oc = it * 4 + (t >> 6);
        int oo = o0 + oc;
        if (oo < 420)
            outinv[((size_t)(b * 420 + oo)) * 2048 + n0 + (t & 63)] = tile[t & 63][oc];
    }
}

// ============================ launch ============================
extern "C" void kernel_launch(void* const* d_in, const int* in_sizes, int n_in,
                              void* d_out, int out_size, void* d_ws, size_t ws_size,
                              hipStream_t stream)
{
    (void)in_sizes; (void)n_in; (void)out_size; (void)ws_size;
    const float* xc   = (const float*)d_in[0];
    const float* normv= (const float*)d_in[1];
    const int*   cat  = (const int*)d_in[2];
    const float* wf0  = (const float*)d_in[3];
    const float* wd0  = (const float*)d_in[4];
    const float* g0   = (const float*)d_in[5];
    const float* b0   = (const float*)d_in[6];
    const float* wf1  = (const float*)d_in[7];
    const float* wd1  = (const float*)d_in[8];
    const float* g1   = (const float*)d_in[9];
    const float* b1   = (const float*)d_in[10];
    const float* wp1  = (const float*)d_in[11];
    const float* wf2  = (const float*)d_in[12];
    const float* wd2  = (const float*)d_in[13];
    const float* g2   = (const float*)d_in[14];
    const float* b2   = (const float*)d_in[15];
    const float* wf3  = (const float*)d_in[16];
    const float* wd3  = (const float*)d_in[17];
    const float* g3   = (const float*)d_in[18];
    const float* b3   = (const float*)d_in[19];
    const float* wp2  = (const float*)d_in[20];
    const float* wf4  = (const float*)d_in[21];
    const float* wd4  = (const float*)d_in[22];
    const float* g4   = (const float*)d_in[23];
    const float* b4   = (const float*)d_in[24];
    const float* wv1f = (const float*)d_in[25];
    const float* wv1d = (const float*)d_in[26];
    const float* wv2f = (const float*)d_in[27];
    const float* wv2d = (const float*)d_in[28];
    const float* w3   = (const float*)d_in[29];
    const float* ws1  = (const float*)d_in[30];
    const float* sg1  = (const float*)d_in[32];
    const float* sb1  = (const float*)d_in[33];
    const float* ws2  = (const float*)d_in[34];
    const float* sg2  = (const float*)d_in[36];
    const float* sb2  = (const float*)d_in[37];
    const float* ws3  = (const float*)d_in[38];
    const float* sg3  = (const float*)d_in[40];
    const float* sb3  = (const float*)d_in[41];

    float* ws = (float*)d_ws;
    float* out = (float*)d_out;

    int*    idx20 = (int*)(ws + WS_IDX20);
    float*  x1t   = ws + WS_X1T;
    float*  x0    = ws + WS_X0;
    float*  x1    = ws + WS_X1;
    float*  xm2   = ws + WS_XM2;
    float*  x2    = ws + WS_X2;
    float*  x3    = ws + WS_X3;
    int*    idx42 = (int*)(ws + WS_IDX42);
    float*  xm4   = ws + WS_XM4;
    float*  x4    = ws + WS_X4;
    int*    i1p   = (int*)(ws + WS_I1);
    int*    i2p   = (int*)(ws + WS_I2);
    float*  mfw   = ws + WS_MF;
    float*  invgl = ws + WS_INVGL;
    double* st    = (double*)(ws + WS_STATS);
    float*  cst   = ws + WS_CST;
    float*  cb    = ws + WS_CB;
    float*  ab    = ws + WS_AB;
    float*  w0    = ws + WS_W0;
    float*  x3t   = ws + WS_X3T;
    unsigned short* w2b  = (unsigned short*)(ws + WS_W2B);
    unsigned short* w3b  = (unsigned short*)(ws + WS_W3B);
    unsigned short* y1b  = (unsigned short*)(ws + WS_Y1B);
    float*  y2t   = ws + WS_Y2T;
    unsigned short* y2b  = (unsigned short*)(ws + WS_Y2B);
    float*  y3t   = ws + WS_Y3T;

    // single memset covers mfw + invgl + stats + cst (contiguous span)
    hipMemsetAsync((void*)mfw, 0, ZERO_SPAN_BYTES, stream);

    // weight conversions (independent)
    wconv_kernel<<<dim3(4, 512), 256, 0, stream>>>(ws2, w2b, 512, 1024, 1024);
    wconv_kernel<<<dim3(2, 512), 256, 0, stream>>>(ws3, w3b, 420, 512, 512);

    // KNN-20: 2 queries per wave
    knn_reg_kernel<32, 20, 2><<<dim3(256, 4), 256, 0, stream>>>(xc, 1, 1, idx20, 2048);

    // stage 0 (surf features fused) — apply0 also produces ST1 stats
    stats0_kernel<<<dim3(43, 4), 256, 0, stream>>>(xc, idx20, wf0, st + ST0_OFF);
    apply0_kernel<<<dim3(43, 4), 256, 0, stream>>>(xc, idx20, wf0, wd0, g0, b0,
                                                   st + ST0_OFF, wf1, st + ST1_OFF, x0);

    // stage 1 apply (reads ST1; emits point-major x1t for pool gather)
    vn_apply_kernel<42, 42, 6, 256, 1, true, 0><<<dim3(342, 4), 256, 0, stream>>>(
        x0, wf1, wd1, g1, b1, st + ST1_OFF, 8192.0, 2048, x1, x1t, nullptr, nullptr);

    // pool 1 (coalesced point-major gather)
    vn_pool_kernel<<<dim3(512, 4), 256, 0, stream>>>(x1t, idx20, 40960LL, 80, wp1, xm2,
                                                     42, 2048, 512);
    // stage 2: stats on xm2, then apply2 with FUSED stage-3 stats
    vn_stats_kernel<42, 84, 3, 256, 8><<<dim3(22, 4), 256, 0, stream>>>(
        xm2, wf2, st + ST2_OFF, 512);
    vn_apply_kernel<42, 84, 3, 256, 8, false, 84><<<dim3(22, 4), 256, 0, stream>>>(
        xm2, wf2, wd2, g2, b2, st + ST2_OFF, 2048.0, 512, x2, nullptr, wf3, st + ST3_OFF);
    // stage 3 apply (reads ST3; emits x3t for pool 2)
    vn_apply_kernel<84, 84, 3, 256, 1, true, 0><<<dim3(171, 4), 256, 0, stream>>>(
        x2, wf3, wd3, g3, b3, st + ST3_OFF, 2048.0, 512, x3, x3t, nullptr, nullptr);

    // knn-4 on coord2 (cands stride 4, queries stride 16)
    knn_reg_kernel<8, 4, 1><<<dim3(32, 4), 256, 0, stream>>>(xc, 4, 16, idx42, 128);
    vn_pool_kernel<<<dim3(128, 4), 256, 0, stream>>>(x3t, idx42, 512LL, 4, wp2, xm4,
                                                     84, 512, 128);
    // stage 4
    vn_stats_kernel<84, 168, 3, 512, 4><<<dim3(11, 4), 512, 0, stream>>>(
        xm4, wf4, st + ST4_OFF, 128);
    vn_apply_kernel<84, 168, 3, 512, 1, false, 0><<<dim3(43, 4), 512, 0, stream>>>(
        xm4, wf4, wd4, g4, b4, st + ST4_OFF, 512.0, 128, x4, nullptr, nullptr, nullptr);

    // nearest-neighbor upsample indices (i1 + i2 from one scan)
    nearest_dual_kernel<<<dim3(512, 4), 256, 0, stream>>>(xc, i1p, i2p);

    // eqv (output 0) with fused mean partials
    eqv_kernel<<<dim3(8, 1260, 4), 256, 0, stream>>>(x0, x1, x2, x3, x4, i1p, i2p,
                                                     out + OUT_EQV, mfw);
    // mf_finalize + z1 + z2 + z3 + inv_gl in one kernel (outputs 1 and 3)
    zhead_kernel<<<4, 256, 0, stream>>>(mfw, out + OUT_MF, wv1f, wv1d, wv2f, wv2d,
                                        w3, invgl, out + OUT_INVGL);

    // invariant branch: conv1 factored (wave-per-(b,o), coalesced)
    conv1_coef_kernel<<<dim3(256, 4), 256, 0, stream>>>(ws1, invgl, mfw, cat, cb, ab, w0);
    // y1: stats pass + BN/ReLU regenerate pass (y1t never materialized)
    y1_stats_kernel<<<dim3(4, 32), 256, 0, stream>>>(cb, ab, w0, xc, normv,
                                                     cst + CST1_OFF);
    y1_bnrelu_kernel<<<dim3(4, 32), 256, 0, stream>>>(cb, ab, w0, xc, normv,
                                                      cst + CST1_OFF, sg1, sb1, y1b);

    gemm_mfma_kernel<<<dim3(128, 8), 256, 0, stream>>>(y1b, w2b, y2t, cst + CST2_OFF,
                                                       1024, 512);
    bnreluT_kernel<<<16384, 256, 0, stream>>>(y2t, cst + CST2_OFF, sg2, sb2, y2b,
                                              512, 511);

    gemm_mfma_kernel<<<dim3(128, 7), 256, 0, stream>>>(y2b, w3b, y3t, cst + CST3_OFF,
                                                       512, 420);
    bnrelu_outT_kernel<<<dim3(128, 7), 256, 0, stream>>>(y3t, cst + CST3_OFF, sg3, sb3,
                                                         out + OUT_INV);
}

// Round 8
// 582.733 us; speedup vs baseline: 1.1248x; 1.1248x over previous
//
#include <hip/hip_runtime.h>
#include <hip/hip_bf16.h>
#include <cstdint>
#include <cstddef>

#define NTOT 2048
#define BTOT 4

typedef short bf16x8 __attribute__((ext_vector_type(8)));
typedef float f32x4 __attribute__((ext_vector_type(4)));

__device__ inline unsigned short f2b(float v) {
    __hip_bfloat16 h = __float2bfloat16(v);
    return *reinterpret_cast<unsigned short*>(&h);
}

// ---------------- workspace layout (float-element offsets) ----------------
static const size_t WS_IDX20 = 0;                       // int[163840]
static const size_t WS_X1T   = 163840;                  // float[1032192] (B,2048,126) pool1 gather copy
static const size_t WS_X0    = 1638400;                 // float[2064384] (B,42,3,2048)
static const size_t WS_X1    = 3702784;                 // float[2064384]
static const size_t WS_XM2   = 5767168;                 // float[258048]
static const size_t WS_X2    = 6025216;                 // float[516096]
static const size_t WS_X3    = 6541312;                 // float[516096]
static const size_t WS_IDX42 = 7057408;                 // int[2048]
static const size_t WS_XM4   = 7059456;                 // float[129024]
static const size_t WS_X4    = 7188480;                 // float[258048]
static const size_t WS_I1    = 7446528;                 // int[8192]
static const size_t WS_I2    = 7454720;                 // int[8192]
static const size_t WS_MF    = 7462912;                 // float[5040]
static const size_t WS_INVGL = 7467952;                 // float[3360]
static const size_t WS_STATS = 7471312;                 // double[840] (1680 fl slots)
static const size_t WS_CST   = 7472992;                 // float[3912] conv bn sums
static const size_t WS_CB    = 7480320;                 // float[4096]   cb[b][o]
static const size_t WS_AB    = 7484416;                 // float[12288]  ab[b][o][3]
static const size_t WS_W0    = 7496704;                 // float[1024]   ws1[:,0]
static const size_t WS_Z1    = 7497728;                 // float[2520]   z1[b][210*3]
static const size_t WS_Z2    = 7500288;                 // float[1008]   z2[b][84*3]
static const size_t WS_X3T   = 7501312;                 // float[516096] (B,512,252) pool2 gather copy
                                                        //   (inside Y2T span; lifetime-disjoint: dead before gemm1)
static const size_t WS_W2B   = 13378560;                // ushort[512*1024]
static const size_t WS_W3B   = 13640704;                // ushort[512*512]
static const size_t WS_Y1B   = 0;                       // ushort overlay (written late; x1t dead by then)
static const size_t WS_Y2T   = 7480320;                 // float overlay (CB/AB/Z dead)
static const size_t WS_Y2B   = 4194304;                 // ushort overlay
static const size_t WS_Y3T   = 13771776;                // float overlay

// zero-span: mfw..cst contiguous (mfw 5040 + invgl 3360 + stats 1680 + cst 3912)
#define ZERO_SPAN_BYTES ((7476904 - 7462912) * 4)

#define ST0_OFF 0
#define ST1_OFF 84
#define ST2_OFF 168
#define ST3_OFF 336
#define ST4_OFF 504
#define CST1_OFF 0
#define CST2_OFF 2048
#define CST3_OFF 3072

#define OUT_EQV   0
#define OUT_MF    10321920
#define OUT_INV   10326960
#define OUT_INVGL 13767600

// ============================ KNN v5 (v3 extraction + NQ-query ILP) ==========
// NOTE: fp contract OFF here — distance ordering feeds index selection.
template <int SLOTS, int K, int NQ>
__global__ __launch_bounds__(256)
void knn_reg_kernel(const float* __restrict__ coord, int cand_stride, int q_stride,
                    int* __restrict__ out_idx, int q_cnt)
{
#pragma clang fp contract(off)
    constexpr int Q = SLOTS / 8;
    int b = blockIdx.y;
    int wave = threadIdx.x >> 6, lane = threadIdx.x & 63;
    int qbase = (blockIdx.x * 4 + wave) * NQ;
    if (qbase >= q_cnt) return;
    float qx[NQ], qy[NQ], qz[NQ], xxq[NQ];
#pragma unroll
    for (int u = 0; u < NQ; ++u) {
        int nq = (qbase + u) * q_stride;
        qx[u] = coord[(b * 3 + 0) * NTOT + nq];
        qy[u] = coord[(b * 3 + 1) * NTOT + nq];
        qz[u] = coord[(b * 3 + 2) * NTOT + nq];
        xxq[u] = qx[u] * qx[u] + qy[u] * qy[u] + qz[u] * qz[u];
    }
    float v[NQ][SLOTS];
#pragma unroll
    for (int j = 0; j < SLOTS; ++j) {
        int mo = (lane + 64 * j) * cand_stride;
        float cx = coord[(b * 3 + 0) * NTOT + mo];
        float cy = coord[(b * 3 + 1) * NTOT + mo];
        float cz = coord[(b * 3 + 2) * NTOT + mo];
        float xxc = cx * cx + cy * cy + cz * cz;
#pragma unroll
        for (int u = 0; u < NQ; ++u) {
            float inner = qx[u] * cx + qy[u] * cy + qz[u] * cz;
            v[u][j] = (2.0f * inner - xxq[u]) - xxc;
        }
    }
    float qv[NQ][Q]; int qj[NQ][Q];
#pragma unroll
    for (int u = 0; u < NQ; ++u)
#pragma unroll
        for (int qq = 0; qq < Q; ++qq) {
            float nv = v[u][qq * 8]; int nj = qq * 8;
#pragma unroll
            for (int j = 1; j < 8; ++j)
                if (v[u][qq * 8 + j] > nv) { nv = v[u][qq * 8 + j]; nj = qq * 8 + j; }
            qv[u][qq] = nv; qj[u][qq] = nj;
        }
#pragma clang loop unroll(disable)
    for (int kk = 0; kk < K; ++kk) {
        float bv[NQ]; int bm[NQ];
#pragma unroll
        for (int u = 0; u < NQ; ++u) {
            float tv = qv[u][0]; int tj = qj[u][0];
#pragma unroll
            for (int qq = 1; qq < Q; ++qq)
                if (qv[u][qq] > tv) { tv = qv[u][qq]; tj = qj[u][qq]; }
            bv[u] = tv; bm[u] = lane + 64 * tj;
        }
        // interleaved butterflies: NQ independent chains hide shuffle latency
        for (int off = 32; off; off >>= 1) {
            float ov[NQ]; int om[NQ];
#pragma unroll
            for (int u = 0; u < NQ; ++u) {
                ov[u] = __shfl_down(bv[u], off);
                om[u] = __shfl_down(bm[u], off);
            }
#pragma unroll
            for (int u = 0; u < NQ; ++u)
                if (ov[u] > bv[u] || (ov[u] == bv[u] && om[u] < bm[u])) {
                    bv[u] = ov[u]; bm[u] = om[u];
                }
        }
#pragma unroll
        for (int u = 0; u < NQ; ++u) {
            int m_win = __builtin_amdgcn_readfirstlane(bm[u]);
            if (lane == 0)
                out_idx[((size_t)(b * q_cnt) + qbase + u) * K + kk] = m_win;
            int w_slot = m_win >> 6;
            bool isw = (lane == (m_win & 63));
#pragma unroll
            for (int qq = 0; qq < Q; ++qq) {
                if (qq == (w_slot >> 3)) {
#pragma unroll
                    for (int j = 0; j < 8; ++j)
                        if (qq * 8 + j == w_slot)
                            v[u][qq * 8 + j] = isw ? -3.4e38f : v[u][qq * 8 + j];
                    float nv = v[u][qq * 8]; int nj = qq * 8;
#pragma unroll
                    for (int j = 1; j < 8; ++j)
                        if (v[u][qq * 8 + j] > nv) { nv = v[u][qq * 8 + j]; nj = qq * 8 + j; }
                    qv[u][qq] = nv; qj[u][qq] = nj;
                }
            }
        }
    }
}

// ============================ nearest DUAL (i1 stride-4 + i2 stride-16) ======
__global__ __launch_bounds__(256)
void nearest_dual_kernel(const float* __restrict__ coord,
                         int* __restrict__ out1, int* __restrict__ out2)
{
#pragma clang fp contract(off)
    int b = blockIdx.y;
    int wave = threadIdx.x >> 6, lane = threadIdx.x & 63;
    int n = blockIdx.x * 4 + wave;
    float qx = coord[(b * 3 + 0) * NTOT + n];
    float qy = coord[(b * 3 + 1) * NTOT + n];
    float qz = coord[(b * 3 + 2) * NTOT + n];
    float tt = qx * qx + qy * qy + qz * qz;
    float v[8];
#pragma unroll
    for (int j = 0; j < 8; ++j) {
        int mo = (lane + 64 * j) * 4;
        float cx = coord[(b * 3 + 0) * NTOT + mo];
        float cy = coord[(b * 3 + 1) * NTOT + mo];
        float cz = coord[(b * 3 + 2) * NTOT + mo];
        float inner = qx * cx + qy * cy + qz * cz;
        float ss = cx * cx + cy * cy + cz * cz;
        v[j] = (tt - 2.0f * inner) + ss;
    }
    float bv = v[0];
    int bj = 0;
#pragma unroll
    for (int j = 1; j < 8; ++j)
        if (v[j] < bv) { bv = v[j]; bj = j; }
    int bm = lane + 64 * bj;
    bool has2 = ((lane & 3) == 0);
    float bv2 = 3.4e38f;
    int bm2 = 0x7fffffff;
    if (has2) {
        bv2 = v[0]; bm2 = (lane >> 2);
#pragma unroll
        for (int j = 1; j < 8; ++j) {
            if (v[j] < bv2) { bv2 = v[j]; bm2 = (lane >> 2) + 16 * j; }
        }
    }
    for (int off = 32; off; off >>= 1) {
        float ov = __shfl_down(bv, off);
        int   om = __shfl_down(bm, off);
        if (ov < bv || (ov == bv && om < bm)) { bv = ov; bm = om; }
        float ov2 = __shfl_down(bv2, off);
        int   om2 = __shfl_down(bm2, off);
        if (ov2 < bv2 || (ov2 == bv2 && om2 < bm2)) { bv2 = ov2; bm2 = om2; }
    }
    if (lane == 0) {
        out1[b * NTOT + n] = bm;
        out2[b * NTOT + n] = bm2;
    }
}

// ============================ stage-0 stats (fused surf feature) ==============
__global__ __launch_bounds__(256)
void stats0_kernel(const float* __restrict__ coord, const int* __restrict__ idx20,
                   const float* __restrict__ wf0, double* __restrict__ stats)
{
    __shared__ float nbc[360];   // [6 pts][20 nb][xyz]
    __shared__ float ctr[18];    // [6 pts][xyz]
    __shared__ double red[2][6][42];
    int t = threadIdx.x, b = blockIdx.y;
    int ps = t / 42, o = t - ps * 42;
    bool active = ps < 6;
    float w0 = 0.f, w1 = 0.f, w2 = 0.f;
    if (active) { w0 = wf0[o * 3]; w1 = wf0[o * 3 + 1]; w2 = wf0[o * 3 + 2]; }
    double s = 0.0, s2 = 0.0;
    int base = blockIdx.x * 48;
    for (int it = 0; it < 8; ++it) {
        int n0 = base + it * 6;
        __syncthreads();
        if (t < 120) {
            int pl = t / 20, k = t - pl * 20;
            int n = n0 + pl; if (n > NTOT - 1) n = NTOT - 1;
            int m = idx20[((size_t)(b * NTOT + n)) * 20 + k];
            nbc[t * 3 + 0] = coord[(b * 3 + 0) * NTOT + m];
            nbc[t * 3 + 1] = coord[(b * 3 + 1) * NTOT + m];
            nbc[t * 3 + 2] = coord[(b * 3 + 2) * NTOT + m];
        }
        if (t >= 128 && t < 146) {
            int i = t - 128; int pl = i / 3, vd = i - pl * 3;
            int n = n0 + pl; if (n > NTOT - 1) n = NTOT - 1;
            ctr[i] = coord[(b * 3 + vd) * NTOT + n];
        }
        __syncthreads();
        if (active && n0 + ps < NTOT) {
            float cx = ctr[ps * 3], cy = ctr[ps * 3 + 1], cz = ctr[ps * 3 + 2];
            const float* nb = &nbc[ps * 60];
            float sf = 0.f, sf2 = 0.f;
            for (int k = 0; k < 20; ++k) {
                float nx = nb[k * 3], ny = nb[k * 3 + 1], nz = nb[k * 3 + 2];
                float dx = nx - cx, dy = ny - cy, dz = nz - cz;
                float crx = ny * cz - nz * cy;
                float cry = nz * cx - nx * cz;
                float crz = nx * cy - ny * cx;
                float p0 = w0 * dx + w1 * cx + w2 * crx;
                float p1 = w0 * dy + w1 * cy + w2 * cry;
                float p2 = w0 * dz + w1 * cz + w2 * crz;
                float nrm = sqrtf(p0 * p0 + p1 * p1 + p2 * p2) + 1e-6f;
                sf += nrm; sf2 += nrm * nrm;
            }
            s += (double)sf; s2 += (double)sf2;
        }
    }
    if (active) { red[0][ps][o] = s; red[1][ps][o] = s2; }
    __syncthreads();
    if (t < 42) {
        double a = 0.0, a2 = 0.0;
#pragma unroll
        for (int p = 0; p < 6; ++p) { a += red[0][p][t]; a2 += red[1][p][t]; }
        atomicAdd(&stats[t], a);
        atomicAdd(&stats[42 + t], a2);
    }
}

// ============================ stage-0 apply (fused surf feature) ==============
__global__ __launch_bounds__(256)
void apply0_kernel(const float* __restrict__ coord, const int* __restrict__ idx20,
                   const float* __restrict__ wf0, const float* __restrict__ wd0,
                   const float* __restrict__ g0, const float* __restrict__ b0,
                   const double* __restrict__ stats, float* __restrict__ x0)
{
    __shared__ float nbc[360];
    __shared__ float ctr[18];
    int t = threadIdx.x;
    int b = blockIdx.y;
    int ps = t / 42, o = t - ps * 42;
    int n0 = blockIdx.x * 6;
    if (t < 120) {
        int pl = t / 20, k = t - pl * 20;
        int n = n0 + pl; if (n > NTOT - 1) n = NTOT - 1;
        int m = idx20[((size_t)(b * NTOT + n)) * 20 + k];
        nbc[t * 3 + 0] = coord[(b * 3 + 0) * NTOT + m];
        nbc[t * 3 + 1] = coord[(b * 3 + 1) * NTOT + m];
        nbc[t * 3 + 2] = coord[(b * 3 + 2) * NTOT + m];
    }
    if (t >= 128 && t < 146) {
        int i = t - 128; int pl = i / 3, vd = i - pl * 3;
        int n = n0 + pl; if (n > NTOT - 1) n = NTOT - 1;
        ctr[i] = coord[(b * 3 + vd) * NTOT + n];
    }
    __syncthreads();
    int n = n0 + ps;
    if (ps >= 6 || n >= NTOT) return;
    double S1 = stats[o], S2 = stats[42 + o];
    double md = S1 / 163840.0;
    float m = (float)md;
    float var = (float)(S2 / 163840.0 - md * md);
    float gs = g0[o] / sqrtf(var + 1e-5f);
    float bb = b0[o];
    float wa0 = wf0[o * 3], wa1 = wf0[o * 3 + 1], wa2 = wf0[o * 3 + 2];
    float wb0 = wd0[o * 3], wb1 = wd0[o * 3 + 1], wb2 = wd0[o * 3 + 2];
    float cx = ctr[ps * 3], cy = ctr[ps * 3 + 1], cz = ctr[ps * 3 + 2];
    const float* nb = &nbc[ps * 60];
    float a0 = 0.f, a1 = 0.f, a2 = 0.f;
    for (int k = 0; k < 20; ++k) {
        float nx = nb[k * 3], ny = nb[k * 3 + 1], nz = nb[k * 3 + 2];
        float dx = nx - cx, dy = ny - cy, dz = nz - cz;
        float crx = ny * cz - nz * cy;
        float cry = nz * cx - nx * cz;
        float crz = nx * cy - ny * cx;
        float p0 = wa0 * dx + wa1 * cx + wa2 * crx;
        float p1 = wa0 * dy + wa1 * cy + wa2 * cry;
        float p2 = wa0 * dz + wa1 * cz + wa2 * crz;
        float d0 = wb0 * dx + wb1 * cx + wb2 * crx;
        float d1 = wb0 * dy + wb1 * cy + wb2 * cry;
        float d2 = wb0 * dz + wb1 * cz + wb2 * crz;
        float nrm = sqrtf(p0 * p0 + p1 * p1 + p2 * p2) + 1e-6f;
        float nbv = gs * (nrm - m) + bb;
        float sc = nbv / nrm;
        p0 *= sc; p1 *= sc; p2 *= sc;
        float dot = p0 * d0 + p1 * d1 + p2 * d2;
        float dsq = d0 * d0 + d1 * d1 + d2 * d2 + 1e-6f;
        float tq = fminf(dot, 0.f) / dsq;
        a0 += 0.2f * p0 + 0.8f * (p0 - tq * d0);
        a1 += 0.2f * p1 + 0.8f * (p1 - tq * d1);
        a2 += 0.2f * p2 + 0.8f * (p2 - tq * d2);
    }
    x0[((size_t)(b * 42 + o) * 3 + 0) * NTOT + n] = a0 / 20.0f;
    x0[((size_t)(b * 42 + o) * 3 + 1) * NTOT + n] = a1 / 20.0f;
    x0[((size_t)(b * 42 + o) * 3 + 2) * NTOT + n] = a2 / 20.0f;
}

// ============================ generic VN stats (packed (ps,o)) ================
template <int Ci, int Co, int PTS, int NT, int NIT>
__global__ __launch_bounds__(NT)
void vn_stats_kernel(const float* __restrict__ xin,
                     const float* __restrict__ wf,
                     double* __restrict__ stats, int Npts)
{
    constexpr int Ci3 = Ci * 3;
    constexpr int STRIDE = Ci3 + 1;
    __shared__ float col[PTS * STRIDE];
    __shared__ double red[2][PTS][Co];
    int t = threadIdx.x;
    int b = blockIdx.y;
    int ps = t / Co;
    int o = t - ps * Co;
    bool active = ps < PTS;
    double s = 0.0, s2 = 0.0;
    int base = blockIdx.x * (PTS * NIT);
    for (int it = 0; it < NIT; ++it) {
        int pt0 = base + it * PTS;
        __syncthreads();
        for (int i = t; i < PTS * Ci3; i += NT) {
            int pl = i / Ci3, off = i - pl * Ci3;
            int pt = pt0 + pl; if (pt >= Npts) pt = Npts - 1;
            col[pl * STRIDE + off] = xin[(size_t)(b * 3 * Ci + off) * Npts + pt];
        }
        __syncthreads();
        if (active && pt0 + ps < Npts) {
            const float* cl = &col[ps * STRIDE];
            const float* wr = wf + o * Ci;
            float p0 = 0.f, p1 = 0.f, p2 = 0.f;
#pragma unroll
            for (int c = 0; c < Ci; ++c) {
                float w = wr[c];
                p0 += w * cl[3 * c]; p1 += w * cl[3 * c + 1]; p2 += w * cl[3 * c + 2];
            }
            float nrm = sqrtf(p0 * p0 + p1 * p1 + p2 * p2) + 1e-6f;
            s += (double)nrm; s2 += (double)nrm * (double)nrm;
        }
    }
    if (active) { red[0][ps][o] = s; red[1][ps][o] = s2; }
    __syncthreads();
    if (t < Co) {
        double a = 0.0, a2 = 0.0;
#pragma unroll
        for (int p = 0; p < PTS; ++p) { a += red[0][p][t]; a2 += red[1][p][t]; }
        atomicAdd(&stats[t], a);
        atomicAdd(&stats[Co + t], a2);
    }
}

// ============================ VN apply (packed (ps,o); optional transposed out)
template <int Ci, int Co, int PTS, int NT, bool WT>
__global__ __launch_bounds__(NT)
void vn_apply_kernel(const float* __restrict__ xin,
                     const float* __restrict__ wf,
                     const float* __restrict__ wd,
                     const float* __restrict__ g,
                     const float* __restrict__ bbp,
                     const double* __restrict__ stats,
                     double count, int Npts,
                     float* __restrict__ xout,
                     float* __restrict__ xt)
{
    constexpr int Ci3 = Ci * 3;
    constexpr int STRIDE = Ci3 + 1;
    constexpr int CH = Co * 3;
    __shared__ float col[PTS * STRIDE];
    int t = threadIdx.x;
    int b = blockIdx.y;
    int ps = t / Co;
    int o = t - ps * Co;
    bool active = ps < PTS;
    float m = 0.f, gs = 0.f, bb = 0.f;
    if (active) {
        double S1 = stats[o], S2 = stats[Co + o];
        double md = S1 / count;
        m = (float)md;
        float var = (float)(S2 / count - md * md);
        gs = g[o] / sqrtf(var + 1e-5f);
        bb = bbp[o];
    }
    int pt0 = blockIdx.x * PTS;
    for (int i = t; i < PTS * Ci3; i += NT) {
        int pl = i / Ci3, off = i - pl * Ci3;
        int pt = pt0 + pl; if (pt >= Npts) pt = Npts - 1;
        col[pl * STRIDE + off] = xin[(size_t)(b * 3 * Ci + off) * Npts + pt];
    }
    __syncthreads();
    int pt = pt0 + ps;
    if (!active || pt >= Npts) return;
    const float* cl = &col[ps * STRIDE];
    const float* wr = wf + o * Ci;
    const float* wdr = wd + o * Ci;
    float p0 = 0.f, p1 = 0.f, p2 = 0.f, d0 = 0.f, d1 = 0.f, d2 = 0.f;
#pragma unroll
    for (int c = 0; c < Ci; ++c) {
        float c0 = cl[3 * c], c1 = cl[3 * c + 1], c2 = cl[3 * c + 2];
        float w = wr[c];
        p0 += w * c0; p1 += w * c1; p2 += w * c2;
        float w2 = wdr[c];
        d0 += w2 * c0; d1 += w2 * c1; d2 += w2 * c2;
    }
    float nrm = sqrtf(p0 * p0 + p1 * p1 + p2 * p2) + 1e-6f;
    float nb = gs * (nrm - m) + bb;
    float sc = nb / nrm;
    p0 *= sc; p1 *= sc; p2 *= sc;
    float dot = p0 * d0 + p1 * d1 + p2 * d2;
    float dsq = d0 * d0 + d1 * d1 + d2 * d2 + 1e-6f;
    float tq = fminf(dot, 0.f) / dsq;
    float r0 = p0 - tq * d0, r1 = p1 - tq * d1, r2 = p2 - tq * d2;
    float o0 = 0.2f * p0 + 0.8f * r0;
    float o1 = 0.2f * p1 + 0.8f * r1;
    float o2 = 0.2f * p2 + 0.8f * r2;
    xout[((size_t)(b * Co + o) * 3 + 0) * Npts + pt] = o0;
    xout[((size_t)(b * Co + o) * 3 + 1) * Npts + pt] = o1;
    xout[((size_t)(b * Co + o) * 3 + 2) * Npts + pt] = o2;
    if (WT) {
        float* tp = xt + ((size_t)(b * Npts + pt)) * CH + o * 3;
        tp[0] = o0; tp[1] = o1; tp[2] = o2;
    }
}

// ============================ VN max-pool-down (point-major gather) ==========
// NOTE: keep fp contract OFF here — argmax selection over dots.
__global__ void vn_pool_kernel(const float* __restrict__ xint,
                               const int* __restrict__ idx, long long sb, int sq,
                               const float* __restrict__ wp,
                               float* __restrict__ xout,
                               int C, int Np, int Nq)
{
#pragma clang fp contract(off)
    __shared__ float nb[4 * 84 * 3];
    int b = blockIdx.y;
    int q = blockIdx.x;
    const int* ir = idx + b * sb + (long long)q * sq;
    int CH = C * 3;
    for (int kk = 0; kk < 4; ++kk) {
        int mm = ir[kk];
        const float* src = xint + ((size_t)(b * Np + mm)) * CH;
        for (int t = threadIdx.x; t < CH; t += blockDim.x)
            nb[kk * CH + t] = src[t];
    }
    __syncthreads();
    int o = threadIdx.x;
    if (o >= C) return;
    const float* wr = wp + o * C;
    float best = -3.4e38f;
    int bk = 0;
    for (int kk = 0; kk < 4; ++kk) {
        const float* cl = &nb[kk * CH];
        float d0 = 0.f, d1 = 0.f, d2 = 0.f;
        for (int c = 0; c < C; ++c) {
            float w = wr[c];
            d0 += w * cl[3 * c]; d1 += w * cl[3 * c + 1]; d2 += w * cl[3 * c + 2];
        }
        float dot = cl[o * 3] * d0 + cl[o * 3 + 1] * d1 + cl[o * 3 + 2] * d2;
        if (dot > best) { best = dot; bk = kk; }
    }
    const float* cb = &nb[bk * CH];
    xout[((size_t)(b * C + o) * 3 + 0) * Nq + q] = cb[o * 3];
    xout[((size_t)(b * C + o) * 3 + 1) * Nq + q] = cb[o * 3 + 1];
    xout[((size_t)(b * C + o) * 3 + 2) * Nq + q] = cb[o * 3 + 2];
}

// ============================ eqv assembly + fused mean partial ==============
__global__ void eqv_kernel(const float* __restrict__ x0, const float* __restrict__ x1,
                           const float* __restrict__ x2, const float* __restrict__ x3,
                           const float* __restrict__ x4,
                           const int* __restrict__ i1, const int* __restrict__ i2,
                           float* __restrict__ out_eqv, float* __restrict__ mfw)
{
    __shared__ float wsum[4];
    int n = blockIdx.x * 256 + threadIdx.x;
    int cv = blockIdx.y;
    int b = blockIdx.z;
    int cc = cv / 3, v = cv % 3;
    float val;
    if (cc < 42)
        val = x0[((size_t)(b * 42 + cc) * 3 + v) * NTOT + n];
    else if (cc < 84)
        val = x1[((size_t)(b * 42 + (cc - 42)) * 3 + v) * NTOT + n];
    else if (cc < 168) {
        int m = i1[b * NTOT + n];
        val = x2[((size_t)(b * 84 + (cc - 84)) * 3 + v) * 512 + m];
    } else if (cc < 252) {
        int m = i1[b * NTOT + n];
        val = x3[((size_t)(b * 84 + (cc - 168)) * 3 + v) * 512 + m];
    } else {
        int m = i2[b * NTOT + n];
        val = x4[((size_t)(b * 168 + (cc - 252)) * 3 + v) * 128 + m];
    }
    out_eqv[((size_t)(b * 1260 + cv)) * NTOT + n] = val;
    float s = val;
    for (int off = 32; off; off >>= 1) s += __shfl_down(s, off);
    if ((threadIdx.x & 63) == 0) wsum[threadIdx.x >> 6] = s;
    __syncthreads();
    if (threadIdx.x == 0)
        atomicAdd(&mfw[b * 1260 + cv], (wsum[0] + wsum[1]) + (wsum[2] + wsum[3]));
}

// ============================ mean_feat finalize ============================
__global__ void mf_finalize_kernel(float* __restrict__ mfw, float* __restrict__ out_mf)
{
    int i = blockIdx.x * 256 + threadIdx.x;
    if (i < 5040) {
        float m = mfw[i] / 2048.0f;
        mfw[i] = m;
        out_mf[i] = m;
    }
}

// ============================ z1: wave-per-output VN layer (K=420) ===========
__global__ __launch_bounds__(256)
void z1_kernel(const float* __restrict__ mfw,
               const float* __restrict__ wv1f, const float* __restrict__ wv1d,
               float* __restrict__ z1ws)
{
    __shared__ float mf[1260];
    int b = blockIdx.y;
    int wave = threadIdx.x >> 6, lane = threadIdx.x & 63;
    for (int i = threadIdx.x; i < 1260; i += 256) mf[i] = mfw[b * 1260 + i];
    __syncthreads();
    int o = blockIdx.x * 4 + wave;
    if (o >= 210) return;
    const float* wr  = wv1f + (size_t)o * 420;
    const float* wdr = wv1d + (size_t)o * 420;
    float p0 = 0.f, p1 = 0.f, p2 = 0.f, d0 = 0.f, d1 = 0.f, d2 = 0.f;
    for (int c = lane; c < 420; c += 64) {
        float m0 = mf[3 * c], m1 = mf[3 * c + 1], m2 = mf[3 * c + 2];
        float w = wr[c];
        p0 += w * m0; p1 += w * m1; p2 += w * m2;
        float w2 = wdr[c];
        d0 += w2 * m0; d1 += w2 * m1; d2 += w2 * m2;
    }
    for (int off = 32; off; off >>= 1) {
        p0 += __shfl_down(p0, off); p1 += __shfl_down(p1, off);
        p2 += __shfl_down(p2, off); d0 += __shfl_down(d0, off);
        d1 += __shfl_down(d1, off); d2 += __shfl_down(d2, off);
    }
    if (lane == 0) {
        float dot = p0 * d0 + p1 * d1 + p2 * d2;
        float r0, r1, r2;
        if (dot >= 0.f) { r0 = p0; r1 = p1; r2 = p2; }
        else {
            float tq = dot / (d0 * d0 + d1 * d1 + d2 * d2 + 1e-6f);
            r0 = p0 - tq * d0; r1 = p1 - tq * d1; r2 = p2 - tq * d2;
        }
        z1ws[b * 630 + o * 3]     = 0.2f * p0 + 0.8f * r0;
        z1ws[b * 630 + o * 3 + 1] = 0.2f * p1 + 0.8f * r1;
        z1ws[b * 630 + o * 3 + 2] = 0.2f * p2 + 0.8f * r2;
    }
}

// ============================ z2: wave-per-output VN layer (K=210) ===========
__global__ __launch_bounds__(256)
void z2_kernel(const float* __restrict__ z1ws,
               const float* __restrict__ wv2f, const float* __restrict__ wv2d,
               float* __restrict__ z2ws)
{
    __shared__ float zl[630];
    int b = blockIdx.y;
    int wave = threadIdx.x >> 6, lane = threadIdx.x & 63;
    for (int i = threadIdx.x; i < 630; i += 256) zl[i] = z1ws[b * 630 + i];
    __syncthreads();
    int o = blockIdx.x * 4 + wave;
    if (o >= 84) return;
    const float* wr  = wv2f + (size_t)o * 210;
    const float* wdr = wv2d + (size_t)o * 210;
    float p0 = 0.f, p1 = 0.f, p2 = 0.f, d0 = 0.f, d1 = 0.f, d2 = 0.f;
    for (int c = lane; c < 210; c += 64) {
        float m0 = zl[3 * c], m1 = zl[3 * c + 1], m2 = zl[3 * c + 2];
        float w = wr[c];
        p0 += w * m0; p1 += w * m1; p2 += w * m2;
        float w2 = wdr[c];
        d0 += w2 * m0; d1 += w2 * m1; d2 += w2 * m2;
    }
    for (int off = 32; off; off >>= 1) {
        p0 += __shfl_down(p0, off); p1 += __shfl_down(p1, off);
        p2 += __shfl_down(p2, off); d0 += __shfl_down(d0, off);
        d1 += __shfl_down(d1, off); d2 += __shfl_down(d2, off);
    }
    if (lane == 0) {
        float dot = p0 * d0 + p1 * d1 + p2 * d2;
        float r0, r1, r2;
        if (dot >= 0.f) { r0 = p0; r1 = p1; r2 = p2; }
        else {
            float tq = dot / (d0 * d0 + d1 * d1 + d2 * d2 + 1e-6f);
            r0 = p0 - tq * d0; r1 = p1 - tq * d1; r2 = p2 - tq * d2;
        }
        z2ws[b * 252 + o * 3]     = 0.2f * p0 + 0.8f * r0;
        z2ws[b * 252 + o * 3 + 1] = 0.2f * p1 + 0.8f * r1;
        z2ws[b * 252 + o * 3 + 2] = 0.2f * p2 + 0.8f * r2;
    }
}

// ============================ z3 + inv_gl ============================
__global__ void z3invgl_kernel(const float* __restrict__ mfw,
                               const float* __restrict__ z2ws,
                               const float* __restrict__ w3,
                               float* __restrict__ invgl_ws,
                               float* __restrict__ out_invgl)
{
    __shared__ float z2[252];
    __shared__ float z3[6];
    __shared__ float mf[1260];
    int b = blockIdx.x;
    int t = threadIdx.x;
    for (int i = t; i < 252; i += 256) z2[i] = z2ws[b * 252 + i];
    for (int i = t; i < 1260; i += 256) mf[i] = mfw[b * 1260 + i];
    __syncthreads();
    if (t < 6) {
        int v = t / 2, kt = t % 2;
        float s = 0.f;
        for (int c = 0; c < 84; ++c) s += z2[c * 3 + v] * w3[kt * 84 + c];
        z3[v * 2 + kt] = s;
    }
    __syncthreads();
    for (int i = t; i < 840; i += 256) {
        int ii = i / 2, kt = i % 2;
        float s = mf[ii * 3] * z3[0 + kt] + mf[ii * 3 + 1] * z3[2 + kt] +
                  mf[ii * 3 + 2] * z3[4 + kt];
        invgl_ws[b * 840 + i] = s;
        out_invgl[b * 840 + i] = s;
    }
}

// ============================ conv1 factored coefficients (wave-per-o) =======
__global__ __launch_bounds__(256)
void conv1_coef_kernel(const float* __restrict__ ws1,
                       const float* __restrict__ invgl,
                       const float* __restrict__ mfw,
                       const int* __restrict__ cat,
                       float* __restrict__ cb, float* __restrict__ ab,
                       float* __restrict__ w0)
{
    int wave = threadIdx.x >> 6, lane = threadIdx.x & 63;
    int o = blockIdx.x * 4 + wave;           // 0..1023
    int b = blockIdx.y;
    const float* wr = ws1 + (size_t)o * 1267;
    float s = 0.f;
    for (int j = lane; j < 840; j += 64)
        s += wr[1 + j] * invgl[b * 840 + j];
    float a0 = 0.f, a1 = 0.f, a2 = 0.f;
    for (int i = lane; i < 420; i += 64) {
        float w = wr[841 + i];
        a0 += w * mfw[b * 1260 + i * 3];
        a1 += w * mfw[b * 1260 + i * 3 + 1];
        a2 += w * mfw[b * 1260 + i * 3 + 2];
    }
    for (int off = 32; off; off >>= 1) {
        s  += __shfl_down(s, off);
        a0 += __shfl_down(a0, off);
        a1 += __shfl_down(a1, off);
        a2 += __shfl_down(a2, off);
    }
    if (lane == 0) {
        cb[b * 1024 + o] = s + wr[1261 + cat[b]];
        ab[((size_t)(b * 1024 + o)) * 3 + 0] = a0;
        ab[((size_t)(b * 1024 + o)) * 3 + 1] = a1;
        ab[((size_t)(b * 1024 + o)) * 3 + 2] = a2;
        if (b == 0) w0[o] = wr[0];
    }
}

// ============================ y1 stats (no y1t materialization) ==============
__global__ __launch_bounds__(256)
void y1_stats_kernel(const float* __restrict__ cb, const float* __restrict__ ab,
                     const float* __restrict__ w0, const float* __restrict__ coord,
                     const float* __restrict__ normv, float* __restrict__ cst)
{
    __shared__ float px[256], py[256], pz[256], pn[256];
    int t = threadIdx.x;
    int o = blockIdx.x * 256 + t;
    int b = blockIdx.y >> 3;
    int n0 = (blockIdx.y & 7) * 256;
    px[t] = coord[(b * 3 + 0) * NTOT + n0 + t];
    py[t] = coord[(b * 3 + 1) * NTOT + n0 + t];
    pz[t] = coord[(b * 3 + 2) * NTOT + n0 + t];
    pn[t] = normv[b * NTOT + n0 + t];
    __syncthreads();
    size_t bo = (size_t)(b * 1024 + o);
    float c0 = cb[bo];
    float a0 = ab[bo * 3], a1 = ab[bo * 3 + 1], a2 = ab[bo * 3 + 2];
    float wn = w0[o];
    float s = 0.f, s2 = 0.f;
    for (int k = 0; k < 256; ++k) {
        float v = c0 + a0 * px[k] + a1 * py[k] + a2 * pz[k] + wn * pn[k];
        s += v; s2 += v * v;
    }
    atomicAdd(&cst[o], s);
    atomicAdd(&cst[1024 + o], s2);
}

// ============================ y1 BN+ReLU generator -> bf16 ====================
__global__ __launch_bounds__(256)
void y1_bnrelu_kernel(const float* __restrict__ cb, const float* __restrict__ ab,
                      const float* __restrict__ w0, const float* __restrict__ coord,
                      const float* __restrict__ normv, const float* __restrict__ cst,
                      const float* __restrict__ sg, const float* __restrict__ sb,
                      unsigned short* __restrict__ y1b)
{
    __shared__ float px[256], py[256], pz[256], pn[256];
    int t = threadIdx.x;
    int o = blockIdx.x * 256 + t;
    int b = blockIdx.y >> 3;
    int n0 = (blockIdx.y & 7) * 256;
    px[t] = coord[(b * 3 + 0) * NTOT + n0 + t];
    py[t] = coord[(b * 3 + 1) * NTOT + n0 + t];
    pz[t] = coord[(b * 3 + 2) * NTOT + n0 + t];
    pn[t] = normv[b * NTOT + n0 + t];
    __syncthreads();
    size_t bo = (size_t)(b * 1024 + o);
    float c0 = cb[bo];
    float a0 = ab[bo * 3], a1 = ab[bo * 3 + 1], a2 = ab[bo * 3 + 2];
    float wn = w0[o];
    float mm = cst[o] * (1.f / 8192.f);
    float var = cst[1024 + o] * (1.f / 8192.f) - mm * mm;
    float sc = sg[o] / sqrtf(var + 1e-5f);
    float bs = sb[o] - mm * sc;
    size_t rowbase = (size_t)(b * NTOT + n0) * 1024 + o;
    for (int k = 0; k < 256; ++k) {
        float v = c0 + a0 * px[k] + a1 * py[k] + a2 * pz[k] + wn * pn[k];
        float r = sc * v + bs;
        y1b[rowbase + (size_t)k * 1024] = f2b(r > 0.f ? r : 0.f);
    }
}

// ============================ weight convert f32 -> bf16 ============================
__global__ void wconv_kernel(const float* __restrict__ src, unsigned short* __restrict__ dst,
                             int Msrc, int Ksrc, int Kpad)
{
    int k = blockIdx.x * 256 + threadIdx.x;
    int o = blockIdx.y;
    float v = (o < Msrc && k < Ksrc) ? src[(size_t)o * Ksrc + k] : 0.f;
    dst[(size_t)o * Kpad + k] = f2b(v);
}

// ============================ MFMA GEMM 64x64/BK64 (+fused col BN stats) =====
__global__ __launch_bounds__(256)
void gemm_mfma_kernel(const unsigned short* __restrict__ A,
                      const unsigned short* __restrict__ Bw,
                      float* __restrict__ C, float* __restrict__ st,
                      int K, int Mreal)
{
    __shared__ __align__(16) unsigned short Al[64 * 72];
    __shared__ __align__(16) unsigned short Bl[64 * 72];
    __shared__ float sst[64], sst2[64];
    int t = threadIdx.x;
    if (t < 64) { sst[t] = 0.f; sst2[t] = 0.f; }
    int r0 = blockIdx.x * 64;
    int c0 = blockIdx.y * 64;
    int w = t >> 6, l = t & 63;
    int wm = w & 1, wn = w >> 1;
    int lm = l & 15, lq = l >> 4;
    f32x4 acc[2][2] = {};
    for (int k0 = 0; k0 < K; k0 += 64) {
#pragma unroll
        for (int half = 0; half < 2; ++half) {
            int ch = t + half * 256;
            int row = ch >> 3, kc = ch & 7;
            *(uint4*)&Al[row * 72 + kc * 8] =
                *(const uint4*)&A[(size_t)(r0 + row) * K + k0 + kc * 8];
            *(uint4*)&Bl[row * 72 + kc * 8] =
                *(const uint4*)&Bw[(size_t)(c0 + row) * K + k0 + kc * 8];
        }
        __syncthreads();
        bf16x8 af[2][2], bfr[2][2];
#pragma unroll
        for (int kk = 0; kk < 2; ++kk) {
#pragma unroll
            for (int i = 0; i < 2; ++i)
                af[kk][i] = *(const bf16x8*)&Al[(wm * 32 + i * 16 + lm) * 72 + kk * 32 + lq * 8];
#pragma unroll
            for (int j = 0; j < 2; ++j)
                bfr[kk][j] = *(const bf16x8*)&Bl[(wn * 32 + j * 16 + lm) * 72 + kk * 32 + lq * 8];
        }
#pragma unroll
        for (int kk = 0; kk < 2; ++kk)
#pragma unroll
            for (int i = 0; i < 2; ++i)
#pragma unroll
                for (int j = 0; j < 2; ++j)
                    acc[i][j] = __builtin_amdgcn_mfma_f32_16x16x32_bf16(
                        af[kk][i], bfr[kk][j], acc[i][j], 0, 0, 0);
        __syncthreads();
    }
#pragma unroll
    for (int i = 0; i < 2; ++i) {
#pragma unroll
        for (int j = 0; j < 2; ++j) {
            int col = c0 + wn * 32 + j * 16 + lm;
            if (col < Mreal) {
                int rbase = r0 + wm * 32 + i * 16 + lq * 4;
#pragma unroll
                for (int r = 0; r < 4; ++r)
                    C[(size_t)(rbase + r) * Mreal + col] = acc[i][j][r];
            }
        }
    }
#pragma unroll
    for (int j = 0; j < 2; ++j) {
        float s = 0.f, s2 = 0.f;
#pragma unroll
        for (int i = 0; i < 2; ++i)
#pragma unroll
            for (int r = 0; r < 4; ++r) { float x = acc[i][j][r]; s += x; s2 += x * x; }
        s  += __shfl_down(s, 32);  s  += __shfl_down(s, 16);
        s2 += __shfl_down(s2, 32); s2 += __shfl_down(s2, 16);
        if (l < 16) {
            int cc = wn * 32 + j * 16 + lm;
            atomicAdd(&sst[cc], s);
            atomicAdd(&sst2[cc], s2);
        }
    }
    __syncthreads();
    if (t < 64) {
        int col = c0 + t;
        if (col < Mreal) {
            atomicAdd(&st[col], sst[t]);
            atomicAdd(&st[Mreal + col], sst2[t]);
        }
    }
}

// ============================ BN+ReLU -> bf16 ============================
__global__ void bnreluT_kernel(const float* __restrict__ Ct, const float* __restrict__ st,
                               const float* __restrict__ g, const float* __restrict__ be,
                               unsigned short* __restrict__ outb, int M, int maskM)
{
    size_t idx = (size_t)blockIdx.x * 256 + threadIdx.x;
    int o = (int)(idx & (size_t)maskM);
    float m = st[o] * (1.f / 8192.f);
    float var = st[M + o] * (1.f / 8192.f) - m * m;
    float sqv = sqrtf(var + 1e-5f);
    float v = g[o] * (Ct[idx] - m) / sqv + be[o];
    outb[idx] = f2b(v > 0.f ? v : 0.f);
}

// ============================ final BN+ReLU + transpose ============================
__global__ void bnrelu_outT_kernel(const float* __restrict__ Ct, const float* __restrict__ st,
                                   const float* __restrict__ g, const float* __restrict__ be,
                                   float* __restrict__ outinv)
{
    __shared__ float tile[64][65];
    int t = threadIdx.x;
    int r0 = blockIdx.x * 64;
    int o0 = blockIdx.y * 64;
    int b = r0 >> 11, n0 = r0 & 2047;
    int oi = t & 63;
    int o = o0 + oi;
    float m = 0.f, sqv = 1.f, gg = 0.f, bb = 0.f;
    if (o < 420) {
        m = st[o] * (1.f / 8192.f);
        float var = st[420 + o] * (1.f / 8192.f) - m * m;
        sqv = sqrtf(var + 1e-5f);
        gg = g[o]; bb = be[o];
    }
    for (int it = 0; it < 16; ++it) {
        int rr = it * 4 + (t >> 6);
        float v = 0.f;
        if (o < 420) {
            v = gg * (Ct[(size_t)(r0 + rr) * 420 + o] - m) / sqv + bb;
            v = v > 0.f ? v : 0.f;
        }
        tile[rr][oi] = v;
    }
    __syncthreads();
    for (int it = 0; it < 16; ++it) {
        int oc = it * 4 + (t >> 6);
        int oo = o0 + oc;
        if (oo < 420)
            outinv[((size_t)(b * 420 + oo)) * 2048 + n0 + (t & 63)] = tile[t & 63][oc];
    }
}

// ============================ launch ============================
extern "C" void kernel_launch(void* const* d_in, const int* in_sizes, int n_in,
                              void* d_out, int out_size, void* d_ws, size_t ws_size,
                              hipStream_t stream)
{
    (void)in_sizes; (void)n_in; (void)out_size; (void)ws_size;
    const float* xc   = (const float*)d_in[0];
    const float* normv= (const float*)d_in[1];
    const int*   cat  = (const int*)d_in[2];
    const float* wf0  = (const float*)d_in[3];
    const float* wd0  = (const float*)d_in[4];
    const float* g0   = (const float*)d_in[5];
    const float* b0   = (const float*)d_in[6];
    const float* wf1  = (const float*)d_in[7];
    const float* wd1  = (const float*)d_in[8];
    const float* g1   = (const float*)d_in[9];
    const float* b1   = (const float*)d_in[10];
    const float* wp1  = (const float*)d_in[11];
    const float* wf2  = (const float*)d_in[12];
    const float* wd2  = (const float*)d_in[13];
    const float* g2   = (const float*)d_in[14];
    const float* b2   = (const float*)d_in[15];
    const float* wf3  = (const float*)d_in[16];
    const float* wd3  = (const float*)d_in[17];
    const float* g3   = (const float*)d_in[18];
    const float* b3   = (const float*)d_in[19];
    const float* wp2  = (const float*)d_in[20];
    const float* wf4  = (const float*)d_in[21];
    const float* wd4  = (const float*)d_in[22];
    const float* g4   = (const float*)d_in[23];
    const float* b4   = (const float*)d_in[24];
    const float* wv1f = (const float*)d_in[25];
    const float* wv1d = (const float*)d_in[26];
    const float* wv2f = (const float*)d_in[27];
    const float* wv2d = (const float*)d_in[28];
    const float* w3   = (const float*)d_in[29];
    const float* ws1  = (const float*)d_in[30];
    const float* sg1  = (const float*)d_in[32];
    const float* sb1  = (const float*)d_in[33];
    const float* ws2  = (const float*)d_in[34];
    const float* sg2  = (const float*)d_in[36];
    const float* sb2  = (const float*)d_in[37];
    const float* ws3  = (const float*)d_in[38];
    const float* sg3  = (const float*)d_in[40];
    const float* sb3  = (const float*)d_in[41];

    float* ws = (float*)d_ws;
    float* out = (float*)d_out;

    int*    idx20 = (int*)(ws + WS_IDX20);
    float*  x1t   = ws + WS_X1T;
    float*  x0    = ws + WS_X0;
    float*  x1    = ws + WS_X1;
    float*  xm2   = ws + WS_XM2;
    float*  x2    = ws + WS_X2;
    float*  x3    = ws + WS_X3;
    int*    idx42 = (int*)(ws + WS_IDX42);
    float*  xm4   = ws + WS_XM4;
    float*  x4    = ws + WS_X4;
    int*    i1p   = (int*)(ws + WS_I1);
    int*    i2p   = (int*)(ws + WS_I2);
    float*  mfw   = ws + WS_MF;
    float*  invgl = ws + WS_INVGL;
    double* st    = (double*)(ws + WS_STATS);
    float*  cst   = ws + WS_CST;
    float*  cb    = ws + WS_CB;
    float*  ab    = ws + WS_AB;
    float*  w0    = ws + WS_W0;
    float*  z1ws  = ws + WS_Z1;
    float*  z2ws  = ws + WS_Z2;
    float*  x3t   = ws + WS_X3T;
    unsigned short* w2b  = (unsigned short*)(ws + WS_W2B);
    unsigned short* w3b  = (unsigned short*)(ws + WS_W3B);
    unsigned short* y1b  = (unsigned short*)(ws + WS_Y1B);
    float*  y2t   = ws + WS_Y2T;
    unsigned short* y2b  = (unsigned short*)(ws + WS_Y2B);
    float*  y3t   = ws + WS_Y3T;

    // single memset covers mfw + invgl + stats + cst (contiguous span)
    hipMemsetAsync((void*)mfw, 0, ZERO_SPAN_BYTES, stream);

    // weight conversions (independent)
    wconv_kernel<<<dim3(4, 512), 256, 0, stream>>>(ws2, w2b, 512, 1024, 1024);
    wconv_kernel<<<dim3(2, 512), 256, 0, stream>>>(ws3, w3b, 420, 512, 512);

    // KNN-20: 2 queries per wave
    knn_reg_kernel<32, 20, 2><<<dim3(256, 4), 256, 0, stream>>>(xc, 1, 1, idx20, 2048);

    // stage 0 (surf features fused from coord + idx20)
    stats0_kernel<<<dim3(43, 4), 256, 0, stream>>>(xc, idx20, wf0, st + ST0_OFF);
    apply0_kernel<<<dim3(342, 4), 256, 0, stream>>>(xc, idx20, wf0, wd0, g0, b0,
                                                    st + ST0_OFF, x0);

    // stage 1 (also emits point-major x1t for the pool gather)
    vn_stats_kernel<42, 42, 6, 256, 8><<<dim3(43, 4), 256, 0, stream>>>(
        x0, wf1, st + ST1_OFF, 2048);
    vn_apply_kernel<42, 42, 6, 256, true><<<dim3(342, 4), 256, 0, stream>>>(
        x0, wf1, wd1, g1, b1, st + ST1_OFF, 8192.0, 2048, x1, x1t);

    // pool 1 (coalesced point-major gather)
    vn_pool_kernel<<<dim3(512, 4), 256, 0, stream>>>(x1t, idx20, 40960LL, 80, wp1, xm2,
                                                     42, 2048, 512);
    // stage 2
    vn_stats_kernel<42, 84, 3, 256, 8><<<dim3(22, 4), 256, 0, stream>>>(
        xm2, wf2, st + ST2_OFF, 512);
    vn_apply_kernel<42, 84, 3, 256, false><<<dim3(171, 4), 256, 0, stream>>>(
        xm2, wf2, wd2, g2, b2, st + ST2_OFF, 2048.0, 512, x2, nullptr);
    // stage 3 (also emits x3t for pool 2)
    vn_stats_kernel<84, 84, 3, 256, 8><<<dim3(22, 4), 256, 0, stream>>>(
        x2, wf3, st + ST3_OFF, 512);
    vn_apply_kernel<84, 84, 3, 256, true><<<dim3(171, 4), 256, 0, stream>>>(
        x2, wf3, wd3, g3, b3, st + ST3_OFF, 2048.0, 512, x3, x3t);

    // knn-4 on coord2 (cands stride 4, queries stride 16)
    knn_reg_kernel<8, 4, 1><<<dim3(32, 4), 256, 0, stream>>>(xc, 4, 16, idx42, 128);
    vn_pool_kernel<<<dim3(128, 4), 256, 0, stream>>>(x3t, idx42, 512LL, 4, wp2, xm4,
                                                     84, 512, 128);
    // stage 4
    vn_stats_kernel<84, 168, 3, 512, 4><<<dim3(11, 4), 512, 0, stream>>>(
        xm4, wf4, st + ST4_OFF, 128);
    vn_apply_kernel<84, 168, 3, 512, false><<<dim3(43, 4), 512, 0, stream>>>(
        xm4, wf4, wd4, g4, b4, st + ST4_OFF, 512.0, 128, x4, nullptr);

    // nearest-neighbor upsample indices (i1 + i2 from one scan)
    nearest_dual_kernel<<<dim3(512, 4), 256, 0, stream>>>(xc, i1p, i2p);

    // eqv (output 0) with fused mean partials; finalize mean (output 1)
    eqv_kernel<<<dim3(8, 1260, 4), 256, 0, stream>>>(x0, x1, x2, x3, x4, i1p, i2p,
                                                     out + OUT_EQV, mfw);
    mf_finalize_kernel<<<20, 256, 0, stream>>>(mfw, out + OUT_MF);

    // z chain (wave-per-output, coalesced) + inv_gl (output 3)
    z1_kernel<<<dim3(53, 4), 256, 0, stream>>>(mfw, wv1f, wv1d, z1ws);
    z2_kernel<<<dim3(21, 4), 256, 0, stream>>>(z1ws, wv2f, wv2d, z2ws);
    z3invgl_kernel<<<4, 256, 0, stream>>>(mfw, z2ws, w3, invgl, out + OUT_INVGL);

    // invariant branch: conv1 factored (wave-per-(b,o), coalesced)
    conv1_coef_kernel<<<dim3(256, 4), 256, 0, stream>>>(ws1, invgl, mfw, cat, cb, ab, w0);
    // y1: stats pass + BN/ReLU regenerate pass (y1t never materialized)
    y1_stats_kernel<<<dim3(4, 32), 256, 0, stream>>>(cb, ab, w0, xc, normv,
                                                     cst + CST1_OFF);
    y1_bnrelu_kernel<<<dim3(4, 32), 256, 0, stream>>>(cb, ab, w0, xc, normv,
                                                      cst + CST1_OFF, sg1, sb1, y1b);

    gemm_mfma_kernel<<<dim3(128, 8), 256, 0, stream>>>(y1b, w2b, y2t, cst + CST2_OFF,
                                                       1024, 512);
    bnreluT_kernel<<<16384, 256, 0, stream>>>(y2t, cst + CST2_OFF, sg2, sb2, y2b,
                                              512, 511);

    gemm_mfma_kernel<<<dim3(128, 7), 256, 0, stream>>>(y2b, w3b, y3t, cst + CST3_OFF,
                                                       512, 420);
    bnrelu_outT_kernel<<<dim3(128, 7), 256, 0, stream>>>(y3t, cst + CST3_OFF, sg3, sb3,
                                                         out + OUT_INV);
}

// Round 9
// 558.728 us; speedup vs baseline: 1.1732x; 1.0430x over previous
//
#include <hip/hip_runtime.h>
#include <hip/hip_bf16.h>
#include <cstdint>
#include <cstddef>

#define NTOT 2048
#define BTOT 4

typedef short bf16x8 __attribute__((ext_vector_type(8)));
typedef float f32x4 __attribute__((ext_vector_type(4)));

__device__ inline unsigned short f2b(float v) {
    __hip_bfloat16 h = __float2bfloat16(v);
    return *reinterpret_cast<unsigned short*>(&h);
}

// ---------------- workspace layout (float-element offsets) ----------------
static const size_t WS_IDX20 = 0;                       // int[163840]
static const size_t WS_X1T   = 163840;                  // float[1032192] (B,2048,126) pool1 gather copy
static const size_t WS_X0    = 1638400;                 // float[2064384] (B,42,3,2048)
static const size_t WS_X1    = 3702784;                 // float[2064384]
static const size_t WS_XM2   = 5767168;                 // float[258048]
static const size_t WS_X2    = 6025216;                 // float[516096]
static const size_t WS_X3    = 6541312;                 // float[516096]
static const size_t WS_IDX42 = 7057408;                 // int[2048]
static const size_t WS_XM4   = 7059456;                 // float[129024]
static const size_t WS_X4    = 7188480;                 // float[258048]
static const size_t WS_I1    = 7446528;                 // int[8192]
static const size_t WS_I2    = 7454720;                 // int[8192]
static const size_t WS_MF    = 7462912;                 // float[5040]
static const size_t WS_INVGL = 7467952;                 // float[3360]
static const size_t WS_STATS = 7471312;                 // double[840] (1680 fl slots)
static const size_t WS_CST   = 7472992;                 // float[3912] conv bn sums
static const size_t WS_MOM   = 7476904;                 // float[56] per-batch moments (gap before CB)
static const size_t WS_CB    = 7480320;                 // float[4096]   cb[b][o]
static const size_t WS_AB    = 7484416;                 // float[12288]  ab[b][o][3]
static const size_t WS_W0    = 7496704;                 // float[1024]   ws1[:,0]
static const size_t WS_Z1    = 7497728;                 // float[2520]   z1[b][210*3]
static const size_t WS_Z2    = 7500288;                 // float[1008]   z2[b][84*3]
static const size_t WS_X3T   = 7501312;                 // float[516096] (B,512,252) pool2 gather copy
                                                        //   (inside Y2T span; lifetime-disjoint: dead before gemm1)
static const size_t WS_W2B   = 13378560;                // ushort[512*1024]
static const size_t WS_W3B   = 13640704;                // ushort[512*512]
static const size_t WS_Y1B   = 0;                       // ushort overlay (written late; x1t dead by then)
static const size_t WS_Y2T   = 7480320;                 // float overlay (CB/AB/Z dead)
static const size_t WS_Y2B   = 4194304;                 // ushort overlay
static const size_t WS_Y3T   = 13771776;                // float overlay

// zero-span: mfw..cst contiguous (mfw 5040 + invgl 3360 + stats 1680 + cst 3912)
#define ZERO_SPAN_BYTES ((7476904 - 7462912) * 4)

#define ST0_OFF 0
#define ST1_OFF 84
#define ST2_OFF 168
#define ST3_OFF 336
#define ST4_OFF 504
#define CST1_OFF 0
#define CST2_OFF 2048
#define CST3_OFF 3072

#define OUT_EQV   0
#define OUT_MF    10321920
#define OUT_INV   10326960
#define OUT_INVGL 13767600

// ============================ KNN v5 (v3 extraction + NQ-query ILP) ==========
// NOTE: fp contract OFF here — distance ordering feeds index selection.
template <int SLOTS, int K, int NQ>
__global__ __launch_bounds__(256)
void knn_reg_kernel(const float* __restrict__ coord, int cand_stride, int q_stride,
                    int* __restrict__ out_idx, int q_cnt)
{
#pragma clang fp contract(off)
    constexpr int Q = SLOTS / 8;
    int b = blockIdx.y;
    int wave = threadIdx.x >> 6, lane = threadIdx.x & 63;
    int qbase = (blockIdx.x * 4 + wave) * NQ;
    if (qbase >= q_cnt) return;
    float qx[NQ], qy[NQ], qz[NQ], xxq[NQ];
#pragma unroll
    for (int u = 0; u < NQ; ++u) {
        int nq = (qbase + u) * q_stride;
        qx[u] = coord[(b * 3 + 0) * NTOT + nq];
        qy[u] = coord[(b * 3 + 1) * NTOT + nq];
        qz[u] = coord[(b * 3 + 2) * NTOT + nq];
        xxq[u] = qx[u] * qx[u] + qy[u] * qy[u] + qz[u] * qz[u];
    }
    float v[NQ][SLOTS];
#pragma unroll
    for (int j = 0; j < SLOTS; ++j) {
        int mo = (lane + 64 * j) * cand_stride;
        float cx = coord[(b * 3 + 0) * NTOT + mo];
        float cy = coord[(b * 3 + 1) * NTOT + mo];
        float cz = coord[(b * 3 + 2) * NTOT + mo];
        float xxc = cx * cx + cy * cy + cz * cz;
#pragma unroll
        for (int u = 0; u < NQ; ++u) {
            float inner = qx[u] * cx + qy[u] * cy + qz[u] * cz;
            v[u][j] = (2.0f * inner - xxq[u]) - xxc;
        }
    }
    float qv[NQ][Q]; int qj[NQ][Q];
#pragma unroll
    for (int u = 0; u < NQ; ++u)
#pragma unroll
        for (int qq = 0; qq < Q; ++qq) {
            float nv = v[u][qq * 8]; int nj = qq * 8;
#pragma unroll
            for (int j = 1; j < 8; ++j)
                if (v[u][qq * 8 + j] > nv) { nv = v[u][qq * 8 + j]; nj = qq * 8 + j; }
            qv[u][qq] = nv; qj[u][qq] = nj;
        }
#pragma clang loop unroll(disable)
    for (int kk = 0; kk < K; ++kk) {
        float bv[NQ]; int bm[NQ];
#pragma unroll
        for (int u = 0; u < NQ; ++u) {
            float tv = qv[u][0]; int tj = qj[u][0];
#pragma unroll
            for (int qq = 1; qq < Q; ++qq)
                if (qv[u][qq] > tv) { tv = qv[u][qq]; tj = qj[u][qq]; }
            bv[u] = tv; bm[u] = lane + 64 * tj;
        }
        // interleaved butterflies: NQ independent chains hide shuffle latency
        for (int off = 32; off; off >>= 1) {
            float ov[NQ]; int om[NQ];
#pragma unroll
            for (int u = 0; u < NQ; ++u) {
                ov[u] = __shfl_down(bv[u], off);
                om[u] = __shfl_down(bm[u], off);
            }
#pragma unroll
            for (int u = 0; u < NQ; ++u)
                if (ov[u] > bv[u] || (ov[u] == bv[u] && om[u] < bm[u])) {
                    bv[u] = ov[u]; bm[u] = om[u];
                }
        }
#pragma unroll
        for (int u = 0; u < NQ; ++u) {
            int m_win = __builtin_amdgcn_readfirstlane(bm[u]);
            if (lane == 0)
                out_idx[((size_t)(b * q_cnt) + qbase + u) * K + kk] = m_win;
            int w_slot = m_win >> 6;
            bool isw = (lane == (m_win & 63));
#pragma unroll
            for (int qq = 0; qq < Q; ++qq) {
                if (qq == (w_slot >> 3)) {
#pragma unroll
                    for (int j = 0; j < 8; ++j)
                        if (qq * 8 + j == w_slot)
                            v[u][qq * 8 + j] = isw ? -3.4e38f : v[u][qq * 8 + j];
                    float nv = v[u][qq * 8]; int nj = qq * 8;
#pragma unroll
                    for (int j = 1; j < 8; ++j)
                        if (v[u][qq * 8 + j] > nv) { nv = v[u][qq * 8 + j]; nj = qq * 8 + j; }
                    qv[u][qq] = nv; qj[u][qq] = nj;
                }
            }
        }
    }
}

// ============================ nearest DUAL (i1 stride-4 + i2 stride-16) ======
__global__ __launch_bounds__(256)
void nearest_dual_kernel(const float* __restrict__ coord,
                         int* __restrict__ out1, int* __restrict__ out2)
{
#pragma clang fp contract(off)
    int b = blockIdx.y;
    int wave = threadIdx.x >> 6, lane = threadIdx.x & 63;
    int n = blockIdx.x * 4 + wave;
    float qx = coord[(b * 3 + 0) * NTOT + n];
    float qy = coord[(b * 3 + 1) * NTOT + n];
    float qz = coord[(b * 3 + 2) * NTOT + n];
    float tt = qx * qx + qy * qy + qz * qz;
    float v[8];
#pragma unroll
    for (int j = 0; j < 8; ++j) {
        int mo = (lane + 64 * j) * 4;
        float cx = coord[(b * 3 + 0) * NTOT + mo];
        float cy = coord[(b * 3 + 1) * NTOT + mo];
        float cz = coord[(b * 3 + 2) * NTOT + mo];
        float inner = qx * cx + qy * cy + qz * cz;
        float ss = cx * cx + cy * cy + cz * cz;
        v[j] = (tt - 2.0f * inner) + ss;
    }
    float bv = v[0];
    int bj = 0;
#pragma unroll
    for (int j = 1; j < 8; ++j)
        if (v[j] < bv) { bv = v[j]; bj = j; }
    int bm = lane + 64 * bj;
    bool has2 = ((lane & 3) == 0);
    float bv2 = 3.4e38f;
    int bm2 = 0x7fffffff;
    if (has2) {
        bv2 = v[0]; bm2 = (lane >> 2);
#pragma unroll
        for (int j = 1; j < 8; ++j) {
            if (v[j] < bv2) { bv2 = v[j]; bm2 = (lane >> 2) + 16 * j; }
        }
    }
    for (int off = 32; off; off >>= 1) {
        float ov = __shfl_down(bv, off);
        int   om = __shfl_down(bm, off);
        if (ov < bv || (ov == bv && om < bm)) { bv = ov; bm = om; }
        float ov2 = __shfl_down(bv2, off);
        int   om2 = __shfl_down(bm2, off);
        if (ov2 < bv2 || (ov2 == bv2 && om2 < bm2)) { bv2 = ov2; bm2 = om2; }
    }
    if (lane == 0) {
        out1[b * NTOT + n] = bm;
        out2[b * NTOT + n] = bm2;
    }
}

// ============================ per-batch moments of (x,y,z,nr) ================
// 14 sums: Sx,Sy,Sz,Sn, Sxx,Syy,Szz,Snn, Sxy,Sxz,Syz, Sxn,Syn,Szn
__global__ __launch_bounds__(256)
void moments_kernel(const float* __restrict__ coord, const float* __restrict__ normv,
                    float* __restrict__ mom)
{
    __shared__ float red[4][14];
    int b = blockIdx.x, t = threadIdx.x;
    int lane = t & 63, wave = t >> 6;
    float m[14];
#pragma unroll
    for (int k = 0; k < 14; ++k) m[k] = 0.f;
    for (int i = t; i < NTOT; i += 256) {
        float x = coord[(b * 3 + 0) * NTOT + i];
        float y = coord[(b * 3 + 1) * NTOT + i];
        float z = coord[(b * 3 + 2) * NTOT + i];
        float r = normv[b * NTOT + i];
        m[0] += x;     m[1] += y;     m[2] += z;     m[3] += r;
        m[4] += x * x; m[5] += y * y; m[6] += z * z; m[7] += r * r;
        m[8] += x * y; m[9] += x * z; m[10] += y * z;
        m[11] += x * r; m[12] += y * r; m[13] += z * r;
    }
    for (int off = 32; off; off >>= 1)
#pragma unroll
        for (int k = 0; k < 14; ++k) m[k] += __shfl_down(m[k], off);
    if (lane == 0)
#pragma unroll
        for (int k = 0; k < 14; ++k) red[wave][k] = m[k];
    __syncthreads();
    if (t < 14)
        mom[b * 14 + t] = (red[0][t] + red[1][t]) + (red[2][t] + red[3][t]);
}

// ============================ stage-0 stats (fused surf feature) ==============
__global__ __launch_bounds__(256)
void stats0_kernel(const float* __restrict__ coord, const int* __restrict__ idx20,
                   const float* __restrict__ wf0, double* __restrict__ stats)
{
    __shared__ float nbc[360];   // [6 pts][20 nb][xyz]
    __shared__ float ctr[18];    // [6 pts][xyz]
    __shared__ double red[2][6][42];
    int t = threadIdx.x, b = blockIdx.y;
    int ps = t / 42, o = t - ps * 42;
    bool active = ps < 6;
    float w0 = 0.f, w1 = 0.f, w2 = 0.f;
    if (active) { w0 = wf0[o * 3]; w1 = wf0[o * 3 + 1]; w2 = wf0[o * 3 + 2]; }
    double s = 0.0, s2 = 0.0;
    int base = blockIdx.x * 48;
    for (int it = 0; it < 8; ++it) {
        int n0 = base + it * 6;
        __syncthreads();
        if (t < 120) {
            int pl = t / 20, k = t - pl * 20;
            int n = n0 + pl; if (n > NTOT - 1) n = NTOT - 1;
            int m = idx20[((size_t)(b * NTOT + n)) * 20 + k];
            nbc[t * 3 + 0] = coord[(b * 3 + 0) * NTOT + m];
            nbc[t * 3 + 1] = coord[(b * 3 + 1) * NTOT + m];
            nbc[t * 3 + 2] = coord[(b * 3 + 2) * NTOT + m];
        }
        if (t >= 128 && t < 146) {
            int i = t - 128; int pl = i / 3, vd = i - pl * 3;
            int n = n0 + pl; if (n > NTOT - 1) n = NTOT - 1;
            ctr[i] = coord[(b * 3 + vd) * NTOT + n];
        }
        __syncthreads();
        if (active && n0 + ps < NTOT) {
            float cx = ctr[ps * 3], cy = ctr[ps * 3 + 1], cz = ctr[ps * 3 + 2];
            const float* nb = &nbc[ps * 60];
            float sf = 0.f, sf2 = 0.f;
            for (int k = 0; k < 20; ++k) {
                float nx = nb[k * 3], ny = nb[k * 3 + 1], nz = nb[k * 3 + 2];
                float dx = nx - cx, dy = ny - cy, dz = nz - cz;
                float crx = ny * cz - nz * cy;
                float cry = nz * cx - nx * cz;
                float crz = nx * cy - ny * cx;
                float p0 = w0 * dx + w1 * cx + w2 * crx;
                float p1 = w0 * dy + w1 * cy + w2 * cry;
                float p2 = w0 * dz + w1 * cz + w2 * crz;
                float nrm = sqrtf(p0 * p0 + p1 * p1 + p2 * p2) + 1e-6f;
                sf += nrm; sf2 += nrm * nrm;
            }
            s += (double)sf; s2 += (double)sf2;
        }
    }
    if (active) { red[0][ps][o] = s; red[1][ps][o] = s2; }
    __syncthreads();
    if (t < 42) {
        double a = 0.0, a2 = 0.0;
#pragma unroll
        for (int p = 0; p < 6; ++p) { a += red[0][p][t]; a2 += red[1][p][t]; }
        atomicAdd(&stats[t], a);
        atomicAdd(&stats[42 + t], a2);
    }
}

// ============================ stage-0 apply (fused surf feature) ==============
__global__ __launch_bounds__(256)
void apply0_kernel(const float* __restrict__ coord, const int* __restrict__ idx20,
                   const float* __restrict__ wf0, const float* __restrict__ wd0,
                   const float* __restrict__ g0, const float* __restrict__ b0,
                   const double* __restrict__ stats, float* __restrict__ x0)
{
    __shared__ float nbc[360];
    __shared__ float ctr[18];
    int t = threadIdx.x;
    int b = blockIdx.y;
    int ps = t / 42, o = t - ps * 42;
    int n0 = blockIdx.x * 6;
    if (t < 120) {
        int pl = t / 20, k = t - pl * 20;
        int n = n0 + pl; if (n > NTOT - 1) n = NTOT - 1;
        int m = idx20[((size_t)(b * NTOT + n)) * 20 + k];
        nbc[t * 3 + 0] = coord[(b * 3 + 0) * NTOT + m];
        nbc[t * 3 + 1] = coord[(b * 3 + 1) * NTOT + m];
        nbc[t * 3 + 2] = coord[(b * 3 + 2) * NTOT + m];
    }
    if (t >= 128 && t < 146) {
        int i = t - 128; int pl = i / 3, vd = i - pl * 3;
        int n = n0 + pl; if (n > NTOT - 1) n = NTOT - 1;
        ctr[i] = coord[(b * 3 + vd) * NTOT + n];
    }
    __syncthreads();
    int n = n0 + ps;
    if (ps >= 6 || n >= NTOT) return;
    double S1 = stats[o], S2 = stats[42 + o];
    double md = S1 / 163840.0;
    float m = (float)md;
    float var = (float)(S2 / 163840.0 - md * md);
    float gs = g0[o] / sqrtf(var + 1e-5f);
    float bb = b0[o];
    float wa0 = wf0[o * 3], wa1 = wf0[o * 3 + 1], wa2 = wf0[o * 3 + 2];
    float wb0 = wd0[o * 3], wb1 = wd0[o * 3 + 1], wb2 = wd0[o * 3 + 2];
    float cx = ctr[ps * 3], cy = ctr[ps * 3 + 1], cz = ctr[ps * 3 + 2];
    const float* nb = &nbc[ps * 60];
    float a0 = 0.f, a1 = 0.f, a2 = 0.f;
    for (int k = 0; k < 20; ++k) {
        float nx = nb[k * 3], ny = nb[k * 3 + 1], nz = nb[k * 3 + 2];
        float dx = nx - cx, dy = ny - cy, dz = nz - cz;
        float crx = ny * cz - nz * cy;
        float cry = nz * cx - nx * cz;
        float crz = nx * cy - ny * cx;
        float p0 = wa0 * dx + wa1 * cx + wa2 * crx;
        float p1 = wa0 * dy + wa1 * cy + wa2 * cry;
        float p2 = wa0 * dz + wa1 * cz + wa2 * crz;
        float d0 = wb0 * dx + wb1 * cx + wb2 * crx;
        float d1 = wb0 * dy + wb1 * cy + wb2 * cry;
        float d2 = wb0 * dz + wb1 * cz + wb2 * crz;
        float nrm = sqrtf(p0 * p0 + p1 * p1 + p2 * p2) + 1e-6f;
        float nbv = gs * (nrm - m) + bb;
        float sc = nbv / nrm;
        p0 *= sc; p1 *= sc; p2 *= sc;
        float dot = p0 * d0 + p1 * d1 + p2 * d2;
        float dsq = d0 * d0 + d1 * d1 + d2 * d2 + 1e-6f;
        float tq = fminf(dot, 0.f) / dsq;
        a0 += 0.2f * p0 + 0.8f * (p0 - tq * d0);
        a1 += 0.2f * p1 + 0.8f * (p1 - tq * d1);
        a2 += 0.2f * p2 + 0.8f * (p2 - tq * d2);
    }
    x0[((size_t)(b * 42 + o) * 3 + 0) * NTOT + n] = a0 / 20.0f;
    x0[((size_t)(b * 42 + o) * 3 + 1) * NTOT + n] = a1 / 20.0f;
    x0[((size_t)(b * 42 + o) * 3 + 2) * NTOT + n] = a2 / 20.0f;
}

// ============================ generic VN stats (packed (ps,o)) ================
template <int Ci, int Co, int PTS, int NT, int NIT>
__global__ __launch_bounds__(NT)
void vn_stats_kernel(const float* __restrict__ xin,
                     const float* __restrict__ wf,
                     double* __restrict__ stats, int Npts)
{
    constexpr int Ci3 = Ci * 3;
    constexpr int STRIDE = Ci3 + 1;
    __shared__ float col[PTS * STRIDE];
    __shared__ double red[2][PTS][Co];
    int t = threadIdx.x;
    int b = blockIdx.y;
    int ps = t / Co;
    int o = t - ps * Co;
    bool active = ps < PTS;
    double s = 0.0, s2 = 0.0;
    int base = blockIdx.x * (PTS * NIT);
    for (int it = 0; it < NIT; ++it) {
        int pt0 = base + it * PTS;
        __syncthreads();
        for (int i = t; i < PTS * Ci3; i += NT) {
            int pl = i / Ci3, off = i - pl * Ci3;
            int pt = pt0 + pl; if (pt >= Npts) pt = Npts - 1;
            col[pl * STRIDE + off] = xin[(size_t)(b * 3 * Ci + off) * Npts + pt];
        }
        __syncthreads();
        if (active && pt0 + ps < Npts) {
            const float* cl = &col[ps * STRIDE];
            const float* wr = wf + o * Ci;
            float p0 = 0.f, p1 = 0.f, p2 = 0.f;
#pragma unroll
            for (int c = 0; c < Ci; ++c) {
                float w = wr[c];
                p0 += w * cl[3 * c]; p1 += w * cl[3 * c + 1]; p2 += w * cl[3 * c + 2];
            }
            float nrm = sqrtf(p0 * p0 + p1 * p1 + p2 * p2) + 1e-6f;
            s += (double)nrm; s2 += (double)nrm * (double)nrm;
        }
    }
    if (active) { red[0][ps][o] = s; red[1][ps][o] = s2; }
    __syncthreads();
    if (t < Co) {
        double a = 0.0, a2 = 0.0;
#pragma unroll
        for (int p = 0; p < PTS; ++p) { a += red[0][p][t]; a2 += red[1][p][t]; }
        atomicAdd(&stats[t], a);
        atomicAdd(&stats[Co + t], a2);
    }
}

// ============================ VN apply (packed (ps,o); optional transposed out)
template <int Ci, int Co, int PTS, int NT, bool WT>
__global__ __launch_bounds__(NT)
void vn_apply_kernel(const float* __restrict__ xin,
                     const float* __restrict__ wf,
                     const float* __restrict__ wd,
                     const float* __restrict__ g,
                     const float* __restrict__ bbp,
                     const double* __restrict__ stats,
                     double count, int Npts,
                     float* __restrict__ xout,
                     float* __restrict__ xt)
{
    constexpr int Ci3 = Ci * 3;
    constexpr int STRIDE = Ci3 + 1;
    constexpr int CH = Co * 3;
    __shared__ float col[PTS * STRIDE];
    int t = threadIdx.x;
    int b = blockIdx.y;
    int ps = t / Co;
    int o = t - ps * Co;
    bool active = ps < PTS;
    float m = 0.f, gs = 0.f, bb = 0.f;
    if (active) {
        double S1 = stats[o], S2 = stats[Co + o];
        double md = S1 / count;
        m = (float)md;
        float var = (float)(S2 / count - md * md);
        gs = g[o] / sqrtf(var + 1e-5f);
        bb = bbp[o];
    }
    int pt0 = blockIdx.x * PTS;
    for (int i = t; i < PTS * Ci3; i += NT) {
        int pl = i / Ci3, off = i - pl * Ci3;
        int pt = pt0 + pl; if (pt >= Npts) pt = Npts - 1;
        col[pl * STRIDE + off] = xin[(size_t)(b * 3 * Ci + off) * Npts + pt];
    }
    __syncthreads();
    int pt = pt0 + ps;
    if (!active || pt >= Npts) return;
    const float* cl = &col[ps * STRIDE];
    const float* wr = wf + o * Ci;
    const float* wdr = wd + o * Ci;
    float p0 = 0.f, p1 = 0.f, p2 = 0.f, d0 = 0.f, d1 = 0.f, d2 = 0.f;
#pragma unroll
    for (int c = 0; c < Ci; ++c) {
        float c0 = cl[3 * c], c1 = cl[3 * c + 1], c2 = cl[3 * c + 2];
        float w = wr[c];
        p0 += w * c0; p1 += w * c1; p2 += w * c2;
        float w2 = wdr[c];
        d0 += w2 * c0; d1 += w2 * c1; d2 += w2 * c2;
    }
    float nrm = sqrtf(p0 * p0 + p1 * p1 + p2 * p2) + 1e-6f;
    float nb = gs * (nrm - m) + bb;
    float sc = nb / nrm;
    p0 *= sc; p1 *= sc; p2 *= sc;
    float dot = p0 * d0 + p1 * d1 + p2 * d2;
    float dsq = d0 * d0 + d1 * d1 + d2 * d2 + 1e-6f;
    float tq = fminf(dot, 0.f) / dsq;
    float r0 = p0 - tq * d0, r1 = p1 - tq * d1, r2 = p2 - tq * d2;
    float o0 = 0.2f * p0 + 0.8f * r0;
    float o1 = 0.2f * p1 + 0.8f * r1;
    float o2 = 0.2f * p2 + 0.8f * r2;
    xout[((size_t)(b * Co + o) * 3 + 0) * Npts + pt] = o0;
    xout[((size_t)(b * Co + o) * 3 + 1) * Npts + pt] = o1;
    xout[((size_t)(b * Co + o) * 3 + 2) * Npts + pt] = o2;
    if (WT) {
        float* tp = xt + ((size_t)(b * Npts + pt)) * CH + o * 3;
        tp[0] = o0; tp[1] = o1; tp[2] = o2;
    }
}

// ============================ VN max-pool-down (point-major gather) ==========
// NOTE: keep fp contract OFF here — argmax selection over dots.
__global__ void vn_pool_kernel(const float* __restrict__ xint,
                               const int* __restrict__ idx, long long sb, int sq,
                               const float* __restrict__ wp,
                               float* __restrict__ xout,
                               int C, int Np, int Nq)
{
#pragma clang fp contract(off)
    __shared__ float nb[4 * 84 * 3];
    int b = blockIdx.y;
    int q = blockIdx.x;
    const int* ir = idx + b * sb + (long long)q * sq;
    int CH = C * 3;
    for (int kk = 0; kk < 4; ++kk) {
        int mm = ir[kk];
        const float* src = xint + ((size_t)(b * Np + mm)) * CH;
        for (int t = threadIdx.x; t < CH; t += blockDim.x)
            nb[kk * CH + t] = src[t];
    }
    __syncthreads();
    int o = threadIdx.x;
    if (o >= C) return;
    const float* wr = wp + o * C;
    float best = -3.4e38f;
    int bk = 0;
    for (int kk = 0; kk < 4; ++kk) {
        const float* cl = &nb[kk * CH];
        float d0 = 0.f, d1 = 0.f, d2 = 0.f;
        for (int c = 0; c < C; ++c) {
            float w = wr[c];
            d0 += w * cl[3 * c]; d1 += w * cl[3 * c + 1]; d2 += w * cl[3 * c + 2];
        }
        float dot = cl[o * 3] * d0 + cl[o * 3 + 1] * d1 + cl[o * 3 + 2] * d2;
        if (dot > best) { best = dot; bk = kk; }
    }
    const float* cbp = &nb[bk * CH];
    xout[((size_t)(b * C + o) * 3 + 0) * Nq + q] = cbp[o * 3];
    xout[((size_t)(b * C + o) * 3 + 1) * Nq + q] = cbp[o * 3 + 1];
    xout[((size_t)(b * C + o) * 3 + 2) * Nq + q] = cbp[o * 3 + 2];
}

// ============================ eqv assembly + fused mean partial ==============
__global__ void eqv_kernel(const float* __restrict__ x0, const float* __restrict__ x1,
                           const float* __restrict__ x2, const float* __restrict__ x3,
                           const float* __restrict__ x4,
                           const int* __restrict__ i1, const int* __restrict__ i2,
                           float* __restrict__ out_eqv, float* __restrict__ mfw)
{
    __shared__ float wsum[4];
    int n = blockIdx.x * 256 + threadIdx.x;
    int cv = blockIdx.y;
    int b = blockIdx.z;
    int cc = cv / 3, v = cv % 3;
    float val;
    if (cc < 42)
        val = x0[((size_t)(b * 42 + cc) * 3 + v) * NTOT + n];
    else if (cc < 84)
        val = x1[((size_t)(b * 42 + (cc - 42)) * 3 + v) * NTOT + n];
    else if (cc < 168) {
        int m = i1[b * NTOT + n];
        val = x2[((size_t)(b * 84 + (cc - 84)) * 3 + v) * 512 + m];
    } else if (cc < 252) {
        int m = i1[b * NTOT + n];
        val = x3[((size_t)(b * 84 + (cc - 168)) * 3 + v) * 512 + m];
    } else {
        int m = i2[b * NTOT + n];
        val = x4[((size_t)(b * 168 + (cc - 252)) * 3 + v) * 128 + m];
    }
    out_eqv[((size_t)(b * 1260 + cv)) * NTOT + n] = val;
    float s = val;
    for (int off = 32; off; off >>= 1) s += __shfl_down(s, off);
    if ((threadIdx.x & 63) == 0) wsum[threadIdx.x >> 6] = s;
    __syncthreads();
    if (threadIdx.x == 0)
        atomicAdd(&mfw[b * 1260 + cv], (wsum[0] + wsum[1]) + (wsum[2] + wsum[3]));
}

// ============================ mean_feat finalize ============================
__global__ void mf_finalize_kernel(float* __restrict__ mfw, float* __restrict__ out_mf)
{
    int i = blockIdx.x * 256 + threadIdx.x;
    if (i < 5040) {
        float m = mfw[i] / 2048.0f;
        mfw[i] = m;
        out_mf[i] = m;
    }
}

// ============================ z1: wave-per-output VN layer (K=420) ===========
__global__ __launch_bounds__(256)
void z1_kernel(const float* __restrict__ mfw,
               const float* __restrict__ wv1f, const float* __restrict__ wv1d,
               float* __restrict__ z1ws)
{
    __shared__ float mf[1260];
    int b = blockIdx.y;
    int wave = threadIdx.x >> 6, lane = threadIdx.x & 63;
    for (int i = threadIdx.x; i < 1260; i += 256) mf[i] = mfw[b * 1260 + i];
    __syncthreads();
    int o = blockIdx.x * 4 + wave;
    if (o >= 210) return;
    const float* wr  = wv1f + (size_t)o * 420;
    const float* wdr = wv1d + (size_t)o * 420;
    float p0 = 0.f, p1 = 0.f, p2 = 0.f, d0 = 0.f, d1 = 0.f, d2 = 0.f;
    for (int c = lane; c < 420; c += 64) {
        float m0 = mf[3 * c], m1 = mf[3 * c + 1], m2 = mf[3 * c + 2];
        float w = wr[c];
        p0 += w * m0; p1 += w * m1; p2 += w * m2;
        float w2 = wdr[c];
        d0 += w2 * m0; d1 += w2 * m1; d2 += w2 * m2;
    }
    for (int off = 32; off; off >>= 1) {
        p0 += __shfl_down(p0, off); p1 += __shfl_down(p1, off);
        p2 += __shfl_down(p2, off); d0 += __shfl_down(d0, off);
        d1 += __shfl_down(d1, off); d2 += __shfl_down(d2, off);
    }
    if (lane == 0) {
        float dot = p0 * d0 + p1 * d1 + p2 * d2;
        float r0, r1, r2;
        if (dot >= 0.f) { r0 = p0; r1 = p1; r2 = p2; }
        else {
            float tq = dot / (d0 * d0 + d1 * d1 + d2 * d2 + 1e-6f);
            r0 = p0 - tq * d0; r1 = p1 - tq * d1; r2 = p2 - tq * d2;
        }
        z1ws[b * 630 + o * 3]     = 0.2f * p0 + 0.8f * r0;
        z1ws[b * 630 + o * 3 + 1] = 0.2f * p1 + 0.8f * r1;
        z1ws[b * 630 + o * 3 + 2] = 0.2f * p2 + 0.8f * r2;
    }
}

// ============================ z2: wave-per-output VN layer (K=210) ===========
__global__ __launch_bounds__(256)
void z2_kernel(const float* __restrict__ z1ws,
               const float* __restrict__ wv2f, const float* __restrict__ wv2d,
               float* __restrict__ z2ws)
{
    __shared__ float zl[630];
    int b = blockIdx.y;
    int wave = threadIdx.x >> 6, lane = threadIdx.x & 63;
    for (int i = threadIdx.x; i < 630; i += 256) zl[i] = z1ws[b * 630 + i];
    __syncthreads();
    int o = blockIdx.x * 4 + wave;
    if (o >= 84) return;
    const float* wr  = wv2f + (size_t)o * 210;
    const float* wdr = wv2d + (size_t)o * 210;
    float p0 = 0.f, p1 = 0.f, p2 = 0.f, d0 = 0.f, d1 = 0.f, d2 = 0.f;
    for (int c = lane; c < 210; c += 64) {
        float m0 = zl[3 * c], m1 = zl[3 * c + 1], m2 = zl[3 * c + 2];
        float w = wr[c];
        p0 += w * m0; p1 += w * m1; p2 += w * m2;
        float w2 = wdr[c];
        d0 += w2 * m0; d1 += w2 * m1; d2 += w2 * m2;
    }
    for (int off = 32; off; off >>= 1) {
        p0 += __shfl_down(p0, off); p1 += __shfl_down(p1, off);
        p2 += __shfl_down(p2, off); d0 += __shfl_down(d0, off);
        d1 += __shfl_down(d1, off); d2 += __shfl_down(d2, off);
    }
    if (lane == 0) {
        float dot = p0 * d0 + p1 * d1 + p2 * d2;
        float r0, r1, r2;
        if (dot >= 0.f) { r0 = p0; r1 = p1; r2 = p2; }
        else {
            float tq = dot / (d0 * d0 + d1 * d1 + d2 * d2 + 1e-6f);
            r0 = p0 - tq * d0; r1 = p1 - tq * d1; r2 = p2 - tq * d2;
        }
        z2ws[b * 252 + o * 3]     = 0.2f * p0 + 0.8f * r0;
        z2ws[b * 252 + o * 3 + 1] = 0.2f * p1 + 0.8f * r1;
        z2ws[b * 252 + o * 3 + 2] = 0.2f * p2 + 0.8f * r2;
    }
}

// ============================ z3 + inv_gl ============================
__global__ void z3invgl_kernel(const float* __restrict__ mfw,
                               const float* __restrict__ z2ws,
                               const float* __restrict__ w3,
                               float* __restrict__ invgl_ws,
                               float* __restrict__ out_invgl)
{
    __shared__ float z2[252];
    __shared__ float z3[6];
    __shared__ float mf[1260];
    int b = blockIdx.x;
    int t = threadIdx.x;
    for (int i = t; i < 252; i += 256) z2[i] = z2ws[b * 252 + i];
    for (int i = t; i < 1260; i += 256) mf[i] = mfw[b * 1260 + i];
    __syncthreads();
    if (t < 6) {
        int v = t / 2, kt = t % 2;
        float s = 0.f;
        for (int c = 0; c < 84; ++c) s += z2[c * 3 + v] * w3[kt * 84 + c];
        z3[v * 2 + kt] = s;
    }
    __syncthreads();
    for (int i = t; i < 840; i += 256) {
        int ii = i / 2, kt = i % 2;
        float s = mf[ii * 3] * z3[0 + kt] + mf[ii * 3 + 1] * z3[2 + kt] +
                  mf[ii * 3 + 2] * z3[4 + kt];
        invgl_ws[b * 840 + i] = s;
        out_invgl[b * 840 + i] = s;
    }
}

// ===== conv1 factored coefficients + moment-based y1 BN stats (wave-per-o) ===
__global__ __launch_bounds__(256)
void conv1_coef_kernel(const float* __restrict__ ws1,
                       const float* __restrict__ invgl,
                       const float* __restrict__ mfw,
                       const int* __restrict__ cat,
                       const float* __restrict__ mom,
                       float* __restrict__ cb, float* __restrict__ ab,
                       float* __restrict__ w0, float* __restrict__ cst1)
{
    int wave = threadIdx.x >> 6, lane = threadIdx.x & 63;
    int o = blockIdx.x * 4 + wave;           // 0..1023
    int b = blockIdx.y;
    const float* wr = ws1 + (size_t)o * 1267;
    float s = 0.f;
    for (int j = lane; j < 840; j += 64)
        s += wr[1 + j] * invgl[b * 840 + j];
    float a0 = 0.f, a1 = 0.f, a2 = 0.f;
    for (int i = lane; i < 420; i += 64) {
        float w = wr[841 + i];
        a0 += w * mfw[b * 1260 + i * 3];
        a1 += w * mfw[b * 1260 + i * 3 + 1];
        a2 += w * mfw[b * 1260 + i * 3 + 2];
    }
    for (int off = 32; off; off >>= 1) {
        s  += __shfl_down(s, off);
        a0 += __shfl_down(a0, off);
        a1 += __shfl_down(a1, off);
        a2 += __shfl_down(a2, off);
    }
    if (lane == 0) {
        float c0 = s + wr[1261 + cat[b]];
        float wn = wr[0];
        cb[b * 1024 + o] = c0;
        ab[((size_t)(b * 1024 + o)) * 3 + 0] = a0;
        ab[((size_t)(b * 1024 + o)) * 3 + 1] = a1;
        ab[((size_t)(b * 1024 + o)) * 3 + 2] = a2;
        if (b == 0) w0[o] = wn;
        // y1 BN stats from per-batch moments (exact: y1 is affine in (x,y,z,nr))
        const float* M = mom + b * 14;
        float lin = a0 * M[0] + a1 * M[1] + a2 * M[2] + wn * M[3];
        float s1 = 2048.f * c0 + lin;
        float s2 = 2048.f * c0 * c0 + 2.f * c0 * lin
                 + a0 * a0 * M[4] + a1 * a1 * M[5] + a2 * a2 * M[6] + wn * wn * M[7]
                 + 2.f * (a0 * a1 * M[8] + a0 * a2 * M[9] + a1 * a2 * M[10]
                 + a0 * wn * M[11] + a1 * wn * M[12] + a2 * wn * M[13]);
        atomicAdd(&cst1[o], s1);
        atomicAdd(&cst1[1024 + o], s2);
    }
}

// ============================ y1 BN+ReLU generator -> bf16 ====================
__global__ __launch_bounds__(256)
void y1_bnrelu_kernel(const float* __restrict__ cb, const float* __restrict__ ab,
                      const float* __restrict__ w0, const float* __restrict__ coord,
                      const float* __restrict__ normv, const float* __restrict__ cst,
                      const float* __restrict__ sg, const float* __restrict__ sb,
                      unsigned short* __restrict__ y1b)
{
    __shared__ float px[256], py[256], pz[256], pn[256];
    int t = threadIdx.x;
    int o = blockIdx.x * 256 + t;
    int b = blockIdx.y >> 3;
    int n0 = (blockIdx.y & 7) * 256;
    px[t] = coord[(b * 3 + 0) * NTOT + n0 + t];
    py[t] = coord[(b * 3 + 1) * NTOT + n0 + t];
    pz[t] = coord[(b * 3 + 2) * NTOT + n0 + t];
    pn[t] = normv[b * NTOT + n0 + t];
    __syncthreads();
    size_t bo = (size_t)(b * 1024 + o);
    float c0 = cb[bo];
    float a0 = ab[bo * 3], a1 = ab[bo * 3 + 1], a2 = ab[bo * 3 + 2];
    float wn = w0[o];
    float mm = cst[o] * (1.f / 8192.f);
    float var = cst[1024 + o] * (1.f / 8192.f) - mm * mm;
    float sc = sg[o] / sqrtf(var + 1e-5f);
    float bs = sb[o] - mm * sc;
    size_t rowbase = (size_t)(b * NTOT + n0) * 1024 + o;
    for (int k = 0; k < 256; ++k) {
        float v = c0 + a0 * px[k] + a1 * py[k] + a2 * pz[k] + wn * pn[k];
        float r = sc * v + bs;
        y1b[rowbase + (size_t)k * 1024] = f2b(r > 0.f ? r : 0.f);
    }
}

// ============================ weight convert f32 -> bf16 ============================
__global__ void wconv_kernel(const float* __restrict__ src, unsigned short* __restrict__ dst,
                             int Msrc, int Ksrc, int Kpad)
{
    int k = blockIdx.x * 256 + threadIdx.x;
    int o = blockIdx.y;
    float v = (o < Msrc && k < Ksrc) ? src[(size_t)o * Ksrc + k] : 0.f;
    dst[(size_t)o * Kpad + k] = f2b(v);
}

// ============================ MFMA GEMM 64x64/BK64 (+fused col BN stats) =====
__global__ __launch_bounds__(256)
void gemm_mfma_kernel(const unsigned short* __restrict__ A,
                      const unsigned short* __restrict__ Bw,
                      float* __restrict__ C, float* __restrict__ st,
                      int K, int Mreal)
{
    __shared__ __align__(16) unsigned short Al[64 * 72];
    __shared__ __align__(16) unsigned short Bl[64 * 72];
    __shared__ float sst[64], sst2[64];
    int t = threadIdx.x;
    if (t < 64) { sst[t] = 0.f; sst2[t] = 0.f; }
    int r0 = blockIdx.x * 64;
    int c0 = blockIdx.y * 64;
    int w = t >> 6, l = t & 63;
    int wm = w & 1, wn = w >> 1;
    int lm = l & 15, lq = l >> 4;
    f32x4 acc[2][2] = {};
    for (int k0 = 0; k0 < K; k0 += 64) {
#pragma unroll
        for (int half = 0; half < 2; ++half) {
            int ch = t + half * 256;
            int row = ch >> 3, kc = ch & 7;
            *(uint4*)&Al[row * 72 + kc * 8] =
                *(const uint4*)&A[(size_t)(r0 + row) * K + k0 + kc * 8];
            *(uint4*)&Bl[row * 72 + kc * 8] =
                *(const uint4*)&Bw[(size_t)(c0 + row) * K + k0 + kc * 8];
        }
        __syncthreads();
        bf16x8 af[2][2], bfr[2][2];
#pragma unroll
        for (int kk = 0; kk < 2; ++kk) {
#pragma unroll
            for (int i = 0; i < 2; ++i)
                af[kk][i] = *(const bf16x8*)&Al[(wm * 32 + i * 16 + lm) * 72 + kk * 32 + lq * 8];
#pragma unroll
            for (int j = 0; j < 2; ++j)
                bfr[kk][j] = *(const bf16x8*)&Bl[(wn * 32 + j * 16 + lm) * 72 + kk * 32 + lq * 8];
        }
#pragma unroll
        for (int kk = 0; kk < 2; ++kk)
#pragma unroll
            for (int i = 0; i < 2; ++i)
#pragma unroll
                for (int j = 0; j < 2; ++j)
                    acc[i][j] = __builtin_amdgcn_mfma_f32_16x16x32_bf16(
                        af[kk][i], bfr[kk][j], acc[i][j], 0, 0, 0);
        __syncthreads();
    }
#pragma unroll
    for (int i = 0; i < 2; ++i) {
#pragma unroll
        for (int j = 0; j < 2; ++j) {
            int col = c0 + wn * 32 + j * 16 + lm;
            if (col < Mreal) {
                int rbase = r0 + wm * 32 + i * 16 + lq * 4;
#pragma unroll
                for (int r = 0; r < 4; ++r)
                    C[(size_t)(rbase + r) * Mreal + col] = acc[i][j][r];
            }
        }
    }
#pragma unroll
    for (int j = 0; j < 2; ++j) {
        float s = 0.f, s2 = 0.f;
#pragma unroll
        for (int i = 0; i < 2; ++i)
#pragma unroll
            for (int r = 0; r < 4; ++r) { float x = acc[i][j][r]; s += x; s2 += x * x; }
        s  += __shfl_down(s, 32);  s  += __shfl_down(s, 16);
        s2 += __shfl_down(s2, 32); s2 += __shfl_down(s2, 16);
        if (l < 16) {
            int cc = wn * 32 + j * 16 + lm;
            atomicAdd(&sst[cc], s);
            atomicAdd(&sst2[cc], s2);
        }
    }
    __syncthreads();
    if (t < 64) {
        int col = c0 + t;
        if (col < Mreal) {
            atomicAdd(&st[col], sst[t]);
            atomicAdd(&st[Mreal + col], sst2[t]);
        }
    }
}

// ============================ BN+ReLU -> bf16 ============================
__global__ void bnreluT_kernel(const float* __restrict__ Ct, const float* __restrict__ st,
                               const float* __restrict__ g, const float* __restrict__ be,
                               unsigned short* __restrict__ outb, int M, int maskM)
{
    size_t idx = (size_t)blockIdx.x * 256 + threadIdx.x;
    int o = (int)(idx & (size_t)maskM);
    float m = st[o] * (1.f / 8192.f);
    float var = st[M + o] * (1.f / 8192.f) - m * m;
    float sqv = sqrtf(var + 1e-5f);
    float v = g[o] * (Ct[idx] - m) / sqv + be[o];
    outb[idx] = f2b(v > 0.f ? v : 0.f);
}

// ============================ final BN+ReLU + transpose ============================
__global__ void bnrelu_outT_kernel(const float* __restrict__ Ct, const float* __restrict__ st,
                                   const float* __restrict__ g, const float* __restrict__ be,
                                   float* __restrict__ outinv)
{
    __shared__ float tile[64][65];
    int t = threadIdx.x;
    int r0 = blockIdx.x * 64;
    int o0 = blockIdx.y * 64;
    int b = r0 >> 11, n0 = r0 & 2047;
    int oi = t & 63;
    int o = o0 + oi;
    float m = 0.f, sqv = 1.f, gg = 0.f, bb = 0.f;
    if (o < 420) {
        m = st[o] * (1.f / 8192.f);
        float var = st[420 + o] * (1.f / 8192.f) - m * m;
        sqv = sqrtf(var + 1e-5f);
        gg = g[o]; bb = be[o];
    }
    for (int it = 0; it < 16; ++it) {
        int rr = it * 4 + (t >> 6);
        float v = 0.f;
        if (o < 420) {
            v = gg * (Ct[(size_t)(r0 + rr) * 420 + o] - m) / sqv + bb;
            v = v > 0.f ? v : 0.f;
        }
        tile[rr][oi] = v;
    }
    __syncthreads();
    for (int it = 0; it < 16; ++it) {
        int oc = it * 4 + (t >> 6);
        int oo = o0 + oc;
        if (oo < 420)
            outinv[((size_t)(b * 420 + oo)) * 2048 + n0 + (t & 63)] = tile[t & 63][oc];
    }
}

// ============================ launch ============================
extern "C" void kernel_launch(void* const* d_in, const int* in_sizes, int n_in,
                              void* d_out, int out_size, void* d_ws, size_t ws_size,
                              hipStream_t stream)
{
    (void)in_sizes; (void)n_in; (void)out_size; (void)ws_size;
    const float* xc   = (const float*)d_in[0];
    const float* normv= (const float*)d_in[1];
    const int*   cat  = (const int*)d_in[2];
    const float* wf0  = (const float*)d_in[3];
    const float* wd0  = (const float*)d_in[4];
    const float* g0   = (const float*)d_in[5];
    const float* b0   = (const float*)d_in[6];
    const float* wf1  = (const float*)d_in[7];
    const float* wd1  = (const float*)d_in[8];
    const float* g1   = (const float*)d_in[9];
    const float* b1   = (const float*)d_in[10];
    const float* wp1  = (const float*)d_in[11];
    const float* wf2  = (const float*)d_in[12];
    const float* wd2  = (const float*)d_in[13];
    const float* g2   = (const float*)d_in[14];
    const float* b2   = (const float*)d_in[15];
    const float* wf3  = (const float*)d_in[16];
    const float* wd3  = (const float*)d_in[17];
    const float* g3   = (const float*)d_in[18];
    const float* b3   = (const float*)d_in[19];
    const float* wp2  = (const float*)d_in[20];
    const float* wf4  = (const float*)d_in[21];
    const float* wd4  = (const float*)d_in[22];
    const float* g4   = (const float*)d_in[23];
    const float* b4   = (const float*)d_in[24];
    const float* wv1f = (const float*)d_in[25];
    const float* wv1d = (const float*)d_in[26];
    const float* wv2f = (const float*)d_in[27];
    const float* wv2d = (const float*)d_in[28];
    const float* w3   = (const float*)d_in[29];
    const float* ws1  = (const float*)d_in[30];
    const float* sg1  = (const float*)d_in[32];
    const float* sb1  = (const float*)d_in[33];
    const float* ws2  = (const float*)d_in[34];
    const float* sg2  = (const float*)d_in[36];
    const float* sb2  = (const float*)d_in[37];
    const float* ws3  = (const float*)d_in[38];
    const float* sg3  = (const float*)d_in[40];
    const float* sb3  = (const float*)d_in[41];

    float* ws = (float*)d_ws;
    float* out = (float*)d_out;

    int*    idx20 = (int*)(ws + WS_IDX20);
    float*  x1t   = ws + WS_X1T;
    float*  x0    = ws + WS_X0;
    float*  x1    = ws + WS_X1;
    float*  xm2   = ws + WS_XM2;
    float*  x2    = ws + WS_X2;
    float*  x3    = ws + WS_X3;
    int*    idx42 = (int*)(ws + WS_IDX42);
    float*  xm4   = ws + WS_XM4;
    float*  x4    = ws + WS_X4;
    int*    i1p   = (int*)(ws + WS_I1);
    int*    i2p   = (int*)(ws + WS_I2);
    float*  mfw   = ws + WS_MF;
    float*  invgl = ws + WS_INVGL;
    double* st    = (double*)(ws + WS_STATS);
    float*  cst   = ws + WS_CST;
    float*  mom   = ws + WS_MOM;
    float*  cb    = ws + WS_CB;
    float*  ab    = ws + WS_AB;
    float*  w0    = ws + WS_W0;
    float*  z1ws  = ws + WS_Z1;
    float*  z2ws  = ws + WS_Z2;
    float*  x3t   = ws + WS_X3T;
    unsigned short* w2b  = (unsigned short*)(ws + WS_W2B);
    unsigned short* w3b  = (unsigned short*)(ws + WS_W3B);
    unsigned short* y1b  = (unsigned short*)(ws + WS_Y1B);
    float*  y2t   = ws + WS_Y2T;
    unsigned short* y2b  = (unsigned short*)(ws + WS_Y2B);
    float*  y3t   = ws + WS_Y3T;

    // single memset covers mfw + invgl + stats + cst (contiguous span)
    hipMemsetAsync((void*)mfw, 0, ZERO_SPAN_BYTES, stream);

    // per-batch coordinate moments (for moment-based y1 BN stats)
    moments_kernel<<<4, 256, 0, stream>>>(xc, normv, mom);

    // weight conversions (independent)
    wconv_kernel<<<dim3(4, 512), 256, 0, stream>>>(ws2, w2b, 512, 1024, 1024);
    wconv_kernel<<<dim3(2, 512), 256, 0, stream>>>(ws3, w3b, 420, 512, 512);

    // KNN-20: 2 queries per wave
    knn_reg_kernel<32, 20, 2><<<dim3(256, 4), 256, 0, stream>>>(xc, 1, 1, idx20, 2048);

    // stage 0 (surf features fused from coord + idx20)
    stats0_kernel<<<dim3(43, 4), 256, 0, stream>>>(xc, idx20, wf0, st + ST0_OFF);
    apply0_kernel<<<dim3(342, 4), 256, 0, stream>>>(xc, idx20, wf0, wd0, g0, b0,
                                                    st + ST0_OFF, x0);

    // stage 1 (also emits point-major x1t for the pool gather)
    vn_stats_kernel<42, 42, 6, 256, 8><<<dim3(43, 4), 256, 0, stream>>>(
        x0, wf1, st + ST1_OFF, 2048);
    vn_apply_kernel<42, 42, 6, 256, true><<<dim3(342, 4), 256, 0, stream>>>(
        x0, wf1, wd1, g1, b1, st + ST1_OFF, 8192.0, 2048, x1, x1t);

    // pool 1 (coalesced point-major gather)
    vn_pool_kernel<<<dim3(512, 4), 256, 0, stream>>>(x1t, idx20, 40960LL, 80, wp1, xm2,
                                                     42, 2048, 512);
    // stage 2
    vn_stats_kernel<42, 84, 3, 256, 8><<<dim3(22, 4), 256, 0, stream>>>(
        xm2, wf2, st + ST2_OFF, 512);
    vn_apply_kernel<42, 84, 3, 256, false><<<dim3(171, 4), 256, 0, stream>>>(
        xm2, wf2, wd2, g2, b2, st + ST2_OFF, 2048.0, 512, x2, nullptr);
    // stage 3 (also emits x3t for pool 2)
    vn_stats_kernel<84, 84, 3, 256, 8><<<dim3(22, 4), 256, 0, stream>>>(
        x2, wf3, st + ST3_OFF, 512);
    vn_apply_kernel<84, 84, 3, 256, true><<<dim3(171, 4), 256, 0, stream>>>(
        x2, wf3, wd3, g3, b3, st + ST3_OFF, 2048.0, 512, x3, x3t);

    // knn-4 on coord2 (cands stride 4, queries stride 16)
    knn_reg_kernel<8, 4, 1><<<dim3(32, 4), 256, 0, stream>>>(xc, 4, 16, idx42, 128);
    vn_pool_kernel<<<dim3(128, 4), 256, 0, stream>>>(x3t, idx42, 512LL, 4, wp2, xm4,
                                                     84, 512, 128);
    // stage 4
    vn_stats_kernel<84, 168, 3, 512, 4><<<dim3(11, 4), 512, 0, stream>>>(
        xm4, wf4, st + ST4_OFF, 128);
    vn_apply_kernel<84, 168, 3, 512, false><<<dim3(43, 4), 512, 0, stream>>>(
        xm4, wf4, wd4, g4, b4, st + ST4_OFF, 512.0, 128, x4, nullptr);

    // nearest-neighbor upsample indices (i1 + i2 from one scan)
    nearest_dual_kernel<<<dim3(512, 4), 256, 0, stream>>>(xc, i1p, i2p);

    // eqv (output 0) with fused mean partials; finalize mean (output 1)
    eqv_kernel<<<dim3(8, 1260, 4), 256, 0, stream>>>(x0, x1, x2, x3, x4, i1p, i2p,
                                                     out + OUT_EQV, mfw);
    mf_finalize_kernel<<<20, 256, 0, stream>>>(mfw, out + OUT_MF);

    // z chain (wave-per-output, coalesced) + inv_gl (output 3)
    z1_kernel<<<dim3(53, 4), 256, 0, stream>>>(mfw, wv1f, wv1d, z1ws);
    z2_kernel<<<dim3(21, 4), 256, 0, stream>>>(z1ws, wv2f, wv2d, z2ws);
    z3invgl_kernel<<<4, 256, 0, stream>>>(mfw, z2ws, w3, invgl, out + OUT_INVGL);

    // invariant branch: conv1 factored + moment-based cst1 (y1_stats eliminated)
    conv1_coef_kernel<<<dim3(256, 4), 256, 0, stream>>>(ws1, invgl, mfw, cat, mom,
                                                        cb, ab, w0, cst + CST1_OFF);
    y1_bnrelu_kernel<<<dim3(4, 32), 256, 0, stream>>>(cb, ab, w0, xc, normv,
                                                      cst + CST1_OFF, sg1, sb1, y1b);

    gemm_mfma_kernel<<<dim3(128, 8), 256, 0, stream>>>(y1b, w2b, y2t, cst + CST2_OFF,
                                                       1024, 512);
    bnreluT_kernel<<<16384, 256, 0, stream>>>(y2t, cst + CST2_OFF, sg2, sb2, y2b,
                                              512, 511);

    gemm_mfma_kernel<<<dim3(128, 7), 256, 0, stream>>>(y2b, w3b, y3t, cst + CST3_OFF,
                                                       512, 420);
    bnrelu_outT_kernel<<<dim3(128, 7), 256, 0, stream>>>(y3t, cst + CST3_OFF, sg3, sb3,
                                                         out + OUT_INV);
}

// Round 10
// 549.745 us; speedup vs baseline: 1.1923x; 1.0163x over previous
//
#include <hip/hip_runtime.h>
#include <hip/hip_bf16.h>
#include <cstdint>
#include <cstddef>

#define NTOT 2048
#define BTOT 4

typedef short bf16x8 __attribute__((ext_vector_type(8)));
typedef float f32x4 __attribute__((ext_vector_type(4)));

__device__ inline unsigned short f2b(float v) {
    __hip_bfloat16 h = __float2bfloat16(v);
    return *reinterpret_cast<unsigned short*>(&h);
}

// order-preserving float->uint map: a<b (float) <=> ordkey(a)<ordkey(b) (uint)
__device__ __forceinline__ unsigned ordkey(float f) {
    unsigned u = __float_as_uint(f);
    return (u & 0x80000000u) ? ~u : (u | 0x80000000u);
}

// ---------------- workspace layout (float-element offsets) ----------------
static const size_t WS_IDX20 = 0;                       // int[163840]
static const size_t WS_X1T   = 163840;                  // float[1032192] (B,2048,126) pool1 gather copy
static const size_t WS_X0    = 1638400;                 // float[2064384] (B,42,3,2048)
static const size_t WS_X1    = 3702784;                 // float[2064384]
static const size_t WS_XM2   = 5767168;                 // float[258048]
static const size_t WS_X2    = 6025216;                 // float[516096]
static const size_t WS_X3    = 6541312;                 // float[516096]
static const size_t WS_IDX42 = 7057408;                 // int[2048]
static const size_t WS_XM4   = 7059456;                 // float[129024]
static const size_t WS_X4    = 7188480;                 // float[258048]
static const size_t WS_I1    = 7446528;                 // int[8192]
static const size_t WS_I2    = 7454720;                 // int[8192]
static const size_t WS_MF    = 7462912;                 // float[5040] (RAW partial sums; /2048 at consumers)
static const size_t WS_INVGL = 7467952;                 // float[3360]
static const size_t WS_STATS = 7471312;                 // double[840] (1680 fl slots)
static const size_t WS_CST   = 7472992;                 // float[3912] conv bn sums
static const size_t WS_MOM   = 7476904;                 // float[56] per-batch moments (gap before CB)
static const size_t WS_CB    = 7480320;                 // float[4096]   cb[b][o]
static const size_t WS_AB    = 7484416;                 // float[12288]  ab[b][o][3]
static const size_t WS_W0    = 7496704;                 // float[1024]   ws1[:,0]
static const size_t WS_Z1    = 7497728;                 // float[2520]   z1[b][210*3]
static const size_t WS_Z2    = 7500288;                 // float[1008]   z2[b][84*3]
static const size_t WS_X3T   = 7501312;                 // float[516096] (B,512,252) pool2 gather copy
                                                        //   (inside Y2T span; lifetime-disjoint: dead before gemm1)
static const size_t WS_W2B   = 13378560;                // ushort[512*1024]
static const size_t WS_W3B   = 13640704;                // ushort[512*512]
static const size_t WS_Y1B   = 0;                       // ushort overlay (written late; x1t dead by then)
static const size_t WS_Y2T   = 7480320;                 // float overlay (CB/AB/Z dead)
static const size_t WS_Y2B   = 4194304;                 // ushort overlay
static const size_t WS_Y3T   = 13771776;                // float overlay

// zero-span: mfw..cst contiguous (mfw 5040 + invgl 3360 + stats 1680 + cst 3912)
#define ZERO_SPAN_BYTES ((7476904 - 7462912) * 4)

#define ST0_OFF 0
#define ST1_OFF 84
#define ST2_OFF 168
#define ST3_OFF 336
#define ST4_OFF 504
#define CST1_OFF 0
#define CST2_OFF 2048
#define CST3_OFF 3072

#define OUT_EQV   0
#define OUT_MF    10321920
#define OUT_INV   10326960
#define OUT_INVGL 13767600

// ============================ KNN v6 (packed u64-key butterfly) ==============
// key = (ordkey(dist) << 32) | ~m  — max-reduce gives max dist, min index on
// ties: selection bit-identical to (float,v idx) compare chain, ~1/2 VALU.
// NOTE: fp contract OFF — distance values must match prior rounds exactly.
template <int SLOTS, int K, int NQ>
__global__ __launch_bounds__(256)
void knn_reg_kernel(const float* __restrict__ coord, int cand_stride, int q_stride,
                    int* __restrict__ out_idx, int q_cnt)
{
#pragma clang fp contract(off)
    constexpr int Q = SLOTS / 8;
    int b = blockIdx.y;
    int wave = threadIdx.x >> 6, lane = threadIdx.x & 63;
    int qbase = (blockIdx.x * 4 + wave) * NQ;
    if (qbase >= q_cnt) return;
    float qx[NQ], qy[NQ], qz[NQ], xxq[NQ];
#pragma unroll
    for (int u = 0; u < NQ; ++u) {
        int nq = (qbase + u) * q_stride;
        qx[u] = coord[(b * 3 + 0) * NTOT + nq];
        qy[u] = coord[(b * 3 + 1) * NTOT + nq];
        qz[u] = coord[(b * 3 + 2) * NTOT + nq];
        xxq[u] = qx[u] * qx[u] + qy[u] * qy[u] + qz[u] * qz[u];
    }
    unsigned v[NQ][SLOTS];
#pragma unroll
    for (int j = 0; j < SLOTS; ++j) {
        int mo = (lane + 64 * j) * cand_stride;
        float cx = coord[(b * 3 + 0) * NTOT + mo];
        float cy = coord[(b * 3 + 1) * NTOT + mo];
        float cz = coord[(b * 3 + 2) * NTOT + mo];
        float xxc = cx * cx + cy * cy + cz * cz;
#pragma unroll
        for (int u = 0; u < NQ; ++u) {
            float inner = qx[u] * cx + qy[u] * cy + qz[u] * cz;
            float d = (2.0f * inner - xxq[u]) - xxc;
            v[u][j] = ordkey(d);
        }
    }
    unsigned qv[NQ][Q]; int qj[NQ][Q];
#pragma unroll
    for (int u = 0; u < NQ; ++u)
#pragma unroll
        for (int qq = 0; qq < Q; ++qq) {
            unsigned nv = v[u][qq * 8]; int nj = qq * 8;
#pragma unroll
            for (int j = 1; j < 8; ++j)
                if (v[u][qq * 8 + j] > nv) { nv = v[u][qq * 8 + j]; nj = qq * 8 + j; }
            qv[u][qq] = nv; qj[u][qq] = nj;
        }
#pragma clang loop unroll(disable)
    for (int kk = 0; kk < K; ++kk) {
        unsigned long long key[NQ];
#pragma unroll
        for (int u = 0; u < NQ; ++u) {
            unsigned tv = qv[u][0]; int tj = qj[u][0];
#pragma unroll
            for (int qq = 1; qq < Q; ++qq)
                if (qv[u][qq] > tv) { tv = qv[u][qq]; tj = qj[u][qq]; }
            key[u] = ((unsigned long long)tv << 32) |
                     (unsigned)(~(lane + 64 * tj));
        }
        // xor-butterfly max on packed key: all lanes converge on winner
        for (int off = 32; off; off >>= 1) {
#pragma unroll
            for (int u = 0; u < NQ; ++u) {
                unsigned long long o = __shfl_xor(key[u], off);
                if (o > key[u]) key[u] = o;
            }
        }
#pragma unroll
        for (int u = 0; u < NQ; ++u) {
            int m_win = (int)(~(unsigned)key[u]);
            m_win = __builtin_amdgcn_readfirstlane(m_win);
            if (lane == 0)
                out_idx[((size_t)(b * q_cnt) + qbase + u) * K + kk] = m_win;
            if (kk == K - 1 && u == NQ - 1) break;
            int w_slot = m_win >> 6;
            bool isw = (lane == (m_win & 63));
#pragma unroll
            for (int qq = 0; qq < Q; ++qq) {
                if (qq == (w_slot >> 3)) {
#pragma unroll
                    for (int j = 0; j < 8; ++j)
                        if (qq * 8 + j == w_slot)
                            v[u][qq * 8 + j] = isw ? 0u : v[u][qq * 8 + j];
                    unsigned nv = v[u][qq * 8]; int nj = qq * 8;
#pragma unroll
                    for (int j = 1; j < 8; ++j)
                        if (v[u][qq * 8 + j] > nv) { nv = v[u][qq * 8 + j]; nj = qq * 8 + j; }
                    qv[u][qq] = nv; qj[u][qq] = nj;
                }
            }
        }
    }
}

// ============================ nearest DUAL (packed u64-key min) ==============
// key = (ordkey(dist) << 32) | m — min-reduce gives min dist, min index ties.
__global__ __launch_bounds__(256)
void nearest_dual_kernel(const float* __restrict__ coord,
                         int* __restrict__ out1, int* __restrict__ out2)
{
#pragma clang fp contract(off)
    int b = blockIdx.y;
    int wave = threadIdx.x >> 6, lane = threadIdx.x & 63;
    int n = blockIdx.x * 4 + wave;
    float qx = coord[(b * 3 + 0) * NTOT + n];
    float qy = coord[(b * 3 + 1) * NTOT + n];
    float qz = coord[(b * 3 + 2) * NTOT + n];
    float tt = qx * qx + qy * qy + qz * qz;
    unsigned v[8];
#pragma unroll
    for (int j = 0; j < 8; ++j) {
        int mo = (lane + 64 * j) * 4;
        float cx = coord[(b * 3 + 0) * NTOT + mo];
        float cy = coord[(b * 3 + 1) * NTOT + mo];
        float cz = coord[(b * 3 + 2) * NTOT + mo];
        float inner = qx * cx + qy * cy + qz * cz;
        float ss = cx * cx + cy * cy + cz * cz;
        float d = (tt - 2.0f * inner) + ss;
        v[j] = ordkey(d);
    }
    unsigned bv = v[0];
    int bj = 0;
#pragma unroll
    for (int j = 1; j < 8; ++j)
        if (v[j] < bv) { bv = v[j]; bj = j; }
    unsigned long long k1 = ((unsigned long long)bv << 32) |
                            (unsigned)(lane + 64 * bj);
    // subset (stride-16 candidates): lanes with lane%4==0
    unsigned long long k2 = ~0ull;
    if ((lane & 3) == 0) {
        unsigned bv2 = v[0]; int bm2 = (lane >> 2);
#pragma unroll
        for (int j = 1; j < 8; ++j)
            if (v[j] < bv2) { bv2 = v[j]; bm2 = (lane >> 2) + 16 * j; }
        k2 = ((unsigned long long)bv2 << 32) | (unsigned)bm2;
    }
    for (int off = 32; off; off >>= 1) {
        unsigned long long o1 = __shfl_xor(k1, off);
        if (o1 < k1) k1 = o1;
        unsigned long long o2 = __shfl_xor(k2, off);
        if (o2 < k2) k2 = o2;
    }
    if (lane == 0) {
        out1[b * NTOT + n] = (int)(unsigned)k1;
        out2[b * NTOT + n] = (int)(unsigned)k2;
    }
}

// ============================ per-batch moments of (x,y,z,nr) ================
// 14 sums: Sx,Sy,Sz,Sn, Sxx,Syy,Szz,Snn, Sxy,Sxz,Syz, Sxn,Syn,Szn
__global__ __launch_bounds__(256)
void moments_kernel(const float* __restrict__ coord, const float* __restrict__ normv,
                    float* __restrict__ mom)
{
    __shared__ float red[4][14];
    int b = blockIdx.x, t = threadIdx.x;
    int lane = t & 63, wave = t >> 6;
    float m[14];
#pragma unroll
    for (int k = 0; k < 14; ++k) m[k] = 0.f;
    for (int i = t; i < NTOT; i += 256) {
        float x = coord[(b * 3 + 0) * NTOT + i];
        float y = coord[(b * 3 + 1) * NTOT + i];
        float z = coord[(b * 3 + 2) * NTOT + i];
        float r = normv[b * NTOT + i];
        m[0] += x;     m[1] += y;     m[2] += z;     m[3] += r;
        m[4] += x * x; m[5] += y * y; m[6] += z * z; m[7] += r * r;
        m[8] += x * y; m[9] += x * z; m[10] += y * z;
        m[11] += x * r; m[12] += y * r; m[13] += z * r;
    }
    for (int off = 32; off; off >>= 1)
#pragma unroll
        for (int k = 0; k < 14; ++k) m[k] += __shfl_down(m[k], off);
    if (lane == 0)
#pragma unroll
        for (int k = 0; k < 14; ++k) red[wave][k] = m[k];
    __syncthreads();
    if (t < 14)
        mom[b * 14 + t] = (red[0][t] + red[1][t]) + (red[2][t] + red[3][t]);
}

// ============================ stage-0 stats (fused surf feature) ==============
__global__ __launch_bounds__(256)
void stats0_kernel(const float* __restrict__ coord, const int* __restrict__ idx20,
                   const float* __restrict__ wf0, double* __restrict__ stats)
{
    __shared__ float nbc[360];   // [6 pts][20 nb][xyz]
    __shared__ float ctr[18];    // [6 pts][xyz]
    __shared__ double red[2][6][42];
    int t = threadIdx.x, b = blockIdx.y;
    int ps = t / 42, o = t - ps * 42;
    bool active = ps < 6;
    float w0 = 0.f, w1 = 0.f, w2 = 0.f;
    if (active) { w0 = wf0[o * 3]; w1 = wf0[o * 3 + 1]; w2 = wf0[o * 3 + 2]; }
    double s = 0.0, s2 = 0.0;
    int base = blockIdx.x * 48;
    for (int it = 0; it < 8; ++it) {
        int n0 = base + it * 6;
        __syncthreads();
        if (t < 120) {
            int pl = t / 20, k = t - pl * 20;
            int n = n0 + pl; if (n > NTOT - 1) n = NTOT - 1;
            int m = idx20[((size_t)(b * NTOT + n)) * 20 + k];
            nbc[t * 3 + 0] = coord[(b * 3 + 0) * NTOT + m];
            nbc[t * 3 + 1] = coord[(b * 3 + 1) * NTOT + m];
            nbc[t * 3 + 2] = coord[(b * 3 + 2) * NTOT + m];
        }
        if (t >= 128 && t < 146) {
            int i = t - 128; int pl = i / 3, vd = i - pl * 3;
            int n = n0 + pl; if (n > NTOT - 1) n = NTOT - 1;
            ctr[i] = coord[(b * 3 + vd) * NTOT + n];
        }
        __syncthreads();
        if (active && n0 + ps < NTOT) {
            float cx = ctr[ps * 3], cy = ctr[ps * 3 + 1], cz = ctr[ps * 3 + 2];
            const float* nb = &nbc[ps * 60];
            float sf = 0.f, sf2 = 0.f;
            for (int k = 0; k < 20; ++k) {
                float nx = nb[k * 3], ny = nb[k * 3 + 1], nz = nb[k * 3 + 2];
                float dx = nx - cx, dy = ny - cy, dz = nz - cz;
                float crx = ny * cz - nz * cy;
                float cry = nz * cx - nx * cz;
                float crz = nx * cy - ny * cx;
                float p0 = w0 * dx + w1 * cx + w2 * crx;
                float p1 = w0 * dy + w1 * cy + w2 * cry;
                float p2 = w0 * dz + w1 * cz + w2 * crz;
                float nrm = sqrtf(p0 * p0 + p1 * p1 + p2 * p2) + 1e-6f;
                sf += nrm; sf2 += nrm * nrm;
            }
            s += (double)sf; s2 += (double)sf2;
        }
    }
    if (active) { red[0][ps][o] = s; red[1][ps][o] = s2; }
    __syncthreads();
    if (t < 42) {
        double a = 0.0, a2 = 0.0;
#pragma unroll
        for (int p = 0; p < 6; ++p) { a += red[0][p][t]; a2 += red[1][p][t]; }
        atomicAdd(&stats[t], a);
        atomicAdd(&stats[42 + t], a2);
    }
}

// ============================ stage-0 apply (fused surf feature) ==============
__global__ __launch_bounds__(256)
void apply0_kernel(const float* __restrict__ coord, const int* __restrict__ idx20,
                   const float* __restrict__ wf0, const float* __restrict__ wd0,
                   const float* __restrict__ g0, const float* __restrict__ b0,
                   const double* __restrict__ stats, float* __restrict__ x0)
{
    __shared__ float nbc[360];
    __shared__ float ctr[18];
    int t = threadIdx.x;
    int b = blockIdx.y;
    int ps = t / 42, o = t - ps * 42;
    int n0 = blockIdx.x * 6;
    if (t < 120) {
        int pl = t / 20, k = t - pl * 20;
        int n = n0 + pl; if (n > NTOT - 1) n = NTOT - 1;
        int m = idx20[((size_t)(b * NTOT + n)) * 20 + k];
        nbc[t * 3 + 0] = coord[(b * 3 + 0) * NTOT + m];
        nbc[t * 3 + 1] = coord[(b * 3 + 1) * NTOT + m];
        nbc[t * 3 + 2] = coord[(b * 3 + 2) * NTOT + m];
    }
    if (t >= 128 && t < 146) {
        int i = t - 128; int pl = i / 3, vd = i - pl * 3;
        int n = n0 + pl; if (n > NTOT - 1) n = NTOT - 1;
        ctr[i] = coord[(b * 3 + vd) * NTOT + n];
    }
    __syncthreads();
    int n = n0 + ps;
    if (ps >= 6 || n >= NTOT) return;
    double S1 = stats[o], S2 = stats[42 + o];
    double md = S1 / 163840.0;
    float m = (float)md;
    float var = (float)(S2 / 163840.0 - md * md);
    float gs = g0[o] / sqrtf(var + 1e-5f);
    float bb = b0[o];
    float wa0 = wf0[o * 3], wa1 = wf0[o * 3 + 1], wa2 = wf0[o * 3 + 2];
    float wb0 = wd0[o * 3], wb1 = wd0[o * 3 + 1], wb2 = wd0[o * 3 + 2];
    float cx = ctr[ps * 3], cy = ctr[ps * 3 + 1], cz = ctr[ps * 3 + 2];
    const float* nb = &nbc[ps * 60];
    float a0 = 0.f, a1 = 0.f, a2 = 0.f;
    for (int k = 0; k < 20; ++k) {
        float nx = nb[k * 3], ny = nb[k * 3 + 1], nz = nb[k * 3 + 2];
        float dx = nx - cx, dy = ny - cy, dz = nz - cz;
        float crx = ny * cz - nz * cy;
        float cry = nz * cx - nx * cz;
        float crz = nx * cy - ny * cx;
        float p0 = wa0 * dx + wa1 * cx + wa2 * crx;
        float p1 = wa0 * dy + wa1 * cy + wa2 * cry;
        float p2 = wa0 * dz + wa1 * cz + wa2 * crz;
        float d0 = wb0 * dx + wb1 * cx + wb2 * crx;
        float d1 = wb0 * dy + wb1 * cy + wb2 * cry;
        float d2 = wb0 * dz + wb1 * cz + wb2 * crz;
        float nrm = sqrtf(p0 * p0 + p1 * p1 + p2 * p2) + 1e-6f;
        float nbv = gs * (nrm - m) + bb;
        float sc = nbv / nrm;
        p0 *= sc; p1 *= sc; p2 *= sc;
        float dot = p0 * d0 + p1 * d1 + p2 * d2;
        float dsq = d0 * d0 + d1 * d1 + d2 * d2 + 1e-6f;
        float tq = fminf(dot, 0.f) / dsq;
        a0 += 0.2f * p0 + 0.8f * (p0 - tq * d0);
        a1 += 0.2f * p1 + 0.8f * (p1 - tq * d1);
        a2 += 0.2f * p2 + 0.8f * (p2 - tq * d2);
    }
    x0[((size_t)(b * 42 + o) * 3 + 0) * NTOT + n] = a0 / 20.0f;
    x0[((size_t)(b * 42 + o) * 3 + 1) * NTOT + n] = a1 / 20.0f;
    x0[((size_t)(b * 42 + o) * 3 + 2) * NTOT + n] = a2 / 20.0f;
}

// ============================ generic VN stats (packed (ps,o)) ================
template <int Ci, int Co, int PTS, int NT, int NIT>
__global__ __launch_bounds__(NT)
void vn_stats_kernel(const float* __restrict__ xin,
                     const float* __restrict__ wf,
                     double* __restrict__ stats, int Npts)
{
    constexpr int Ci3 = Ci * 3;
    constexpr int STRIDE = Ci3 + 1;
    __shared__ float col[PTS * STRIDE];
    __shared__ double red[2][PTS][Co];
    int t = threadIdx.x;
    int b = blockIdx.y;
    int ps = t / Co;
    int o = t - ps * Co;
    bool active = ps < PTS;
    double s = 0.0, s2 = 0.0;
    int base = blockIdx.x * (PTS * NIT);
    for (int it = 0; it < NIT; ++it) {
        int pt0 = base + it * PTS;
        __syncthreads();
        for (int i = t; i < PTS * Ci3; i += NT) {
            int pl = i / Ci3, off = i - pl * Ci3;
            int pt = pt0 + pl; if (pt >= Npts) pt = Npts - 1;
            col[pl * STRIDE + off] = xin[(size_t)(b * 3 * Ci + off) * Npts + pt];
        }
        __syncthreads();
        if (active && pt0 + ps < Npts) {
            const float* cl = &col[ps * STRIDE];
            const float* wr = wf + o * Ci;
            float p0 = 0.f, p1 = 0.f, p2 = 0.f;
#pragma unroll
            for (int c = 0; c < Ci; ++c) {
                float w = wr[c];
                p0 += w * cl[3 * c]; p1 += w * cl[3 * c + 1]; p2 += w * cl[3 * c + 2];
            }
            float nrm = sqrtf(p0 * p0 + p1 * p1 + p2 * p2) + 1e-6f;
            s += (double)nrm; s2 += (double)nrm * (double)nrm;
        }
    }
    if (active) { red[0][ps][o] = s; red[1][ps][o] = s2; }
    __syncthreads();
    if (t < Co) {
        double a = 0.0, a2 = 0.0;
#pragma unroll
        for (int p = 0; p < PTS; ++p) { a += red[0][p][t]; a2 += red[1][p][t]; }
        atomicAdd(&stats[t], a);
        atomicAdd(&stats[Co + t], a2);
    }
}

// ============================ VN apply (packed (ps,o); optional transposed out)
template <int Ci, int Co, int PTS, int NT, bool WT>
__global__ __launch_bounds__(NT)
void vn_apply_kernel(const float* __restrict__ xin,
                     const float* __restrict__ wf,
                     const float* __restrict__ wd,
                     const float* __restrict__ g,
                     const float* __restrict__ bbp,
                     const double* __restrict__ stats,
                     double count, int Npts,
                     float* __restrict__ xout,
                     float* __restrict__ xt)
{
    constexpr int Ci3 = Ci * 3;
    constexpr int STRIDE = Ci3 + 1;
    constexpr int CH = Co * 3;
    __shared__ float col[PTS * STRIDE];
    int t = threadIdx.x;
    int b = blockIdx.y;
    int ps = t / Co;
    int o = t - ps * Co;
    bool active = ps < PTS;
    float m = 0.f, gs = 0.f, bb = 0.f;
    if (active) {
        double S1 = stats[o], S2 = stats[Co + o];
        double md = S1 / count;
        m = (float)md;
        float var = (float)(S2 / count - md * md);
        gs = g[o] / sqrtf(var + 1e-5f);
        bb = bbp[o];
    }
    int pt0 = blockIdx.x * PTS;
    for (int i = t; i < PTS * Ci3; i += NT) {
        int pl = i / Ci3, off = i - pl * Ci3;
        int pt = pt0 + pl; if (pt >= Npts) pt = Npts - 1;
        col[pl * STRIDE + off] = xin[(size_t)(b * 3 * Ci + off) * Npts + pt];
    }
    __syncthreads();
    int pt = pt0 + ps;
    if (!active || pt >= Npts) return;
    const float* cl = &col[ps * STRIDE];
    const float* wr = wf + o * Ci;
    const float* wdr = wd + o * Ci;
    float p0 = 0.f, p1 = 0.f, p2 = 0.f, d0 = 0.f, d1 = 0.f, d2 = 0.f;
#pragma unroll
    for (int c = 0; c < Ci; ++c) {
        float c0 = cl[3 * c], c1 = cl[3 * c + 1], c2 = cl[3 * c + 2];
        float w = wr[c];
        p0 += w * c0; p1 += w * c1; p2 += w * c2;
        float w2 = wdr[c];
        d0 += w2 * c0; d1 += w2 * c1; d2 += w2 * c2;
    }
    float nrm = sqrtf(p0 * p0 + p1 * p1 + p2 * p2) + 1e-6f;
    float nb = gs * (nrm - m) + bb;
    float sc = nb / nrm;
    p0 *= sc; p1 *= sc; p2 *= sc;
    float dot = p0 * d0 + p1 * d1 + p2 * d2;
    float dsq = d0 * d0 + d1 * d1 + d2 * d2 + 1e-6f;
    float tq = fminf(dot, 0.f) / dsq;
    float r0 = p0 - tq * d0, r1 = p1 - tq * d1, r2 = p2 - tq * d2;
    float o0 = 0.2f * p0 + 0.8f * r0;
    float o1 = 0.2f * p1 + 0.8f * r1;
    float o2 = 0.2f * p2 + 0.8f * r2;
    xout[((size_t)(b * Co + o) * 3 + 0) * Npts + pt] = o0;
    xout[((size_t)(b * Co + o) * 3 + 1) * Npts + pt] = o1;
    xout[((size_t)(b * Co + o) * 3 + 2) * Npts + pt] = o2;
    if (WT) {
        float* tp = xt + ((size_t)(b * Npts + pt)) * CH + o * 3;
        tp[0] = o0; tp[1] = o1; tp[2] = o2;
    }
}

// ============================ VN max-pool-down (point-major gather) ==========
// NOTE: keep fp contract OFF here — argmax selection over dots.
__global__ void vn_pool_kernel(const float* __restrict__ xint,
                               const int* __restrict__ idx, long long sb, int sq,
                               const float* __restrict__ wp,
                               float* __restrict__ xout,
                               int C, int Np, int Nq)
{
#pragma clang fp contract(off)
    __shared__ float nb[4 * 84 * 3];
    int b = blockIdx.y;
    int q = blockIdx.x;
    const int* ir = idx + b * sb + (long long)q * sq;
    int CH = C * 3;
    for (int kk = 0; kk < 4; ++kk) {
        int mm = ir[kk];
        const float* src = xint + ((size_t)(b * Np + mm)) * CH;
        for (int t = threadIdx.x; t < CH; t += blockDim.x)
            nb[kk * CH + t] = src[t];
    }
    __syncthreads();
    int o = threadIdx.x;
    if (o >= C) return;
    const float* wr = wp + o * C;
    float best = -3.4e38f;
    int bk = 0;
    for (int kk = 0; kk < 4; ++kk) {
        const float* cl = &nb[kk * CH];
        float d0 = 0.f, d1 = 0.f, d2 = 0.f;
        for (int c = 0; c < C; ++c) {
            float w = wr[c];
            d0 += w * cl[3 * c]; d1 += w * cl[3 * c + 1]; d2 += w * cl[3 * c + 2];
        }
        float dot = cl[o * 3] * d0 + cl[o * 3 + 1] * d1 + cl[o * 3 + 2] * d2;
        if (dot > best) { best = dot; bk = kk; }
    }
    const float* cbp = &nb[bk * CH];
    xout[((size_t)(b * C + o) * 3 + 0) * Nq + q] = cbp[o * 3];
    xout[((size_t)(b * C + o) * 3 + 1) * Nq + q] = cbp[o * 3 + 1];
    xout[((size_t)(b * C + o) * 3 + 2) * Nq + q] = cbp[o * 3 + 2];
}

// ============================ eqv assembly + fused mean partial ==============
__global__ void eqv_kernel(const float* __restrict__ x0, const float* __restrict__ x1,
                           const float* __restrict__ x2, const float* __restrict__ x3,
                           const float* __restrict__ x4,
                           const int* __restrict__ i1, const int* __restrict__ i2,
                           float* __restrict__ out_eqv, float* __restrict__ mfw)
{
    __shared__ float wsum[4];
    int n = blockIdx.x * 256 + threadIdx.x;
    int cv = blockIdx.y;
    int b = blockIdx.z;
    int cc = cv / 3, v = cv % 3;
    float val;
    if (cc < 42)
        val = x0[((size_t)(b * 42 + cc) * 3 + v) * NTOT + n];
    else if (cc < 84)
        val = x1[((size_t)(b * 42 + (cc - 42)) * 3 + v) * NTOT + n];
    else if (cc < 168) {
        int m = i1[b * NTOT + n];
        val = x2[((size_t)(b * 84 + (cc - 84)) * 3 + v) * 512 + m];
    } else if (cc < 252) {
        int m = i1[b * NTOT + n];
        val = x3[((size_t)(b * 84 + (cc - 168)) * 3 + v) * 512 + m];
    } else {
        int m = i2[b * NTOT + n];
        val = x4[((size_t)(b * 168 + (cc - 252)) * 3 + v) * 128 + m];
    }
    out_eqv[((size_t)(b * 1260 + cv)) * NTOT + n] = val;
    float s = val;
    for (int off = 32; off; off >>= 1) s += __shfl_down(s, off);
    if ((threadIdx.x & 63) == 0) wsum[threadIdx.x >> 6] = s;
    __syncthreads();
    if (threadIdx.x == 0)
        atomicAdd(&mfw[b * 1260 + cv], (wsum[0] + wsum[1]) + (wsum[2] + wsum[3]));
}

// ====== z1: wave-per-output VN layer (K=420) + fused mf finalize/out_mf ======
// mfw holds RAW partial sums; /2048 (exact pow2 scale) applied on load.
__global__ __launch_bounds__(256)
void z1_kernel(const float* __restrict__ mfw, float* __restrict__ out_mf,
               const float* __restrict__ wv1f, const float* __restrict__ wv1d,
               float* __restrict__ z1ws)
{
    __shared__ float mf[1260];
    int b = blockIdx.y;
    int wave = threadIdx.x >> 6, lane = threadIdx.x & 63;
    for (int i = threadIdx.x; i < 1260; i += 256) {
        float m = mfw[b * 1260 + i] * (1.f / 2048.f);
        mf[i] = m;
        if (blockIdx.x == 0) out_mf[b * 1260 + i] = m;
    }
    __syncthreads();
    int o = blockIdx.x * 4 + wave;
    if (o >= 210) return;
    const float* wr  = wv1f + (size_t)o * 420;
    const float* wdr = wv1d + (size_t)o * 420;
    float p0 = 0.f, p1 = 0.f, p2 = 0.f, d0 = 0.f, d1 = 0.f, d2 = 0.f;
    for (int c = lane; c < 420; c += 64) {
        float m0 = mf[3 * c], m1 = mf[3 * c + 1], m2 = mf[3 * c + 2];
        float w = wr[c];
        p0 += w * m0; p1 += w * m1; p2 += w * m2;
        float w2 = wdr[c];
        d0 += w2 * m0; d1 += w2 * m1; d2 += w2 * m2;
    }
    for (int off = 32; off; off >>= 1) {
        p0 += __shfl_down(p0, off); p1 += __shfl_down(p1, off);
        p2 += __shfl_down(p2, off); d0 += __shfl_down(d0, off);
        d1 += __shfl_down(d1, off); d2 += __shfl_down(d2, off);
    }
    if (lane == 0) {
        float dot = p0 * d0 + p1 * d1 + p2 * d2;
        float r0, r1, r2;
        if (dot >= 0.f) { r0 = p0; r1 = p1; r2 = p2; }
        else {
            float tq = dot / (d0 * d0 + d1 * d1 + d2 * d2 + 1e-6f);
            r0 = p0 - tq * d0; r1 = p1 - tq * d1; r2 = p2 - tq * d2;
        }
        z1ws[b * 630 + o * 3]     = 0.2f * p0 + 0.8f * r0;
        z1ws[b * 630 + o * 3 + 1] = 0.2f * p1 + 0.8f * r1;
        z1ws[b * 630 + o * 3 + 2] = 0.2f * p2 + 0.8f * r2;
    }
}

// ============================ z2: wave-per-output VN layer (K=210) ===========
__global__ __launch_bounds__(256)
void z2_kernel(const float* __restrict__ z1ws,
               const float* __restrict__ wv2f, const float* __restrict__ wv2d,
               float* __restrict__ z2ws)
{
    __shared__ float zl[630];
    int b = blockIdx.y;
    int wave = threadIdx.x >> 6, lane = threadIdx.x & 63;
    for (int i = threadIdx.x; i < 630; i += 256) zl[i] = z1ws[b * 630 + i];
    __syncthreads();
    int o = blockIdx.x * 4 + wave;
    if (o >= 84) return;
    const float* wr  = wv2f + (size_t)o * 210;
    const float* wdr = wv2d + (size_t)o * 210;
    float p0 = 0.f, p1 = 0.f, p2 = 0.f, d0 = 0.f, d1 = 0.f, d2 = 0.f;
    for (int c = lane; c < 210; c += 64) {
        float m0 = zl[3 * c], m1 = zl[3 * c + 1], m2 = zl[3 * c + 2];
        float w = wr[c];
        p0 += w * m0; p1 += w * m1; p2 += w * m2;
        float w2 = wdr[c];
        d0 += w2 * m0; d1 += w2 * m1; d2 += w2 * m2;
    }
    for (int off = 32; off; off >>= 1) {
        p0 += __shfl_down(p0, off); p1 += __shfl_down(p1, off);
        p2 += __shfl_down(p2, off); d0 += __shfl_down(d0, off);
        d1 += __shfl_down(d1, off); d2 += __shfl_down(d2, off);
    }
    if (lane == 0) {
        float dot = p0 * d0 + p1 * d1 + p2 * d2;
        float r0, r1, r2;
        if (dot >= 0.f) { r0 = p0; r1 = p1; r2 = p2; }
        else {
            float tq = dot / (d0 * d0 + d1 * d1 + d2 * d2 + 1e-6f);
            r0 = p0 - tq * d0; r1 = p1 - tq * d1; r2 = p2 - tq * d2;
        }
        z2ws[b * 252 + o * 3]     = 0.2f * p0 + 0.8f * r0;
        z2ws[b * 252 + o * 3 + 1] = 0.2f * p1 + 0.8f * r1;
        z2ws[b * 252 + o * 3 + 2] = 0.2f * p2 + 0.8f * r2;
    }
}

// ============================ z3 + inv_gl (mfw raw, /2048 on load) ==========
__global__ void z3invgl_kernel(const float* __restrict__ mfw,
                               const float* __restrict__ z2ws,
                               const float* __restrict__ w3,
                               float* __restrict__ invgl_ws,
                               float* __restrict__ out_invgl)
{
    __shared__ float z2[252];
    __shared__ float z3[6];
    __shared__ float mf[1260];
    int b = blockIdx.x;
    int t = threadIdx.x;
    for (int i = t; i < 252; i += 256) z2[i] = z2ws[b * 252 + i];
    for (int i = t; i < 1260; i += 256) mf[i] = mfw[b * 1260 + i] * (1.f / 2048.f);
    __syncthreads();
    if (t < 6) {
        int v = t / 2, kt = t % 2;
        float s = 0.f;
        for (int c = 0; c < 84; ++c) s += z2[c * 3 + v] * w3[kt * 84 + c];
        z3[v * 2 + kt] = s;
    }
    __syncthreads();
    for (int i = t; i < 840; i += 256) {
        int ii = i / 2, kt = i % 2;
        float s = mf[ii * 3] * z3[0 + kt] + mf[ii * 3 + 1] * z3[2 + kt] +
                  mf[ii * 3 + 2] * z3[4 + kt];
        invgl_ws[b * 840 + i] = s;
        out_invgl[b * 840 + i] = s;
    }
}

// ===== conv1 factored coefficients + moment-based y1 BN stats (wave-per-o) ===
// mfw raw: scale reduced a-terms by exact 1/2048 (pow2 => bit-identical).
__global__ __launch_bounds__(256)
void conv1_coef_kernel(const float* __restrict__ ws1,
                       const float* __restrict__ invgl,
                       const float* __restrict__ mfw,
                       const int* __restrict__ cat,
                       const float* __restrict__ mom,
                       float* __restrict__ cb, float* __restrict__ ab,
                       float* __restrict__ w0, float* __restrict__ cst1)
{
    int wave = threadIdx.x >> 6, lane = threadIdx.x & 63;
    int o = blockIdx.x * 4 + wave;           // 0..1023
    int b = blockIdx.y;
    const float* wr = ws1 + (size_t)o * 1267;
    float s = 0.f;
    for (int j = lane; j < 840; j += 64)
        s += wr[1 + j] * invgl[b * 840 + j];
    float a0 = 0.f, a1 = 0.f, a2 = 0.f;
    for (int i = lane; i < 420; i += 64) {
        float w = wr[841 + i];
        a0 += w * mfw[b * 1260 + i * 3];
        a1 += w * mfw[b * 1260 + i * 3 + 1];
        a2 += w * mfw[b * 1260 + i * 3 + 2];
    }
    for (int off = 32; off; off >>= 1) {
        s  += __shfl_down(s, off);
        a0 += __shfl_down(a0, off);
        a1 += __shfl_down(a1, off);
        a2 += __shfl_down(a2, off);
    }
    if (lane == 0) {
        a0 *= (1.f / 2048.f); a1 *= (1.f / 2048.f); a2 *= (1.f / 2048.f);
        float c0 = s + wr[1261 + cat[b]];
        float wn = wr[0];
        cb[b * 1024 + o] = c0;
        ab[((size_t)(b * 1024 + o)) * 3 + 0] = a0;
        ab[((size_t)(b * 1024 + o)) * 3 + 1] = a1;
        ab[((size_t)(b * 1024 + o)) * 3 + 2] = a2;
        if (b == 0) w0[o] = wn;
        // y1 BN stats from per-batch moments (exact: y1 is affine in (x,y,z,nr))
        const float* M = mom + b * 14;
        float lin = a0 * M[0] + a1 * M[1] + a2 * M[2] + wn * M[3];
        float s1 = 2048.f * c0 + lin;
        float s2 = 2048.f * c0 * c0 + 2.f * c0 * lin
                 + a0 * a0 * M[4] + a1 * a1 * M[5] + a2 * a2 * M[6] + wn * wn * M[7]
                 + 2.f * (a0 * a1 * M[8] + a0 * a2 * M[9] + a1 * a2 * M[10]
                 + a0 * wn * M[11] + a1 * wn * M[12] + a2 * wn * M[13]);
        atomicAdd(&cst1[o], s1);
        atomicAdd(&cst1[1024 + o], s2);
    }
}

// ============================ y1 BN+ReLU generator -> bf16 ====================
__global__ __launch_bounds__(256)
void y1_bnrelu_kernel(const float* __restrict__ cb, const float* __restrict__ ab,
                      const float* __restrict__ w0, const float* __restrict__ coord,
                      const float* __restrict__ normv, const float* __restrict__ cst,
                      const float* __restrict__ sg, const float* __restrict__ sb,
                      unsigned short* __restrict__ y1b)
{
    __shared__ float px[256], py[256], pz[256], pn[256];
    int t = threadIdx.x;
    int o = blockIdx.x * 256 + t;
    int b = blockIdx.y >> 3;
    int n0 = (blockIdx.y & 7) * 256;
    px[t] = coord[(b * 3 + 0) * NTOT + n0 + t];
    py[t] = coord[(b * 3 + 1) * NTOT + n0 + t];
    pz[t] = coord[(b * 3 + 2) * NTOT + n0 + t];
    pn[t] = normv[b * NTOT + n0 + t];
    __syncthreads();
    size_t bo = (size_t)(b * 1024 + o);
    float c0 = cb[bo];
    float a0 = ab[bo * 3], a1 = ab[bo * 3 + 1], a2 = ab[bo * 3 + 2];
    float wn = w0[o];
    float mm = cst[o] * (1.f / 8192.f);
    float var = cst[1024 + o] * (1.f / 8192.f) - mm * mm;
    float sc = sg[o] / sqrtf(var + 1e-5f);
    float bs = sb[o] - mm * sc;
    size_t rowbase = (size_t)(b * NTOT + n0) * 1024 + o;
    for (int k = 0; k < 256; ++k) {
        float v = c0 + a0 * px[k] + a1 * py[k] + a2 * pz[k] + wn * pn[k];
        float r = sc * v + bs;
        y1b[rowbase + (size_t)k * 1024] = f2b(r > 0.f ? r : 0.f);
    }
}

// ============================ weight convert f32 -> bf16 ============================
__global__ void wconv_kernel(const float* __restrict__ src, unsigned short* __restrict__ dst,
                             int Msrc, int Ksrc, int Kpad)
{
    int k = blockIdx.x * 256 + threadIdx.x;
    int o = blockIdx.y;
    float v = (o < Msrc && k < Ksrc) ? src[(size_t)o * Ksrc + k] : 0.f;
    dst[(size_t)o * Kpad + k] = f2b(v);
}

// ============================ MFMA GEMM 64x64/BK64 (+fused col BN stats) =====
__global__ __launch_bounds__(256)
void gemm_mfma_kernel(const unsigned short* __restrict__ A,
                      const unsigned short* __restrict__ Bw,
                      float* __restrict__ C, float* __restrict__ st,
                      int K, int Mreal)
{
    __shared__ __align__(16) unsigned short Al[64 * 72];
    __shared__ __align__(16) unsigned short Bl[64 * 72];
    __shared__ float sst[64], sst2[64];
    int t = threadIdx.x;
    if (t < 64) { sst[t] = 0.f; sst2[t] = 0.f; }
    int r0 = blockIdx.x * 64;
    int c0 = blockIdx.y * 64;
    int w = t >> 6, l = t & 63;
    int wm = w & 1, wn = w >> 1;
    int lm = l & 15, lq = l >> 4;
    f32x4 acc[2][2] = {};
    for (int k0 = 0; k0 < K; k0 += 64) {
#pragma unroll
        for (int half = 0; half < 2; ++half) {
            int ch = t + half * 256;
            int row = ch >> 3, kc = ch & 7;
            *(uint4*)&Al[row * 72 + kc * 8] =
                *(const uint4*)&A[(size_t)(r0 + row) * K + k0 + kc * 8];
            *(uint4*)&Bl[row * 72 + kc * 8] =
                *(const uint4*)&Bw[(size_t)(c0 + row) * K + k0 + kc * 8];
        }
        __syncthreads();
        bf16x8 af[2][2], bfr[2][2];
#pragma unroll
        for (int kk = 0; kk < 2; ++kk) {
#pragma unroll
            for (int i = 0; i < 2; ++i)
                af[kk][i] = *(const bf16x8*)&Al[(wm * 32 + i * 16 + lm) * 72 + kk * 32 + lq * 8];
#pragma unroll
            for (int j = 0; j < 2; ++j)
                bfr[kk][j] = *(const bf16x8*)&Bl[(wn * 32 + j * 16 + lm) * 72 + kk * 32 + lq * 8];
        }
#pragma unroll
        for (int kk = 0; kk < 2; ++kk)
#pragma unroll
            for (int i = 0; i < 2; ++i)
#pragma unroll
                for (int j = 0; j < 2; ++j)
                    acc[i][j] = __builtin_amdgcn_mfma_f32_16x16x32_bf16(
                        af[kk][i], bfr[kk][j], acc[i][j], 0, 0, 0);
        __syncthreads();
    }
#pragma unroll
    for (int i = 0; i < 2; ++i) {
#pragma unroll
        for (int j = 0; j < 2; ++j) {
            int col = c0 + wn * 32 + j * 16 + lm;
            if (col < Mreal) {
                int rbase = r0 + wm * 32 + i * 16 + lq * 4;
#pragma unroll
                for (int r = 0; r < 4; ++r)
                    C[(size_t)(rbase + r) * Mreal + col] = acc[i][j][r];
            }
        }
    }
#pragma unroll
    for (int j = 0; j < 2; ++j) {
        float s = 0.f, s2 = 0.f;
#pragma unroll
        for (int i = 0; i < 2; ++i)
#pragma unroll
            for (int r = 0; r < 4; ++r) { float x = acc[i][j][r]; s += x; s2 += x * x; }
        s  += __shfl_down(s, 32);  s  += __shfl_down(s, 16);
        s2 += __shfl_down(s2, 32); s2 += __shfl_down(s2, 16);
        if (l < 16) {
            int cc = wn * 32 + j * 16 + lm;
            atomicAdd(&sst[cc], s);
            atomicAdd(&sst2[cc], s2);
        }
    }
    __syncthreads();
    if (t < 64) {
        int col = c0 + t;
        if (col < Mreal) {
            atomicAdd(&st[col], sst[t]);
            atomicAdd(&st[Mreal + col], sst2[t]);
        }
    }
}

// ============================ BN+ReLU -> bf16 ============================
__global__ void bnreluT_kernel(const float* __restrict__ Ct, const float* __restrict__ st,
                               const float* __restrict__ g, const float* __restrict__ be,
                               unsigned short* __restrict__ outb, int M, int maskM)
{
    size_t idx = (size_t)blockIdx.x * 256 + threadIdx.x;
    int o = (int)(idx & (size_t)maskM);
    float m = st[o] * (1.f / 8192.f);
    float var = st[M + o] * (1.f / 8192.f) - m * m;
    float sqv = sqrtf(var + 1e-5f);
    float v = g[o] * (Ct[idx] - m) / sqv + be[o];
    outb[idx] = f2b(v > 0.f ? v : 0.f);
}

// ============================ final BN+ReLU + transpose ============================
__global__ void bnrelu_outT_kernel(const float* __restrict__ Ct, const float* __restrict__ st,
                                   const float* __restrict__ g, const float* __restrict__ be,
                                   float* __restrict__ outinv)
{
    __shared__ float tile[64][65];
    int t = threadIdx.x;
    int r0 = blockIdx.x * 64;
    int o0 = blockIdx.y * 64;
    int b = r0 >> 11, n0 = r0 & 2047;
    int oi = t & 63;
    int o = o0 + oi;
    float m = 0.f, sqv = 1.f, gg = 0.f, bb = 0.f;
    if (o < 420) {
        m = st[o] * (1.f / 8192.f);
        float var = st[420 + o] * (1.f / 8192.f) - m * m;
        sqv = sqrtf(var + 1e-5f);
        gg = g[o]; bb = be[o];
    }
    for (int it = 0; it < 16; ++it) {
        int rr = it * 4 + (t >> 6);
        float v = 0.f;
        if (o < 420) {
            v = gg * (Ct[(size_t)(r0 + rr) * 420 + o] - m) / sqv + bb;
            v = v > 0.f ? v : 0.f;
        }
        tile[rr][oi] = v;
    }
    __syncthreads();
    for (int it = 0; it < 16; ++it) {
        int oc = it * 4 + (t >> 6);
        int oo = o0 + oc;
        if (oo < 420)
            outinv[((size_t)(b * 420 + oo)) * 2048 + n0 + (t & 63)] = tile[t & 63][oc];
    }
}

// ============================ launch ============================
extern "C" void kernel_launch(void* const* d_in, const int* in_sizes, int n_in,
                              void* d_out, int out_size, void* d_ws, size_t ws_size,
                              hipStream_t stream)
{
    (void)in_sizes; (void)n_in; (void)out_size; (void)ws_size;
    const float* xc   = (const float*)d_in[0];
    const float* normv= (const float*)d_in[1];
    const int*   cat  = (const int*)d_in[2];
    const float* wf0  = (const float*)d_in[3];
    const float* wd0  = (const float*)d_in[4];
    const float* g0   = (const float*)d_in[5];
    const float* b0   = (const float*)d_in[6];
    const float* wf1  = (const float*)d_in[7];
    const float* wd1  = (const float*)d_in[8];
    const float* g1   = (const float*)d_in[9];
    const float* b1   = (const float*)d_in[10];
    const float* wp1  = (const float*)d_in[11];
    const float* wf2  = (const float*)d_in[12];
    const float* wd2  = (const float*)d_in[13];
    const float* g2   = (const float*)d_in[14];
    const float* b2   = (const float*)d_in[15];
    const float* wf3  = (const float*)d_in[16];
    const float* wd3  = (const float*)d_in[17];
    const float* g3   = (const float*)d_in[18];
    const float* b3   = (const float*)d_in[19];
    const float* wp2  = (const float*)d_in[20];
    const float* wf4  = (const float*)d_in[21];
    const float* wd4  = (const float*)d_in[22];
    const float* g4   = (const float*)d_in[23];
    const float* b4   = (const float*)d_in[24];
    const float* wv1f = (const float*)d_in[25];
    const float* wv1d = (const float*)d_in[26];
    const float* wv2f = (const float*)d_in[27];
    const float* wv2d = (const float*)d_in[28];
    const float* w3   = (const float*)d_in[29];
    const float* ws1  = (const float*)d_in[30];
    const float* sg1  = (const float*)d_in[32];
    const float* sb1  = (const float*)d_in[33];
    const float* ws2  = (const float*)d_in[34];
    const float* sg2  = (const float*)d_in[36];
    const float* sb2  = (const float*)d_in[37];
    const float* ws3  = (const float*)d_in[38];
    const float* sg3  = (const float*)d_in[40];
    const float* sb3  = (const float*)d_in[41];

    float* ws = (float*)d_ws;
    float* out = (float*)d_out;

    int*    idx20 = (int*)(ws + WS_IDX20);
    float*  x1t   = ws + WS_X1T;
    float*  x0    = ws + WS_X0;
    float*  x1    = ws + WS_X1;
    float*  xm2   = ws + WS_XM2;
    float*  x2    = ws + WS_X2;
    float*  x3    = ws + WS_X3;
    int*    idx42 = (int*)(ws + WS_IDX42);
    float*  xm4   = ws + WS_XM4;
    float*  x4    = ws + WS_X4;
    int*    i1p   = (int*)(ws + WS_I1);
    int*    i2p   = (int*)(ws + WS_I2);
    float*  mfw   = ws + WS_MF;
    float*  invgl = ws + WS_INVGL;
    double* st    = (double*)(ws + WS_STATS);
    float*  cst   = ws + WS_CST;
    float*  mom   = ws + WS_MOM;
    float*  cb    = ws + WS_CB;
    float*  ab    = ws + WS_AB;
    float*  w0    = ws + WS_W0;
    float*  z1ws  = ws + WS_Z1;
    float*  z2ws  = ws + WS_Z2;
    float*  x3t   = ws + WS_X3T;
    unsigned short* w2b  = (unsigned short*)(ws + WS_W2B);
    unsigned short* w3b  = (unsigned short*)(ws + WS_W3B);
    unsigned short* y1b  = (unsigned short*)(ws + WS_Y1B);
    float*  y2t   = ws + WS_Y2T;
    unsigned short* y2b  = (unsigned short*)(ws + WS_Y2B);
    float*  y3t   = ws + WS_Y3T;

    // single memset covers mfw + invgl + stats + cst (contiguous span)
    hipMemsetAsync((void*)mfw, 0, ZERO_SPAN_BYTES, stream);

    // per-batch coordinate moments (for moment-based y1 BN stats)
    moments_kernel<<<4, 256, 0, stream>>>(xc, normv, mom);

    // weight conversions (independent)
    wconv_kernel<<<dim3(4, 512), 256, 0, stream>>>(ws2, w2b, 512, 1024, 1024);
    wconv_kernel<<<dim3(2, 512), 256, 0, stream>>>(ws3, w3b, 420, 512, 512);

    // KNN-20: 2 queries per wave, packed-key butterfly
    knn_reg_kernel<32, 20, 2><<<dim3(256, 4), 256, 0, stream>>>(xc, 1, 1, idx20, 2048);

    // stage 0 (surf features fused from coord + idx20)
    stats0_kernel<<<dim3(43, 4), 256, 0, stream>>>(xc, idx20, wf0, st + ST0_OFF);
    apply0_kernel<<<dim3(342, 4), 256, 0, stream>>>(xc, idx20, wf0, wd0, g0, b0,
                                                    st + ST0_OFF, x0);

    // stage 1 (also emits point-major x1t for the pool gather)
    vn_stats_kernel<42, 42, 6, 256, 8><<<dim3(43, 4), 256, 0, stream>>>(
        x0, wf1, st + ST1_OFF, 2048);
    vn_apply_kernel<42, 42, 6, 256, true><<<dim3(342, 4), 256, 0, stream>>>(
        x0, wf1, wd1, g1, b1, st + ST1_OFF, 8192.0, 2048, x1, x1t);

    // pool 1 (coalesced point-major gather)
    vn_pool_kernel<<<dim3(512, 4), 256, 0, stream>>>(x1t, idx20, 40960LL, 80, wp1, xm2,
                                                     42, 2048, 512);
    // stage 2
    vn_stats_kernel<42, 84, 3, 256, 8><<<dim3(22, 4), 256, 0, stream>>>(
        xm2, wf2, st + ST2_OFF, 512);
    vn_apply_kernel<42, 84, 3, 256, false><<<dim3(171, 4), 256, 0, stream>>>(
        xm2, wf2, wd2, g2, b2, st + ST2_OFF, 2048.0, 512, x2, nullptr);
    // stage 3 (also emits x3t for pool 2)
    vn_stats_kernel<84, 84, 3, 256, 8><<<dim3(22, 4), 256, 0, stream>>>(
        x2, wf3, st + ST3_OFF, 512);
    vn_apply_kernel<84, 84, 3, 256, true><<<dim3(171, 4), 256, 0, stream>>>(
        x2, wf3, wd3, g3, b3, st + ST3_OFF, 2048.0, 512, x3, x3t);

    // knn-4 on coord2 (cands stride 4, queries stride 16)
    knn_reg_kernel<8, 4, 1><<<dim3(32, 4), 256, 0, stream>>>(xc, 4, 16, idx42, 128);
    vn_pool_kernel<<<dim3(128, 4), 256, 0, stream>>>(x3t, idx42, 512LL, 4, wp2, xm4,
                                                     84, 512, 128);
    // stage 4
    vn_stats_kernel<84, 168, 3, 512, 4><<<dim3(11, 4), 512, 0, stream>>>(
        xm4, wf4, st + ST4_OFF, 128);
    vn_apply_kernel<84, 168, 3, 512, false><<<dim3(43, 4), 512, 0, stream>>>(
        xm4, wf4, wd4, g4, b4, st + ST4_OFF, 512.0, 128, x4, nullptr);

    // nearest-neighbor upsample indices (i1 + i2 from one scan)
    nearest_dual_kernel<<<dim3(512, 4), 256, 0, stream>>>(xc, i1p, i2p);

    // eqv (output 0) with fused mean partials
    eqv_kernel<<<dim3(8, 1260, 4), 256, 0, stream>>>(x0, x1, x2, x3, x4, i1p, i2p,
                                                     out + OUT_EQV, mfw);

    // z chain (z1 fuses mf finalize + out_mf write) + inv_gl (output 3)
    z1_kernel<<<dim3(53, 4), 256, 0, stream>>>(mfw, out + OUT_MF, wv1f, wv1d, z1ws);
    z2_kernel<<<dim3(21, 4), 256, 0, stream>>>(z1ws, wv2f, wv2d, z2ws);
    z3invgl_kernel<<<4, 256, 0, stream>>>(mfw, z2ws, w3, invgl, out + OUT_INVGL);

    // invariant branch: conv1 factored + moment-based cst1 (y1_stats eliminated)
    conv1_coef_kernel<<<dim3(256, 4), 256, 0, stream>>>(ws1, invgl, mfw, cat, mom,
                                                        cb, ab, w0, cst + CST1_OFF);
    y1_bnrelu_kernel<<<dim3(4, 32), 256, 0, stream>>>(cb, ab, w0, xc, normv,
                                                      cst + CST1_OFF, sg1, sb1, y1b);

    gemm_mfma_kernel<<<dim3(128, 8), 256, 0, stream>>>(y1b, w2b, y2t, cst + CST2_OFF,
                                                       1024, 512);
    bnreluT_kernel<<<16384, 256, 0, stream>>>(y2t, cst + CST2_OFF, sg2, sb2, y2b,
                                              512, 511);

    gemm_mfma_kernel<<<dim3(128, 7), 256, 0, stream>>>(y2b, w3b, y3t, cst + CST3_OFF,
                                                       512, 420);
    bnrelu_outT_kernel<<<dim3(128, 7), 256, 0, stream>>>(y3t, cst + CST3_OFF, sg3, sb3,
                                                         out + OUT_INV);
}